// Round 1
// baseline (2278.584 us; speedup 1.0000x reference)
//
#include <hip/hip_runtime.h>
#include <hip/hip_bf16.h>
#include <math.h>

// Problem constants
static constexpr int BB = 4;
static constexpr int TT = 1024;
static constexpr int HH = 1024;
static constexpr int NHD = 4;
static constexpr int KDIM = 512;
static constexpr int VDIM = 1024;
static constexpr int DKH = 128;   // KD / NH
static constexpr int DVH = 256;   // VD / NH
static constexpr int RR = 32;
static constexpr int R5D = 160;
static constexpr int GG = 64;
static constexpr int NTOK = BB * TT;   // 4096

// ---------------------------------------------------------------------------
// Kernel 1: x_lerp = h + (h_prev - h)*x_proj_mu ; x1 = tanh(tanh(x_lerp@w1^T)@w2^T + b2)
// one block per token, 256 threads
// ---------------------------------------------------------------------------
__global__ __launch_bounds__(256) void k_lora_x(
    const float* __restrict__ h, const float* __restrict__ mu,
    const float* __restrict__ w1, const float* __restrict__ w2,
    const float* __restrict__ b2, float* __restrict__ x1out)
{
    int m = blockIdx.x;            // token index (b*T + t)
    int t = m & (TT - 1);
    int tid = threadIdx.x;
    const float* hc = h + (size_t)m * HH;
    __shared__ float xs[256];
    __shared__ float part[8][32];
    __shared__ float t0[RR];
    int r = tid & 31, seg = tid >> 5;
    float acc = 0.f;
    for (int c = 0; c < HH; c += 256) {
        int hh = c + tid;
        float cur = hc[hh];
        float prev = (t > 0) ? hc[hh - HH] : 0.f;
        xs[tid] = cur + (prev - cur) * mu[hh];
        __syncthreads();
        const float* wrow = w1 + (size_t)r * HH + c + seg * 32;
        const float* xrow = xs + seg * 32;
        #pragma unroll
        for (int j = 0; j < 32; j++) acc += xrow[j] * wrow[j];
        __syncthreads();
    }
    part[seg][r] = acc;
    __syncthreads();
    if (tid < 32) {
        float s = 0.f;
        #pragma unroll
        for (int q = 0; q < 8; q++) s += part[q][tid];
        t0[tid] = tanhf(s);
    }
    __syncthreads();
    if (tid < R5D) {
        float s = b2[tid];
        const float* w2r = w2 + (size_t)tid * RR;
        #pragma unroll
        for (int q = 0; q < RR; q++) s += t0[q] * w2r[q];
        x1out[(size_t)m * R5D + tid] = tanhf(s);
    }
}

// ---------------------------------------------------------------------------
// Kernel 2: mus = einsum(x1, x_out_w) + x_bias; X_n = h + (h_prev-h)*mu_n
// one block per token, 256 threads, 4 h per thread
// ---------------------------------------------------------------------------
__global__ __launch_bounds__(256) void k_mix(
    const float* __restrict__ h, const float* __restrict__ x1,
    const float* __restrict__ xow, const float* __restrict__ xb,
    float* __restrict__ xr, float* __restrict__ xw, float* __restrict__ xk,
    float* __restrict__ xv, float* __restrict__ xg)
{
    int m = blockIdx.x;
    int t = m & (TT - 1);
    int tid = threadIdx.x;
    __shared__ float s1[R5D];
    if (tid < R5D) s1[tid] = x1[(size_t)m * R5D + tid];
    __syncthreads();
    const float* hc = h + (size_t)m * HH;
    float* outs[5] = {xr, xw, xk, xv, xg};
    for (int q = 0; q < 4; q++) {
        int hh = q * 256 + tid;
        float cur = hc[hh];
        float prev = (t > 0) ? hc[hh - HH] : 0.f;
        float d = prev - cur;
        const float* wr = xow + (size_t)hh * R5D;
        #pragma unroll
        for (int n = 0; n < 5; n++) {
            float s = xb[n * HH + hh];
            #pragma unroll
            for (int r2 = 0; r2 < 32; r2++) s += s1[n * 32 + r2] * wr[n * 32 + r2];
            outs[n][(size_t)m * HH + hh] = cur + d * s;
        }
    }
}

// ---------------------------------------------------------------------------
// Kernel 3: generic fp32 GEMM  C[M,N] = A[M,K] @ B[N,K]^T  (+ epilogue)
// EPI: 0 = none, 1 = tanh, 2 = exp(-exp(x + bias[col]))
// BM=BN=64, BK=16, 256 threads, 4x4 per thread
// ---------------------------------------------------------------------------
template <int EPI>
__global__ __launch_bounds__(256) void k_gemm(
    const float* __restrict__ A, const float* __restrict__ Bm,
    const float* __restrict__ bias, float* __restrict__ C,
    int M, int N, int K)
{
    __shared__ float As[16][68];
    __shared__ float Bs[16][68];
    int tid = threadIdx.x;
    int bm = blockIdx.x * 64, bn = blockIdx.y * 64;
    int tx = tid & 15, ty = tid >> 4;
    int lr = tid >> 2;
    int lk = (tid & 3) * 4;
    float acc[4][4] = {};
    for (int k0 = 0; k0 < K; k0 += 16) {
        float4 av = *(const float4*)(A + (size_t)(bm + lr) * K + k0 + lk);
        float4 bv = *(const float4*)(Bm + (size_t)(bn + lr) * K + k0 + lk);
        As[lk + 0][lr] = av.x; As[lk + 1][lr] = av.y;
        As[lk + 2][lr] = av.z; As[lk + 3][lr] = av.w;
        Bs[lk + 0][lr] = bv.x; Bs[lk + 1][lr] = bv.y;
        Bs[lk + 2][lr] = bv.z; Bs[lk + 3][lr] = bv.w;
        __syncthreads();
        #pragma unroll
        for (int kk = 0; kk < 16; kk++) {
            float4 a4 = *(const float4*)&As[kk][ty * 4];
            float4 b4 = *(const float4*)&Bs[kk][tx * 4];
            float aa[4] = {a4.x, a4.y, a4.z, a4.w};
            float bb[4] = {b4.x, b4.y, b4.z, b4.w};
            #pragma unroll
            for (int i = 0; i < 4; i++)
                #pragma unroll
                for (int j = 0; j < 4; j++)
                    acc[i][j] += aa[i] * bb[j];
        }
        __syncthreads();
    }
    #pragma unroll
    for (int i = 0; i < 4; i++) {
        int row = bm + ty * 4 + i;
        int col = bn + tx * 4;
        float4 ov;
        float vv[4];
        #pragma unroll
        for (int j = 0; j < 4; j++) {
            float v = acc[i][j];
            if (EPI == 1) v = tanhf(v);
            else if (EPI == 2) v = expf(-expf(v + bias[col + j]));
            vv[j] = v;
        }
        ov.x = vv[0]; ov.y = vv[1]; ov.z = vv[2]; ov.w = vv[3];
        *(float4*)(C + (size_t)row * N + col) = ov;
    }
}

// ---------------------------------------------------------------------------
// Kernel 4: bonus dot  u[b,t,h] = sum_k r*bonus*k   (grid = B*T*NH, 128 thr)
// ---------------------------------------------------------------------------
__global__ __launch_bounds__(128) void k_bonus(
    const float* __restrict__ r, const float* __restrict__ k,
    const float* __restrict__ bonus, float* __restrict__ u)
{
    int g = blockIdx.x;            // (b*T+t)*NH + h
    int h = g & (NHD - 1);
    int tid = threadIdx.x;
    size_t base = (size_t)g * DKH;
    float p = r[base + tid] * k[base + tid] * bonus[h * DKH + tid];
    #pragma unroll
    for (int m = 32; m; m >>= 1) p += __shfl_down(p, m);
    __shared__ float wsum[2];
    if ((tid & 63) == 0) wsum[tid >> 6] = p;
    __syncthreads();
    if (tid == 0) u[g] = wsum[0] + wsum[1];
}

// ---------------------------------------------------------------------------
// Kernel 5: sequential scan over T. 64 blocks = (b,h, v-slice of 64).
// 256 threads: kg = tid&15 (8 k each), vg = tid>>4 (4 v each). State in regs.
// ---------------------------------------------------------------------------
__global__ __launch_bounds__(256) void k_scan(
    const float* __restrict__ rp, const float* __restrict__ kp,
    const float* __restrict__ wp, const float* __restrict__ vp,
    const float* __restrict__ up, float* __restrict__ op)
{
    constexpr int VS = 64;
    constexpr int NSPLIT = DVH / VS;   // 4
    int blk = blockIdx.x;
    int vs = blk & (NSPLIT - 1);
    int bh = blk / NSPLIT;             // b*NH + h
    int tid = threadIdx.x;
    int kg = tid & 15;
    int vg = tid >> 4;
    float S[8][4] = {};
    __shared__ float stage[2][449];
    for (int t = 0; t < TT; t++) {
        float* st = stage[t & 1];
        size_t gb = (size_t)(bh & 3) + (size_t)((bh >> 2) * TT + t) * NHD;
        {
            int i = tid;
            st[i] = (i < 128) ? rp[gb * DKH + i] : kp[gb * DKH + (i - 128)];
            int i2 = tid + 256;
            if (i2 < 384)       st[i2] = wp[gb * DKH + (i2 - 256)];
            else if (i2 < 448)  st[i2] = vp[gb * DVH + vs * VS + (i2 - 384)];
            else if (i2 == 448) st[i2] = up[gb];
        }
        __syncthreads();
        const float* rr = st;
        const float* kk2 = st + 128;
        const float* ww = st + 256;
        const float* vv = st + 384;
        float u = st[448];
        float ra[8], wa[8], ka[8], vt[4];
        #pragma unroll
        for (int i = 0; i < 8; i++) {
            ra[i] = rr[kg * 8 + i];
            wa[i] = ww[kg * 8 + i];
            ka[i] = kk2[kg * 8 + i];
        }
        #pragma unroll
        for (int j = 0; j < 4; j++) vt[j] = vv[vg * 4 + j];
        float o[4] = {0.f, 0.f, 0.f, 0.f};
        #pragma unroll
        for (int i = 0; i < 8; i++)
            #pragma unroll
            for (int j = 0; j < 4; j++) o[j] += ra[i] * S[i][j];
        #pragma unroll
        for (int mks = 1; mks < 16; mks <<= 1) {
            #pragma unroll
            for (int j = 0; j < 4; j++) o[j] += __shfl_xor(o[j], mks);
        }
        if (kg == 0) {
            float4 ov;
            ov.x = o[0] + u * vt[0];
            ov.y = o[1] + u * vt[1];
            ov.z = o[2] + u * vt[2];
            ov.w = o[3] + u * vt[3];
            *(float4*)(op + gb * DVH + vs * VS + vg * 4) = ov;
        }
        #pragma unroll
        for (int i = 0; i < 8; i++) {
            float wv = wa[i], kv = ka[i];
            #pragma unroll
            for (int j = 0; j < 4; j++) S[i][j] = S[i][j] * wv + kv * vt[j];
        }
    }
}

// ---------------------------------------------------------------------------
// Kernel 6: per-head groupnorm + gn affine + silu(g) gate
// grid = B*T*NH, 256 threads (one per dv)
// ---------------------------------------------------------------------------
__global__ __launch_bounds__(256) void k_gn(
    const float* __restrict__ o, const float* __restrict__ g,
    const float* __restrict__ gw, const float* __restrict__ gb,
    float* __restrict__ y)
{
    int gidx = blockIdx.x;           // (b*T+t)*NH + h
    int h = gidx & (NHD - 1);
    int tid = threadIdx.x;
    size_t base = (size_t)gidx * DVH;
    float x = o[base + tid];
    float s = x, s2 = x * x;
    #pragma unroll
    for (int m = 32; m; m >>= 1) { s += __shfl_down(s, m); s2 += __shfl_down(s2, m); }
    __shared__ float as_[4], bs_[4];
    if ((tid & 63) == 0) { as_[tid >> 6] = s; bs_[tid >> 6] = s2; }
    __syncthreads();
    s = as_[0] + as_[1] + as_[2] + as_[3];
    s2 = bs_[0] + bs_[1] + bs_[2] + bs_[3];
    float mean = s * (1.f / DVH);
    float var = s2 * (1.f / DVH) - mean * mean;
    float inv = rsqrtf(var + 1e-5f);
    int c = h * DVH + tid;
    size_t mtok = (size_t)(gidx >> 2);
    float gv = g[mtok * VDIM + c];
    float sig = 1.f / (1.f + expf(-gv));
    y[mtok * VDIM + c] = ((x - mean) * inv * gw[c] + gb[c]) * (gv * sig);
}

// ---------------------------------------------------------------------------
extern "C" void kernel_launch(void* const* d_in, const int* in_sizes, int n_in,
                              void* d_out, int out_size, void* d_ws, size_t ws_size,
                              hipStream_t stream)
{
    const float* h        = (const float*)d_in[0];
    const float* x_mu     = (const float*)d_in[1];
    const float* xl_w1    = (const float*)d_in[2];
    const float* xl_w2    = (const float*)d_in[3];
    const float* xl_b2    = (const float*)d_in[4];
    const float* x_out_w  = (const float*)d_in[5];
    const float* x_bias   = (const float*)d_in[6];
    const float* r_w      = (const float*)d_in[7];
    const float* w_w1     = (const float*)d_in[8];
    const float* w_w2     = (const float*)d_in[9];
    const float* w_b      = (const float*)d_in[10];
    const float* k_w      = (const float*)d_in[11];
    const float* v_w      = (const float*)d_in[12];
    const float* g_w      = (const float*)d_in[13];
    const float* bonus    = (const float*)d_in[14];
    const float* gn_w     = (const float*)d_in[15];
    const float* gn_b     = (const float*)d_in[16];
    const float* o_w      = (const float*)d_in[17];
    float* out = (float*)d_out;

    float* ws = (float*)d_ws;
    size_t off = 0;
    float* x1   = ws + off; off += (size_t)NTOK * R5D;        // 0.66M
    float* Xr   = ws + off; off += (size_t)NTOK * HH;         // 4.19M each
    float* Xw   = ws + off; off += (size_t)NTOK * HH;
    float* Xk   = ws + off; off += (size_t)NTOK * HH;
    float* Xv   = ws + off; off += (size_t)NTOK * HH;
    float* Xg   = ws + off; off += (size_t)NTOK * HH;
    float* rbuf = ws + off; off += (size_t)NTOK * KDIM;
    float* wdbf = ws + off; off += (size_t)NTOK * KDIM;
    float* kbuf = ws + off; off += (size_t)NTOK * KDIM;
    float* vbuf = ws + off; off += (size_t)NTOK * VDIM;
    float* gbuf = ws + off; off += (size_t)NTOK * VDIM;
    float* w1t  = ws + off; off += (size_t)NTOK * GG;
    float* ubuf = ws + off; off += (size_t)NTOK * NHD;
    // aliases (lifetimes disjoint): scan output over Xr, gated y over Xw
    float* obuf = Xr;
    float* ybuf = Xw;

    k_lora_x<<<NTOK, 256, 0, stream>>>(h, x_mu, xl_w1, xl_w2, xl_b2, x1);
    k_mix<<<NTOK, 256, 0, stream>>>(h, x1, x_out_w, x_bias, Xr, Xw, Xk, Xv, Xg);

    // projections
    k_gemm<0><<<dim3(NTOK / 64, KDIM / 64), 256, 0, stream>>>(Xr, r_w, nullptr, rbuf, NTOK, KDIM, HH);
    k_gemm<0><<<dim3(NTOK / 64, KDIM / 64), 256, 0, stream>>>(Xk, k_w, nullptr, kbuf, NTOK, KDIM, HH);
    k_gemm<0><<<dim3(NTOK / 64, VDIM / 64), 256, 0, stream>>>(Xv, v_w, nullptr, vbuf, NTOK, VDIM, HH);
    k_gemm<0><<<dim3(NTOK / 64, VDIM / 64), 256, 0, stream>>>(Xg, g_w, nullptr, gbuf, NTOK, VDIM, HH);
    k_gemm<1><<<dim3(NTOK / 64, GG / 64), 256, 0, stream>>>(Xw, w_w1, nullptr, w1t, NTOK, GG, HH);
    k_gemm<2><<<dim3(NTOK / 64, KDIM / 64), 256, 0, stream>>>(w1t, w_w2, w_b, wdbf, NTOK, KDIM, GG);

    k_bonus<<<NTOK * NHD, 128, 0, stream>>>(rbuf, kbuf, bonus, ubuf);
    k_scan<<<BB * NHD * 4, 256, 0, stream>>>(rbuf, kbuf, wdbf, vbuf, ubuf, obuf);
    k_gn<<<NTOK * NHD, 256, 0, stream>>>(obuf, gbuf, gn_w, gn_b, ybuf);

    // final projection -> d_out
    k_gemm<0><<<dim3(NTOK / 64, HH / 64), 256, 0, stream>>>(ybuf, o_w, nullptr, out, NTOK, HH, VDIM);
}

// Round 2
// 1178.393 us; speedup vs baseline: 1.9336x; 1.9336x over previous
//
#include <hip/hip_runtime.h>
#include <hip/hip_bf16.h>
#include <math.h>

// Problem constants
static constexpr int BB = 4;
static constexpr int TT = 1024;
static constexpr int HH = 1024;
static constexpr int NHD = 4;
static constexpr int KDIM = 512;
static constexpr int VDIM = 1024;
static constexpr int DKH = 128;   // KD / NH
static constexpr int DVH = 256;   // VD / NH
static constexpr int RR = 32;
static constexpr int R5D = 160;
static constexpr int GG = 64;
static constexpr int NTOK = BB * TT;   // 4096
static constexpr int CK = 32;          // chunk length
static constexpr int NCK = TT / CK;    // 32 chunks per sequence

// ---------------------------------------------------------------------------
// Kernel 1: x_lerp = h + (h_prev - h)*x_proj_mu ; x1 = tanh(tanh(x_lerp@w1^T)@w2^T + b2)
// ---------------------------------------------------------------------------
__global__ __launch_bounds__(256) void k_lora_x(
    const float* __restrict__ h, const float* __restrict__ mu,
    const float* __restrict__ w1, const float* __restrict__ w2,
    const float* __restrict__ b2, float* __restrict__ x1out)
{
    int m = blockIdx.x;            // token index (b*T + t)
    int t = m & (TT - 1);
    int tid = threadIdx.x;
    const float* hc = h + (size_t)m * HH;
    __shared__ float xs[256];
    __shared__ float part[8][32];
    __shared__ float t0[RR];
    int r = tid & 31, seg = tid >> 5;
    float acc = 0.f;
    for (int c = 0; c < HH; c += 256) {
        int hh = c + tid;
        float cur = hc[hh];
        float prev = (t > 0) ? hc[hh - HH] : 0.f;
        xs[tid] = cur + (prev - cur) * mu[hh];
        __syncthreads();
        const float* wrow = w1 + (size_t)r * HH + c + seg * 32;
        const float* xrow = xs + seg * 32;
        #pragma unroll
        for (int j = 0; j < 32; j++) acc += xrow[j] * wrow[j];
        __syncthreads();
    }
    part[seg][r] = acc;
    __syncthreads();
    if (tid < 32) {
        float s = 0.f;
        #pragma unroll
        for (int q = 0; q < 8; q++) s += part[q][tid];
        t0[tid] = tanhf(s);
    }
    __syncthreads();
    if (tid < R5D) {
        float s = b2[tid];
        const float* w2r = w2 + (size_t)tid * RR;
        #pragma unroll
        for (int q = 0; q < RR; q++) s += t0[q] * w2r[q];
        x1out[(size_t)m * R5D + tid] = tanhf(s);
    }
}

// ---------------------------------------------------------------------------
// Kernel 2: mus = einsum(x1, x_out_w) + x_bias; X_n = h + (h_prev-h)*mu_n
// ---------------------------------------------------------------------------
__global__ __launch_bounds__(256) void k_mix(
    const float* __restrict__ h, const float* __restrict__ x1,
    const float* __restrict__ xow, const float* __restrict__ xb,
    float* __restrict__ xr, float* __restrict__ xw, float* __restrict__ xk,
    float* __restrict__ xv, float* __restrict__ xg)
{
    int m = blockIdx.x;
    int t = m & (TT - 1);
    int tid = threadIdx.x;
    __shared__ float s1[R5D];
    if (tid < R5D) s1[tid] = x1[(size_t)m * R5D + tid];
    __syncthreads();
    const float* hc = h + (size_t)m * HH;
    float* outs[5] = {xr, xw, xk, xv, xg};
    for (int q = 0; q < 4; q++) {
        int hh = q * 256 + tid;
        float cur = hc[hh];
        float prev = (t > 0) ? hc[hh - HH] : 0.f;
        float d = prev - cur;
        const float* wr = xow + (size_t)hh * R5D;
        #pragma unroll
        for (int n = 0; n < 5; n++) {
            float s = xb[n * HH + hh];
            #pragma unroll
            for (int r2 = 0; r2 < 32; r2++) s += s1[n * 32 + r2] * wr[n * 32 + r2];
            outs[n][(size_t)m * HH + hh] = cur + d * s;
        }
    }
}

// ---------------------------------------------------------------------------
// Kernel 3: generic fp32 GEMM  C[M,N] = A[M,K] @ B[N,K]^T  (+ epilogue)
// EPI: 0 = none, 1 = tanh, 2 = exp(x + bias[col])   (decay exponent e)
// ---------------------------------------------------------------------------
template <int EPI>
__global__ __launch_bounds__(256) void k_gemm(
    const float* __restrict__ A, const float* __restrict__ Bm,
    const float* __restrict__ bias, float* __restrict__ C,
    int M, int N, int K)
{
    __shared__ float As[16][68];
    __shared__ float Bs[16][68];
    int tid = threadIdx.x;
    int bm = blockIdx.x * 64, bn = blockIdx.y * 64;
    int tx = tid & 15, ty = tid >> 4;
    int lr = tid >> 2;
    int lk = (tid & 3) * 4;
    float acc[4][4] = {};
    for (int k0 = 0; k0 < K; k0 += 16) {
        float4 av = *(const float4*)(A + (size_t)(bm + lr) * K + k0 + lk);
        float4 bv = *(const float4*)(Bm + (size_t)(bn + lr) * K + k0 + lk);
        As[lk + 0][lr] = av.x; As[lk + 1][lr] = av.y;
        As[lk + 2][lr] = av.z; As[lk + 3][lr] = av.w;
        Bs[lk + 0][lr] = bv.x; Bs[lk + 1][lr] = bv.y;
        Bs[lk + 2][lr] = bv.z; Bs[lk + 3][lr] = bv.w;
        __syncthreads();
        #pragma unroll
        for (int kk = 0; kk < 16; kk++) {
            float4 a4 = *(const float4*)&As[kk][ty * 4];
            float4 b4 = *(const float4*)&Bs[kk][tx * 4];
            float aa[4] = {a4.x, a4.y, a4.z, a4.w};
            float bb[4] = {b4.x, b4.y, b4.z, b4.w};
            #pragma unroll
            for (int i = 0; i < 4; i++)
                #pragma unroll
                for (int j = 0; j < 4; j++)
                    acc[i][j] += aa[i] * bb[j];
        }
        __syncthreads();
    }
    #pragma unroll
    for (int i = 0; i < 4; i++) {
        int row = bm + ty * 4 + i;
        int col = bn + tx * 4;
        float4 ov;
        float vv[4];
        #pragma unroll
        for (int j = 0; j < 4; j++) {
            float v = acc[i][j];
            if (EPI == 1) v = tanhf(v);
            else if (EPI == 2) v = __expf(v + bias[col + j]);
            vv[j] = v;
        }
        ov.x = vv[0]; ov.y = vv[1]; ov.z = vv[2]; ov.w = vv[3];
        *(float4*)(C + (size_t)row * N + col) = ov;
    }
}

// ---------------------------------------------------------------------------
// Kernel 4: bonus dot  u[b,t,h] = sum_k r*bonus*k  (raw r,k — run BEFORE chunkA)
// ---------------------------------------------------------------------------
__global__ __launch_bounds__(128) void k_bonus(
    const float* __restrict__ r, const float* __restrict__ k,
    const float* __restrict__ bonus, float* __restrict__ u)
{
    int g = blockIdx.x;            // (b*T+t)*NH + h
    int h = g & (NHD - 1);
    int tid = threadIdx.x;
    size_t base = (size_t)g * DKH;
    float p = r[base + tid] * k[base + tid] * bonus[h * DKH + tid];
    #pragma unroll
    for (int m = 32; m; m >>= 1) p += __shfl_down(p, m);
    __shared__ float wsum[2];
    if ((tid & 63) == 0) wsum[tid >> 6] = p;
    __syncthreads();
    if (tid == 0) u[g] = wsum[0] + wsum[1];
}

// ---------------------------------------------------------------------------
// Kernel 5a (chunkA): per (bh,chunk): cumsum decay L; r~ = r*exp(-L_prev)
// (written back in place over rbuf); k~ = k*exp(L); P = masked(r~ k~^T), diag=u;
// o_intra = P v;  M = (k~ * exp(-L_C))^T v;  Dtot = exp(-L_C).
// ---------------------------------------------------------------------------
__global__ __launch_bounds__(256) void k_chunkA(
    const float* __restrict__ eb, float* __restrict__ rb,
    const float* __restrict__ kb, const float* __restrict__ vb,
    const float* __restrict__ ub,
    float* __restrict__ ob, float* __restrict__ Mb, float* __restrict__ Db)
{
    int bh = blockIdx.x;       // 0..15 : b*NH + h ordering (h fast)
    int ck = blockIdx.y;       // 0..31
    int h = bh & 3, b = bh >> 2;
    int tok0 = b * TT + ck * CK;
    int tid = threadIdx.x;
    __shared__ float Ls[CK][128];
    __shared__ float rt[CK][129];
    __shared__ float kt[CK][129];
    __shared__ float Ps[CK][33];
    __shared__ float vsm[CK][68];
    __shared__ float Dts[128];
    // load e tile
    {
        int c = tid & 127, r0 = tid >> 7;
        #pragma unroll
        for (int i = 0; i < 16; i++) {
            int t = r0 + 2 * i;
            Ls[t][c] = eb[(size_t)(tok0 + t) * KDIM + h * DKH + c];
        }
    }
    __syncthreads();
    // per-channel cumsum + r~/k~ staging (in-place r~ to global)
    if (tid < 128) {
        int c = tid;
        float run = 0.f;
        for (int t = 0; t < CK; t++) {
            size_t g = (size_t)(tok0 + t) * KDIM + h * DKH + c;
            float e = Ls[t][c];
            float rv = rb[g];
            float kv = kb[g];
            float rs = rv * __expf(-run);
            rt[t][c] = rs;
            rb[g] = rs;
            run += e;
            kt[t][c] = kv * __expf(run);
        }
        float dt = __expf(-run);
        Dts[c] = dt;
        Db[(size_t)(bh * NCK + ck) * 128 + c] = dt;
    }
    __syncthreads();
    // P: 32x32 = 1024 entries, 4 per thread (same t, 4 consecutive s)
    {
        int p0 = tid * 4;
        int t = p0 >> 5, s0 = p0 & 31;
        float acc[4] = {0.f, 0.f, 0.f, 0.f};
        for (int k4 = 0; k4 < 128; k4 += 4) {
            float4 a = *(const float4*)&rt[t][k4];
            #pragma unroll
            for (int i = 0; i < 4; i++) {
                float4 bb = *(const float4*)&kt[s0 + i][k4];
                acc[i] += a.x * bb.x + a.y * bb.y + a.z * bb.z + a.w * bb.w;
            }
        }
        #pragma unroll
        for (int i = 0; i < 4; i++) {
            int s = s0 + i;
            float val = (s < t) ? acc[i]
                      : (s == t ? ub[(size_t)(tok0 + t) * NHD + h] : 0.f);
            Ps[t][s] = val;
        }
    }
    __syncthreads();
    // per 64-col v block: o_intra and M
    for (int jb = 0; jb < 4; jb++) {
        {
            int j = tid & 63, r0 = tid >> 6;
            #pragma unroll
            for (int i = 0; i < 8; i++) {
                int s = r0 + 4 * i;
                vsm[s][j] = vb[(size_t)(tok0 + s) * VDIM + h * DVH + jb * 64 + j];
            }
        }
        __syncthreads();
        // o: 32t x 64j, 8 per thread (2t x 4j); zeros in P handle the mask
        {
            int j0 = (tid & 15) * 4;
            int t0 = (tid >> 4) * 2;
            float o0[4] = {0.f, 0.f, 0.f, 0.f};
            float o1[4] = {0.f, 0.f, 0.f, 0.f};
            for (int s = 0; s < CK; s++) {
                float4 vv = *(const float4*)&vsm[s][j0];
                float p0v = Ps[t0][s];
                float p1v = Ps[t0 + 1][s];
                o0[0] += p0v * vv.x; o0[1] += p0v * vv.y; o0[2] += p0v * vv.z; o0[3] += p0v * vv.w;
                o1[0] += p1v * vv.x; o1[1] += p1v * vv.y; o1[2] += p1v * vv.z; o1[3] += p1v * vv.w;
            }
            size_t ob0 = (size_t)(tok0 + t0) * VDIM + h * DVH + jb * 64 + j0;
            *(float4*)(ob + ob0) = make_float4(o0[0], o0[1], o0[2], o0[3]);
            *(float4*)(ob + ob0 + VDIM) = make_float4(o1[0], o1[1], o1[2], o1[3]);
        }
        // M: 128kk x 64j, 32 per thread (4kk x 8j)
        {
            int kk0 = (tid >> 3) * 4;
            int j0 = (tid & 7) * 8;
            float m[4][8] = {};
            for (int s = 0; s < CK; s++) {
                float4 kv = *(const float4*)&kt[s][kk0];
                float4 v0 = *(const float4*)&vsm[s][j0];
                float4 v1 = *(const float4*)&vsm[s][j0 + 4];
                float ka[4] = {kv.x, kv.y, kv.z, kv.w};
                float va[8] = {v0.x, v0.y, v0.z, v0.w, v1.x, v1.y, v1.z, v1.w};
                #pragma unroll
                for (int i = 0; i < 4; i++)
                    #pragma unroll
                    for (int jj = 0; jj < 8; jj++)
                        m[i][jj] += ka[i] * va[jj];
            }
            #pragma unroll
            for (int i = 0; i < 4; i++) {
                float d = Dts[kk0 + i];
                size_t mb = ((size_t)(bh * NCK + ck) * 128 + kk0 + i) * DVH + jb * 64 + j0;
                *(float4*)(Mb + mb)     = make_float4(m[i][0] * d, m[i][1] * d, m[i][2] * d, m[i][3] * d);
                *(float4*)(Mb + mb + 4) = make_float4(m[i][4] * d, m[i][5] * d, m[i][6] * d, m[i][7] * d);
            }
        }
        __syncthreads();
    }
}

// ---------------------------------------------------------------------------
// Kernel 5b (chunkB): sequential over 32 chunks: in-place M -> chunk-init S.
// S_{c+1} = S_c*D_c + M_c ; buffer slot c ends up holding S_c (pre-chunk state).
// grid (16 bh, 16 j-slices of 16), 256 threads, 8 kk per thread.
// ---------------------------------------------------------------------------
__global__ __launch_bounds__(256) void k_chunkB(
    float* __restrict__ MS, const float* __restrict__ Db)
{
    int bh = blockIdx.x;
    int jsl = blockIdx.y;
    int tid = threadIdx.x;
    int j = jsl * 16 + (tid & 15);
    int kk0 = (tid >> 4) * 8;
    float S[8] = {};
    for (int c = 0; c < NCK; c++) {
        size_t kbase = (size_t)(bh * NCK + c) * 128;
        #pragma unroll
        for (int i = 0; i < 8; i++) {
            size_t a = (kbase + kk0 + i) * DVH + j;
            float m = MS[a];
            MS[a] = S[i];
            S[i] = S[i] * Db[kbase + kk0 + i] + m;
        }
    }
}

// ---------------------------------------------------------------------------
// Kernel 5c (chunkC): o += r~ @ S_chunk   ([32x128]@[128x256] per (bh,chunk))
// ---------------------------------------------------------------------------
__global__ __launch_bounds__(256) void k_chunkC(
    const float* __restrict__ rb, const float* __restrict__ Sb,
    float* __restrict__ ob)
{
    int bh = blockIdx.x, ck = blockIdx.y;
    int h = bh & 3, b = bh >> 2;
    int tok0 = b * TT + ck * CK;
    int tid = threadIdx.x;
    __shared__ float rsT[128][33];
    {
        int c = tid & 127, r0 = tid >> 7;
        #pragma unroll
        for (int i = 0; i < 16; i++) {
            int t = r0 + 2 * i;
            rsT[c][t] = rb[(size_t)(tok0 + t) * KDIM + h * DKH + c];
        }
    }
    __syncthreads();
    int t0 = (tid >> 5) * 4;
    int j0 = (tid & 31) * 8;
    float acc[4][8] = {};
    size_t sbase = (size_t)(bh * NCK + ck) * 128 * DVH;
    for (int kk = 0; kk < 128; kk++) {
        float4 a = *(const float4*)&rsT[kk][t0];
        const float* srow = Sb + sbase + (size_t)kk * DVH + j0;
        float4 s0 = *(const float4*)(srow);
        float4 s1 = *(const float4*)(srow + 4);
        float aa[4] = {a.x, a.y, a.z, a.w};
        float sv[8] = {s0.x, s0.y, s0.z, s0.w, s1.x, s1.y, s1.z, s1.w};
        #pragma unroll
        for (int i = 0; i < 4; i++)
            #pragma unroll
            for (int jj = 0; jj < 8; jj++)
                acc[i][jj] += aa[i] * sv[jj];
    }
    #pragma unroll
    for (int i = 0; i < 4; i++) {
        size_t oa = (size_t)(tok0 + t0 + i) * VDIM + h * DVH + j0;
        float4 c0 = *(const float4*)(ob + oa);
        float4 c1 = *(const float4*)(ob + oa + 4);
        c0.x += acc[i][0]; c0.y += acc[i][1]; c0.z += acc[i][2]; c0.w += acc[i][3];
        c1.x += acc[i][4]; c1.y += acc[i][5]; c1.z += acc[i][6]; c1.w += acc[i][7];
        *(float4*)(ob + oa) = c0;
        *(float4*)(ob + oa + 4) = c1;
    }
}

// ---------------------------------------------------------------------------
// Kernel 6: per-head groupnorm + affine + silu(g) gate
// ---------------------------------------------------------------------------
__global__ __launch_bounds__(256) void k_gn(
    const float* __restrict__ o, const float* __restrict__ g,
    const float* __restrict__ gw, const float* __restrict__ gb,
    float* __restrict__ y)
{
    int gidx = blockIdx.x;           // (b*T+t)*NH + h
    int h = gidx & (NHD - 1);
    int tid = threadIdx.x;
    size_t mtok = (size_t)(gidx >> 2);
    size_t base = mtok * VDIM + (size_t)h * DVH;
    float x = o[base + tid];
    float s = x, s2 = x * x;
    #pragma unroll
    for (int m = 32; m; m >>= 1) { s += __shfl_down(s, m); s2 += __shfl_down(s2, m); }
    __shared__ float as_[4], bs_[4];
    if ((tid & 63) == 0) { as_[tid >> 6] = s; bs_[tid >> 6] = s2; }
    __syncthreads();
    s = as_[0] + as_[1] + as_[2] + as_[3];
    s2 = bs_[0] + bs_[1] + bs_[2] + bs_[3];
    float mean = s * (1.f / DVH);
    float var = s2 * (1.f / DVH) - mean * mean;
    float inv = rsqrtf(var + 1e-5f);
    int c = h * DVH + tid;
    float gv = g[mtok * VDIM + c];
    float sig = 1.f / (1.f + __expf(-gv));
    y[mtok * VDIM + c] = ((x - mean) * inv * gw[c] + gb[c]) * (gv * sig);
}

// ---------------------------------------------------------------------------
extern "C" void kernel_launch(void* const* d_in, const int* in_sizes, int n_in,
                              void* d_out, int out_size, void* d_ws, size_t ws_size,
                              hipStream_t stream)
{
    const float* h        = (const float*)d_in[0];
    const float* x_mu     = (const float*)d_in[1];
    const float* xl_w1    = (const float*)d_in[2];
    const float* xl_w2    = (const float*)d_in[3];
    const float* xl_b2    = (const float*)d_in[4];
    const float* x_out_w  = (const float*)d_in[5];
    const float* x_bias   = (const float*)d_in[6];
    const float* r_w      = (const float*)d_in[7];
    const float* w_w1     = (const float*)d_in[8];
    const float* w_w2     = (const float*)d_in[9];
    const float* w_b      = (const float*)d_in[10];
    const float* k_w      = (const float*)d_in[11];
    const float* v_w      = (const float*)d_in[12];
    const float* g_w      = (const float*)d_in[13];
    const float* bonus    = (const float*)d_in[14];
    const float* gn_w     = (const float*)d_in[15];
    const float* gn_b     = (const float*)d_in[16];
    const float* o_w      = (const float*)d_in[17];
    float* out = (float*)d_out;

    // Workspace overlay (peak 36,388,864 floats = 145.6 MB; round-1 used 146.3 MB OK)
    float* ws = (float*)d_ws;
    float* A0   = ws;                  // 4,194,304 : Xr, then obuf
    float* A1   = A0 + 4194304;        // 4,194,304 : Xw, then Mbuf head, then ybuf
    float* A2   = A1 + 4194304;        // Xk
    float* A3   = A2 + 4194304;        // Xv
    float* A4   = A3 + 4194304;        // Xg
    float* A5   = A4 + 4194304;        // 655,360 : x1, then w1t
    float* vbuf = A5 + 655360;         // 4,194,304
    float* gbuf = vbuf + 4194304;      // 4,194,304
    float* rbuf = gbuf + 4194304;      // 2,097,152 (becomes r~ in place)
    float* kbuf = rbuf + 2097152;      // 2,097,152
    float* ebuf = kbuf + 2097152;      // 2,097,152
    float* ubuf = ebuf + 2097152;      // 16,384
    float* Dbuf = ubuf + 16384;        // 65,536

    float* Xr = A0; float* Xw = A1; float* Xk = A2; float* Xv = A3; float* Xg = A4;
    float* x1 = A5; float* w1t = A5;   // w1t reuses x1 (x1 dead after k_mix)
    float* obuf = A0;                  // Xr dead after r-projection
    float* Mbuf = A1;                  // spans A1..A4 = 16,777,216 floats exactly
    float* ybuf = A1;                  // after chunkC consumed S

    k_lora_x<<<NTOK, 256, 0, stream>>>(h, x_mu, xl_w1, xl_w2, xl_b2, x1);
    k_mix<<<NTOK, 256, 0, stream>>>(h, x1, x_out_w, x_bias, Xr, Xw, Xk, Xv, Xg);

    k_gemm<0><<<dim3(NTOK / 64, KDIM / 64), 256, 0, stream>>>(Xr, r_w, nullptr, rbuf, NTOK, KDIM, HH);
    k_gemm<0><<<dim3(NTOK / 64, KDIM / 64), 256, 0, stream>>>(Xk, k_w, nullptr, kbuf, NTOK, KDIM, HH);
    k_gemm<0><<<dim3(NTOK / 64, VDIM / 64), 256, 0, stream>>>(Xv, v_w, nullptr, vbuf, NTOK, VDIM, HH);
    k_gemm<0><<<dim3(NTOK / 64, VDIM / 64), 256, 0, stream>>>(Xg, g_w, nullptr, gbuf, NTOK, VDIM, HH);
    k_gemm<1><<<dim3(NTOK / 64, GG / 64), 256, 0, stream>>>(Xw, w_w1, nullptr, w1t, NTOK, GG, HH);
    k_gemm<2><<<dim3(NTOK / 64, KDIM / 64), 256, 0, stream>>>(w1t, w_w2, w_b, ebuf, NTOK, KDIM, GG);

    k_bonus<<<NTOK * NHD, 128, 0, stream>>>(rbuf, kbuf, bonus, ubuf);

    k_chunkA<<<dim3(BB * NHD, NCK), 256, 0, stream>>>(ebuf, rbuf, kbuf, vbuf, ubuf, obuf, Mbuf, Dbuf);
    k_chunkB<<<dim3(BB * NHD, 16), 256, 0, stream>>>(Mbuf, Dbuf);
    k_chunkC<<<dim3(BB * NHD, NCK), 256, 0, stream>>>(rbuf, Mbuf, obuf);

    k_gn<<<NTOK * NHD, 256, 0, stream>>>(obuf, gbuf, gn_w, gn_b, ybuf);

    k_gemm<0><<<dim3(NTOK / 64, HH / 64), 256, 0, stream>>>(ybuf, o_w, nullptr, out, NTOK, HH, VDIM);
}

// Round 5
// 610.614 us; speedup vs baseline: 3.7316x; 1.9298x over previous
//
#include <hip/hip_runtime.h>
#include <hip/hip_bf16.h>
#include <math.h>

// Problem constants
static constexpr int BB = 4;
static constexpr int TT = 1024;
static constexpr int HH = 1024;
static constexpr int NHD = 4;
static constexpr int KDIM = 512;
static constexpr int VDIM = 1024;
static constexpr int DKH = 128;   // KD / NH
static constexpr int DVH = 256;   // VD / NH
static constexpr int RR = 32;
static constexpr int R5D = 160;
static constexpr int GG = 64;
static constexpr int NTOK = BB * TT;   // 4096
static constexpr int CK = 32;          // chunk length
static constexpr int NCK = TT / CK;    // 32 chunks per sequence

typedef __bf16 bf16x8 __attribute__((ext_vector_type(8)));
typedef float f32x4 __attribute__((ext_vector_type(4)));
typedef __hip_bfloat16 bf16;

static __device__ inline unsigned short f2u(float v) {
    __hip_bfloat16 b = __float2bfloat16(v);
    unsigned short u; __builtin_memcpy(&u, &b, 2); return u;
}
static __device__ inline float u2f(unsigned short u) {
    __hip_bfloat16 b; __builtin_memcpy(&b, &u, 2); return __bfloat162float(b);
}

// ---------------------------------------------------------------------------
// Kernel 0: f32 -> bf16 hi/lo pair (weights)
// ---------------------------------------------------------------------------
__global__ __launch_bounds__(256) void k_f2b2(
    const float* __restrict__ s, bf16* __restrict__ hi, bf16* __restrict__ lo, int n)
{
    int i = (blockIdx.x * 256 + threadIdx.x) * 8;
    if (i >= n) return;
    #pragma unroll
    for (int j = 0; j < 8; j++) {
        float v = s[i + j];
        bf16 h = __float2bfloat16(v);
        float r = v - __bfloat162float(h);
        hi[i + j] = h;
        lo[i + j] = __float2bfloat16(r);
    }
}

// ---------------------------------------------------------------------------
// Kernel 1: x_lerp = h + (h_prev - h)*x_proj_mu ; x1 = tanh(tanh(x_lerp@w1^T)@w2^T + b2)
// ---------------------------------------------------------------------------
__global__ __launch_bounds__(256) void k_lora_x(
    const float* __restrict__ h, const float* __restrict__ mu,
    const float* __restrict__ w1, const float* __restrict__ w2,
    const float* __restrict__ b2, float* __restrict__ x1out)
{
    int m = blockIdx.x;            // token index (b*T + t)
    int t = m & (TT - 1);
    int tid = threadIdx.x;
    const float* hc = h + (size_t)m * HH;
    __shared__ float xs[256];
    __shared__ float part[8][32];
    __shared__ float t0[RR];
    int r = tid & 31, seg = tid >> 5;
    float acc = 0.f;
    for (int c = 0; c < HH; c += 256) {
        int hh = c + tid;
        float cur = hc[hh];
        float prev = (t > 0) ? hc[hh - HH] : 0.f;
        xs[tid] = cur + (prev - cur) * mu[hh];
        __syncthreads();
        const float* wrow = w1 + (size_t)r * HH + c + seg * 32;
        const float* xrow = xs + seg * 32;
        #pragma unroll
        for (int j = 0; j < 32; j++) acc += xrow[j] * wrow[j];
        __syncthreads();
    }
    part[seg][r] = acc;
    __syncthreads();
    if (tid < 32) {
        float s = 0.f;
        #pragma unroll
        for (int q = 0; q < 8; q++) s += part[q][tid];
        t0[tid] = tanhf(s);
    }
    __syncthreads();
    if (tid < R5D) {
        float s = b2[tid];
        const float* w2r = w2 + (size_t)tid * RR;
        #pragma unroll
        for (int q = 0; q < RR; q++) s += t0[q] * w2r[q];
        x1out[(size_t)m * R5D + tid] = tanhf(s);
    }
}

// ---------------------------------------------------------------------------
// Kernel 2: tiled mix: mus = einsum(x1, x_out_w) + x_bias; X_n = h + delta*mu_n
// 64 tokens x 64 h per block, loop over n. Xr/Xk/Xv/Xg bf16, Xw f32.
// ---------------------------------------------------------------------------
__global__ __launch_bounds__(256) void k_mix(
    const float* __restrict__ h, const float* __restrict__ x1,
    const float* __restrict__ xow, const float* __restrict__ xb,
    bf16* __restrict__ xr, float* __restrict__ xw,
    bf16* __restrict__ xk, bf16* __restrict__ xv, bf16* __restrict__ xg)
{
    int m0 = blockIdx.x * 64;
    int h0 = blockIdx.y * 64;
    int tid = threadIdx.x;
    __shared__ float cur[64][65];
    __shared__ float dlt[64][65];
    __shared__ float x1s[64][33];
    __shared__ float xos[64][33];
    {
        int lr = tid >> 2, lc = (tid & 3) * 16;
        int m = m0 + lr;
        int t = m & (TT - 1);
        const float* hp = h + (size_t)m * HH + h0 + lc;
        #pragma unroll
        for (int j = 0; j < 16; j += 4) {
            float4 c4 = *(const float4*)(hp + j);
            float4 p4 = make_float4(0.f, 0.f, 0.f, 0.f);
            if (t > 0) p4 = *(const float4*)(hp + j - HH);
            cur[lr][lc + j + 0] = c4.x; dlt[lr][lc + j + 0] = p4.x - c4.x;
            cur[lr][lc + j + 1] = c4.y; dlt[lr][lc + j + 1] = p4.y - c4.y;
            cur[lr][lc + j + 2] = c4.z; dlt[lr][lc + j + 2] = p4.z - c4.z;
            cur[lr][lc + j + 3] = c4.w; dlt[lr][lc + j + 3] = p4.w - c4.w;
        }
    }
    int tx = tid & 15, ty = tid >> 4;
    int rr = tid >> 2, cc = (tid & 3) * 8;
    for (int n = 0; n < 5; n++) {
        float4 xa = *(const float4*)(x1 + (size_t)(m0 + rr) * R5D + n * 32 + cc);
        float4 xa2 = *(const float4*)(x1 + (size_t)(m0 + rr) * R5D + n * 32 + cc + 4);
        float4 wa = *(const float4*)(xow + (size_t)(h0 + rr) * R5D + n * 32 + cc);
        float4 wa2 = *(const float4*)(xow + (size_t)(h0 + rr) * R5D + n * 32 + cc + 4);
        __syncthreads();   // previous-iter reads done (also covers cur/dlt on n=0)
        x1s[rr][cc + 0] = xa.x;  x1s[rr][cc + 1] = xa.y;
        x1s[rr][cc + 2] = xa.z;  x1s[rr][cc + 3] = xa.w;
        x1s[rr][cc + 4] = xa2.x; x1s[rr][cc + 5] = xa2.y;
        x1s[rr][cc + 6] = xa2.z; x1s[rr][cc + 7] = xa2.w;
        xos[rr][cc + 0] = wa.x;  xos[rr][cc + 1] = wa.y;
        xos[rr][cc + 2] = wa.z;  xos[rr][cc + 3] = wa.w;
        xos[rr][cc + 4] = wa2.x; xos[rr][cc + 5] = wa2.y;
        xos[rr][cc + 6] = wa2.z; xos[rr][cc + 7] = wa2.w;
        __syncthreads();
        float acc[4][4] = {};
        #pragma unroll 8
        for (int r2 = 0; r2 < 32; r2++) {
            float a[4], b[4];
            #pragma unroll
            for (int i = 0; i < 4; i++) a[i] = x1s[ty * 4 + i][r2];
            #pragma unroll
            for (int j = 0; j < 4; j++) b[j] = xos[tx * 4 + j][r2];
            #pragma unroll
            for (int i = 0; i < 4; i++)
                #pragma unroll
                for (int j = 0; j < 4; j++)
                    acc[i][j] += a[i] * b[j];
        }
        #pragma unroll
        for (int i = 0; i < 4; i++) {
            int m = m0 + ty * 4 + i;
            #pragma unroll
            for (int j = 0; j < 4; j++) {
                int hh = h0 + tx * 4 + j;
                float muv = acc[i][j] + xb[n * HH + hh];
                float val = cur[ty * 4 + i][tx * 4 + j] + dlt[ty * 4 + i][tx * 4 + j] * muv;
                size_t idx = (size_t)m * HH + hh;
                if (n == 0)      xr[idx] = __float2bfloat16(val);
                else if (n == 1) xw[idx] = val;
                else if (n == 2) xk[idx] = __float2bfloat16(val);
                else if (n == 3) xv[idx] = __float2bfloat16(val);
                else             xg[idx] = __float2bfloat16(val);
            }
        }
    }
}

// ---------------------------------------------------------------------------
// Kernel 3a: bf16 MFMA GEMM  C[M,N] f32 (= or +=) A[M,K]bf16 @ B[N,K]bf16^T
// 128x128 tile, BK=32, 4 waves, 4x4 fragments of 16x16x32 per wave.
// ---------------------------------------------------------------------------
template <int ACC>
__global__ __launch_bounds__(256) void k_gemm_bf16(
    const bf16* __restrict__ A, const bf16* __restrict__ B,
    float* __restrict__ C, int M, int N, int K)
{
    __shared__ unsigned short As[128 * 32];
    __shared__ unsigned short Bs[128 * 32];
    int tid = threadIdx.x;
    int bm = blockIdx.x * 128, bn = blockIdx.y * 128;
    int lane = tid & 63, w = tid >> 6;
    int wr = w >> 1, wc = w & 1;
    const unsigned short* A16 = (const unsigned short*)A;
    const unsigned short* B16 = (const unsigned short*)B;
    f32x4 acc[4][4];
    #pragma unroll
    for (int i = 0; i < 4; i++)
        #pragma unroll
        for (int j = 0; j < 4; j++)
            acc[i][j] = (f32x4){0.f, 0.f, 0.f, 0.f};
    int ch0 = tid, ch1 = tid + 256;
    int r0c = ch0 >> 2, c0c = (ch0 & 3) * 8;
    int r1c = ch1 >> 2, c1c = (ch1 & 3) * 8;
    int fr = lane & 15, kb = (lane >> 4) * 8;
    for (int k0 = 0; k0 < K; k0 += 32) {
        uint4 a0 = *(const uint4*)(A16 + (size_t)(bm + r0c) * K + k0 + c0c);
        uint4 a1 = *(const uint4*)(A16 + (size_t)(bm + r1c) * K + k0 + c1c);
        uint4 b0 = *(const uint4*)(B16 + (size_t)(bn + r0c) * K + k0 + c0c);
        uint4 b1 = *(const uint4*)(B16 + (size_t)(bn + r1c) * K + k0 + c1c);
        __syncthreads();
        *(uint4*)(As + ch0 * 8) = a0;
        *(uint4*)(As + ch1 * 8) = a1;
        *(uint4*)(Bs + ch0 * 8) = b0;
        *(uint4*)(Bs + ch1 * 8) = b1;
        __syncthreads();
        bf16x8 af[4], bf_[4];
        #pragma unroll
        for (int i = 0; i < 4; i++) {
            af[i]  = *(const bf16x8*)(As + (wr * 64 + i * 16 + fr) * 32 + kb);
            bf_[i] = *(const bf16x8*)(Bs + (wc * 64 + i * 16 + fr) * 32 + kb);
        }
        #pragma unroll
        for (int i = 0; i < 4; i++)
            #pragma unroll
            for (int j = 0; j < 4; j++)
                acc[i][j] = __builtin_amdgcn_mfma_f32_16x16x32_bf16(af[i], bf_[j], acc[i][j], 0, 0, 0);
    }
    int er = (lane >> 4) * 4, ec = lane & 15;
    #pragma unroll
    for (int i = 0; i < 4; i++) {
        int gr = bm + wr * 64 + i * 16 + er;
        #pragma unroll
        for (int j = 0; j < 4; j++) {
            int gc = bn + wc * 64 + j * 16 + ec;
            #pragma unroll
            for (int q = 0; q < 4; q++) {
                size_t idx = (size_t)(gr + q) * N + gc;
                if (ACC) C[idx] += acc[i][j][q];
                else     C[idx] = acc[i][j][q];
            }
        }
    }
}

// ---------------------------------------------------------------------------
// Kernel 3b: fp32 GEMM (w-path only)  C = A @ B^T  (+ epilogue)
// EPI: 1 = tanh, 2 = exp(x + bias[col])
// ---------------------------------------------------------------------------
template <int EPI>
__global__ __launch_bounds__(256) void k_gemm(
    const float* __restrict__ A, const float* __restrict__ Bm,
    const float* __restrict__ bias, float* __restrict__ C,
    int M, int N, int K)
{
    __shared__ float As[16][68];
    __shared__ float Bs[16][68];
    int tid = threadIdx.x;
    int bm = blockIdx.x * 64, bn = blockIdx.y * 64;
    int tx = tid & 15, ty = tid >> 4;
    int lr = tid >> 2;
    int lk = (tid & 3) * 4;
    float acc[4][4] = {};
    for (int k0 = 0; k0 < K; k0 += 16) {
        float4 av = *(const float4*)(A + (size_t)(bm + lr) * K + k0 + lk);
        float4 bv = *(const float4*)(Bm + (size_t)(bn + lr) * K + k0 + lk);
        As[lk + 0][lr] = av.x; As[lk + 1][lr] = av.y;
        As[lk + 2][lr] = av.z; As[lk + 3][lr] = av.w;
        Bs[lk + 0][lr] = bv.x; Bs[lk + 1][lr] = bv.y;
        Bs[lk + 2][lr] = bv.z; Bs[lk + 3][lr] = bv.w;
        __syncthreads();
        #pragma unroll
        for (int kk = 0; kk < 16; kk++) {
            float4 a4 = *(const float4*)&As[kk][ty * 4];
            float4 b4 = *(const float4*)&Bs[kk][tx * 4];
            float aa[4] = {a4.x, a4.y, a4.z, a4.w};
            float bb[4] = {b4.x, b4.y, b4.z, b4.w};
            #pragma unroll
            for (int i = 0; i < 4; i++)
                #pragma unroll
                for (int j = 0; j < 4; j++)
                    acc[i][j] += aa[i] * bb[j];
        }
        __syncthreads();
    }
    #pragma unroll
    for (int i = 0; i < 4; i++) {
        int row = bm + ty * 4 + i;
        int col = bn + tx * 4;
        float4 ov;
        float vv[4];
        #pragma unroll
        for (int j = 0; j < 4; j++) {
            float v = acc[i][j];
            if (EPI == 1) v = tanhf(v);
            else if (EPI == 2) v = __expf(v + bias[col + j]);
            vv[j] = v;
        }
        ov.x = vv[0]; ov.y = vv[1]; ov.z = vv[2]; ov.w = vv[3];
        *(float4*)(C + (size_t)row * N + col) = ov;
    }
}

// ---------------------------------------------------------------------------
// Kernel 4: bonus dot  u = sum_k r*bonus*k  (raw r,k — BEFORE chunkA1)
// ---------------------------------------------------------------------------
__global__ __launch_bounds__(128) void k_bonus(
    const float* __restrict__ r, const float* __restrict__ k,
    const float* __restrict__ bonus, float* __restrict__ u)
{
    int g = blockIdx.x;            // (b*T+t)*NH + h
    int h = g & (NHD - 1);
    int tid = threadIdx.x;
    size_t base = (size_t)g * DKH;
    float p = r[base + tid] * k[base + tid] * bonus[h * DKH + tid];
    #pragma unroll
    for (int m = 32; m; m >>= 1) p += __shfl_down(p, m);
    __shared__ float wsum[2];
    if ((tid & 63) == 0) wsum[tid >> 6] = p;
    __syncthreads();
    if (tid == 0) u[g] = wsum[0] + wsum[1];
}

// ---------------------------------------------------------------------------
// Kernel 5a (chunkA1): cumsum decay; r~ and k~ written IN PLACE (f32);
// M = (k~ * Dtot)^T v; Dtot out.  (no P / o_intra here anymore)
// ---------------------------------------------------------------------------
__global__ __launch_bounds__(256) void k_chunkA1(
    const float* __restrict__ eb, float* __restrict__ rb,
    float* __restrict__ kb, const float* __restrict__ vb,
    float* __restrict__ Mb, float* __restrict__ Db)
{
    int bh = blockIdx.x;       // b*NH + h (h fast)
    int ck = blockIdx.y;       // 0..31
    int h = bh & 3, b = bh >> 2;
    int tok0 = b * TT + ck * CK;
    int tid = threadIdx.x;
    __shared__ float Ls[CK][128];
    __shared__ float kt[CK][129];
    __shared__ float vsm[CK][68];
    __shared__ float Dts[128];
    {
        int c = tid & 127, r0 = tid >> 7;
        #pragma unroll
        for (int i = 0; i < 16; i++) {
            int t = r0 + 2 * i;
            Ls[t][c] = eb[(size_t)(tok0 + t) * KDIM + h * DKH + c];
        }
    }
    __syncthreads();
    if (tid < 128) {
        int c = tid;
        float run = 0.f;
        for (int t = 0; t < CK; t++) {
            size_t g = (size_t)(tok0 + t) * KDIM + h * DKH + c;
            float e = Ls[t][c];
            float rv = rb[g];
            float kv = kb[g];
            rb[g] = rv * __expf(-run);
            run += e;
            float ks = kv * __expf(run);
            kt[t][c] = ks;
            kb[g] = ks;
        }
        float dt = __expf(-run);
        Dts[c] = dt;
        Db[(size_t)(bh * NCK + ck) * 128 + c] = dt;
    }
    __syncthreads();
    for (int jb = 0; jb < 4; jb++) {
        {
            int j = tid & 63, r0 = tid >> 6;
            #pragma unroll
            for (int i = 0; i < 8; i++) {
                int s = r0 + 4 * i;
                vsm[s][j] = vb[(size_t)(tok0 + s) * VDIM + h * DVH + jb * 64 + j];
            }
        }
        __syncthreads();
        {
            int kk0 = (tid >> 3) * 4;
            int j0 = (tid & 7) * 8;
            float m[4][8] = {};
            for (int s = 0; s < CK; s++) {
                float4 kv = *(const float4*)&kt[s][kk0];
                float4 v0 = *(const float4*)&vsm[s][j0];
                float4 v1 = *(const float4*)&vsm[s][j0 + 4];
                float ka[4] = {kv.x, kv.y, kv.z, kv.w};
                float va[8] = {v0.x, v0.y, v0.z, v0.w, v1.x, v1.y, v1.z, v1.w};
                #pragma unroll
                for (int i = 0; i < 4; i++)
                    #pragma unroll
                    for (int jj = 0; jj < 8; jj++)
                        m[i][jj] += ka[i] * va[jj];
            }
            #pragma unroll
            for (int i = 0; i < 4; i++) {
                float d = Dts[kk0 + i];
                size_t mb = ((size_t)(bh * NCK + ck) * 128 + kk0 + i) * DVH + jb * 64 + j0;
                *(float4*)(Mb + mb)     = make_float4(m[i][0] * d, m[i][1] * d, m[i][2] * d, m[i][3] * d);
                *(float4*)(Mb + mb + 4) = make_float4(m[i][4] * d, m[i][5] * d, m[i][6] * d, m[i][7] * d);
            }
        }
        __syncthreads();
    }
}

// ---------------------------------------------------------------------------
// Kernel 5b (chunkB): sequential over chunks: in-place M -> pre-chunk S.
// ---------------------------------------------------------------------------
__global__ __launch_bounds__(256) void k_chunkB(
    float* __restrict__ MS, const float* __restrict__ Db)
{
    int bh = blockIdx.x;
    int jsl = blockIdx.y;
    int tid = threadIdx.x;
    int j = jsl * 16 + (tid & 15);
    int kk0 = (tid >> 4) * 8;
    float S[8] = {};
    for (int c = 0; c < NCK; c++) {
        size_t kbase = (size_t)(bh * NCK + c) * 128;
        #pragma unroll
        for (int i = 0; i < 8; i++) {
            size_t a = (kbase + kk0 + i) * DVH + j;
            float m = MS[a];
            MS[a] = S[i];
            S[i] = S[i] * Db[kbase + kk0 + i] + m;
        }
    }
}

// ---------------------------------------------------------------------------
// Kernel 5c (chunkCG, fused): per (bh,ck) 32-token strip:
// P = mask(r~ k~^T, diag=u); o = P@v + r~@S (f32 regs); groupnorm; silu(g) gate;
// y (f32) written IN PLACE over v. Thread owns 4 tokens x 8 cols.
// ---------------------------------------------------------------------------
__global__ __launch_bounds__(256) void k_chunkCG(
    const float* __restrict__ rb, const float* __restrict__ kb,
    float* __restrict__ vb, const float* __restrict__ ub,
    const float* __restrict__ Sb, const float* __restrict__ gb_,
    const float* __restrict__ gnw, const float* __restrict__ gnb)
{
    int bh = blockIdx.x, ck = blockIdx.y;
    int h = bh & 3, b = bh >> 2;
    int tok0 = b * TT + ck * CK;
    int tid = threadIdx.x;
    __shared__ float rt[CK][129];
    __shared__ float kt[CK][129];
    __shared__ float Ps[CK][33];
    __shared__ float vsm[CK][260];
    // stage r~, k~
    #pragma unroll
    for (int i = 0; i < 16; i++) {
        int idx = i * 256 + tid;
        int t = idx >> 7, c = idx & 127;
        size_t g = (size_t)(tok0 + t) * KDIM + h * DKH + c;
        rt[t][c] = rb[g];
        kt[t][c] = kb[g];
    }
    // stage full v strip [32][256]
    {
        int r0 = tid >> 3, c0 = (tid & 7) * 32;
        const float* vp = vb + (size_t)(tok0 + r0) * VDIM + h * DVH + c0;
        #pragma unroll
        for (int j = 0; j < 32; j += 4) {
            float4 v4 = *(const float4*)(vp + j);
            vsm[r0][c0 + j + 0] = v4.x; vsm[r0][c0 + j + 1] = v4.y;
            vsm[r0][c0 + j + 2] = v4.z; vsm[r0][c0 + j + 3] = v4.w;
        }
    }
    __syncthreads();
    // P: 4 entries per thread
    {
        int p0 = tid * 4;
        int t = p0 >> 5, s0 = p0 & 31;
        float acc[4] = {0.f, 0.f, 0.f, 0.f};
        for (int k4 = 0; k4 < 128; k4 += 4) {
            float4 a = *(const float4*)&rt[t][k4];
            #pragma unroll
            for (int i = 0; i < 4; i++) {
                float4 bb = *(const float4*)&kt[s0 + i][k4];
                acc[i] += a.x * bb.x + a.y * bb.y + a.z * bb.z + a.w * bb.w;
            }
        }
        #pragma unroll
        for (int i = 0; i < 4; i++) {
            int s = s0 + i;
            Ps[t][s] = (s < t) ? acc[i]
                     : (s == t ? ub[(size_t)(tok0 + t) * NHD + h] : 0.f);
        }
    }
    __syncthreads();
    int t0 = (tid >> 5) * 4;
    int j0 = (tid & 31) * 8;
    float acc[4][8] = {};
    // intra-chunk: P @ v
    for (int s = 0; s < CK; s++) {
        float4 v0 = *(const float4*)&vsm[s][j0];
        float4 v1 = *(const float4*)&vsm[s][j0 + 4];
        float va[8] = {v0.x, v0.y, v0.z, v0.w, v1.x, v1.y, v1.z, v1.w};
        #pragma unroll
        for (int i = 0; i < 4; i++) {
            float p = Ps[t0 + i][s];
            #pragma unroll
            for (int jj = 0; jj < 8; jj++) acc[i][jj] += p * va[jj];
        }
    }
    // inter-chunk: r~ @ S
    size_t sbase = (size_t)(bh * NCK + ck) * 128 * DVH;
    for (int kk = 0; kk < 128; kk++) {
        const float* srow = Sb + sbase + (size_t)kk * DVH + j0;
        float4 s0v = *(const float4*)(srow);
        float4 s1v = *(const float4*)(srow + 4);
        float sv[8] = {s0v.x, s0v.y, s0v.z, s0v.w, s1v.x, s1v.y, s1v.z, s1v.w};
        float a0 = rt[t0 + 0][kk], a1 = rt[t0 + 1][kk];
        float a2 = rt[t0 + 2][kk], a3 = rt[t0 + 3][kk];
        #pragma unroll
        for (int jj = 0; jj < 8; jj++) {
            acc[0][jj] += a0 * sv[jj];
            acc[1][jj] += a1 * sv[jj];
            acc[2][jj] += a2 * sv[jj];
            acc[3][jj] += a3 * sv[jj];
        }
    }
    // groupnorm + affine + silu(g) gate, y f32 in place over v
    int c = h * DVH + j0;
    float4 gw0 = *(const float4*)(gnw + c);
    float4 gw1 = *(const float4*)(gnw + c + 4);
    float4 gb0 = *(const float4*)(gnb + c);
    float4 gb1 = *(const float4*)(gnb + c + 4);
    float gwv[8] = {gw0.x, gw0.y, gw0.z, gw0.w, gw1.x, gw1.y, gw1.z, gw1.w};
    float gbv[8] = {gb0.x, gb0.y, gb0.z, gb0.w, gb1.x, gb1.y, gb1.z, gb1.w};
    #pragma unroll
    for (int i = 0; i < 4; i++) {
        float sum = 0.f, sq = 0.f;
        #pragma unroll
        for (int jj = 0; jj < 8; jj++) { sum += acc[i][jj]; sq += acc[i][jj] * acc[i][jj]; }
        #pragma unroll
        for (int m = 1; m < 32; m <<= 1) {
            sum += __shfl_xor(sum, m);
            sq  += __shfl_xor(sq, m);
        }
        float mean = sum * (1.f / DVH);
        float var = sq * (1.f / DVH) - mean * mean;
        float inv = rsqrtf(var + 1e-5f);
        size_t mrow = (size_t)(tok0 + t0 + i) * VDIM + c;
        float4 g0 = *(const float4*)(gb_ + mrow);
        float4 g1 = *(const float4*)(gb_ + mrow + 4);
        float gv[8] = {g0.x, g0.y, g0.z, g0.w, g1.x, g1.y, g1.z, g1.w};
        float o8[8];
        #pragma unroll
        for (int jj = 0; jj < 8; jj++) {
            float gg = gv[jj];
            float sig = 1.f / (1.f + __expf(-gg));
            o8[jj] = ((acc[i][jj] - mean) * inv * gwv[jj] + gbv[jj]) * (gg * sig);
        }
        *(float4*)(vb + mrow)     = make_float4(o8[0], o8[1], o8[2], o8[3]);
        *(float4*)(vb + mrow + 4) = make_float4(o8[4], o8[5], o8[6], o8[7]);
    }
}

// ---------------------------------------------------------------------------
// Kernel 6: output GEMM, split precision: A f32 -> (hi+lo)bf16 on the fly;
// B given as hi/lo pair. acc = Ah@Bh + Al@Bh + Ah@Bl. C = result.
// ---------------------------------------------------------------------------
__global__ __launch_bounds__(256) void k_gemm_out(
    const float* __restrict__ A, const bf16* __restrict__ Bh,
    const bf16* __restrict__ Bl, float* __restrict__ C, int M, int N, int K)
{
    __shared__ unsigned short Ah[128 * 32];
    __shared__ unsigned short Al[128 * 32];
    __shared__ unsigned short Bhs[128 * 32];
    __shared__ unsigned short Bls[128 * 32];
    int tid = threadIdx.x;
    int bm = blockIdx.x * 128, bn = blockIdx.y * 128;
    int lane = tid & 63, w = tid >> 6;
    int wr = w >> 1, wc = w & 1;
    const unsigned short* Bh16 = (const unsigned short*)Bh;
    const unsigned short* Bl16 = (const unsigned short*)Bl;
    f32x4 acc[4][4];
    #pragma unroll
    for (int i = 0; i < 4; i++)
        #pragma unroll
        for (int j = 0; j < 4; j++)
            acc[i][j] = (f32x4){0.f, 0.f, 0.f, 0.f};
    int arow = tid >> 1, acol = (tid & 1) * 16;
    int ch0 = tid, ch1 = tid + 256;
    int r0c = ch0 >> 2, c0c = (ch0 & 3) * 8;
    int r1c = ch1 >> 2, c1c = (ch1 & 3) * 8;
    int fr = lane & 15, kb = (lane >> 4) * 8;
    for (int k0 = 0; k0 < K; k0 += 32) {
        float av[16];
        #pragma unroll
        for (int q = 0; q < 4; q++) {
            float4 t4 = *(const float4*)(A + (size_t)(bm + arow) * K + k0 + acol + q * 4);
            av[q * 4 + 0] = t4.x; av[q * 4 + 1] = t4.y;
            av[q * 4 + 2] = t4.z; av[q * 4 + 3] = t4.w;
        }
        uint4 bh0 = *(const uint4*)(Bh16 + (size_t)(bn + r0c) * K + k0 + c0c);
        uint4 bh1 = *(const uint4*)(Bh16 + (size_t)(bn + r1c) * K + k0 + c1c);
        uint4 bl0 = *(const uint4*)(Bl16 + (size_t)(bn + r0c) * K + k0 + c0c);
        uint4 bl1 = *(const uint4*)(Bl16 + (size_t)(bn + r1c) * K + k0 + c1c);
        __syncthreads();
        alignas(16) unsigned short th[16], tl[16];
        #pragma unroll
        for (int q = 0; q < 16; q++) {
            unsigned short hu = f2u(av[q]);
            th[q] = hu;
            tl[q] = f2u(av[q] - u2f(hu));
        }
        *(uint4*)(Ah + arow * 32 + acol)     = *(const uint4*)&th[0];
        *(uint4*)(Ah + arow * 32 + acol + 8) = *(const uint4*)&th[8];
        *(uint4*)(Al + arow * 32 + acol)     = *(const uint4*)&tl[0];
        *(uint4*)(Al + arow * 32 + acol + 8) = *(const uint4*)&tl[8];
        *(uint4*)(Bhs + ch0 * 8) = bh0;
        *(uint4*)(Bhs + ch1 * 8) = bh1;
        *(uint4*)(Bls + ch0 * 8) = bl0;
        *(uint4*)(Bls + ch1 * 8) = bl1;
        __syncthreads();
        bf16x8 afh[4], afl[4], bfh[4], bfl[4];
        #pragma unroll
        for (int i = 0; i < 4; i++) {
            afh[i] = *(const bf16x8*)(Ah + (wr * 64 + i * 16 + fr) * 32 + kb);
            afl[i] = *(const bf16x8*)(Al + (wr * 64 + i * 16 + fr) * 32 + kb);
            bfh[i] = *(const bf16x8*)(Bhs + (wc * 64 + i * 16 + fr) * 32 + kb);
            bfl[i] = *(const bf16x8*)(Bls + (wc * 64 + i * 16 + fr) * 32 + kb);
        }
        #pragma unroll
        for (int i = 0; i < 4; i++)
            #pragma unroll
            for (int j = 0; j < 4; j++) {
                acc[i][j] = __builtin_amdgcn_mfma_f32_16x16x32_bf16(afh[i], bfh[j], acc[i][j], 0, 0, 0);
                acc[i][j] = __builtin_amdgcn_mfma_f32_16x16x32_bf16(afl[i], bfh[j], acc[i][j], 0, 0, 0);
                acc[i][j] = __builtin_amdgcn_mfma_f32_16x16x32_bf16(afh[i], bfl[j], acc[i][j], 0, 0, 0);
            }
    }
    int er = (lane >> 4) * 4, ec = lane & 15;
    #pragma unroll
    for (int i = 0; i < 4; i++) {
        int gr = bm + wr * 64 + i * 16 + er;
        #pragma unroll
        for (int j = 0; j < 4; j++) {
            int gc = bn + wc * 64 + j * 16 + ec;
            #pragma unroll
            for (int q = 0; q < 4; q++)
                C[(size_t)(gr + q) * N + gc] = acc[i][j][q];
        }
    }
}

// ---------------------------------------------------------------------------
extern "C" void kernel_launch(void* const* d_in, const int* in_sizes, int n_in,
                              void* d_out, int out_size, void* d_ws, size_t ws_size,
                              hipStream_t stream)
{
    const float* h        = (const float*)d_in[0];
    const float* x_mu     = (const float*)d_in[1];
    const float* xl_w1    = (const float*)d_in[2];
    const float* xl_w2    = (const float*)d_in[3];
    const float* xl_b2    = (const float*)d_in[4];
    const float* x_out_w  = (const float*)d_in[5];
    const float* x_bias   = (const float*)d_in[6];
    const float* r_w      = (const float*)d_in[7];
    const float* w_w1     = (const float*)d_in[8];
    const float* w_w2     = (const float*)d_in[9];
    const float* w_b      = (const float*)d_in[10];
    const float* k_w      = (const float*)d_in[11];
    const float* v_w      = (const float*)d_in[12];
    const float* g_w      = (const float*)d_in[13];
    const float* bonus    = (const float*)d_in[14];
    const float* gn_w     = (const float*)d_in[15];
    const float* gn_b     = (const float*)d_in[16];
    const float* o_w      = (const float*)d_in[17];
    float* out = (float*)d_out;

    // Workspace overlay: total 35,733,504 floats = 142.9 MB (same as proven R4 size)
    float* ws = (float*)d_ws;
    bf16*  wbf  = (bf16*)ws;                       // 8,388,608 bf16 = 4,194,304 slots
    float* rbuf = ws + 4194304;                    // 2,097,152
    float* vbuf = ws + 6291456;                    // 4,194,304 (y f32 in place later)
    float* gbuf = ws + 10485760;                   // 4,194,304
    float* kbuf = ws + 14680064;                   // 2,097,152
    float* ebuf = ws + 16777216;                   // 2,097,152
    float* ubuf = ws + 18874368;                   // 16,384
    float* Dbuf = ws + 18890752;                   // 65,536
    float* BIG  = ws + 18956288;                   // 16,777,216 (X phase / Mbuf)

    // weight hi/lo (bf16 element offsets within wbf)
    bf16* rwb_h = wbf;                  // 524,288
    bf16* kwb_h = wbf + 524288;
    bf16* vwb_h = wbf + 1048576;        // 1,048,576
    bf16* gwb_h = wbf + 2097152;
    bf16* owb_h = wbf + 3145728;
    bf16* rwb_l = wbf + 4194304;
    bf16* kwb_l = wbf + 4718592;
    bf16* vwb_l = wbf + 5242880;
    bf16* gwb_l = wbf + 6291456;
    bf16* owb_l = wbf + 7340032;

    // X phase inside BIG
    float* Xw = BIG;                           // f32 [0 .. 4,194,304)
    bf16*  Xr = (bf16*)(BIG + 4194304);        // 2,097,152 slots each
    bf16*  Xk = (bf16*)(BIG + 6291456);
    bf16*  Xv = (bf16*)(BIG + 8388608);
    bf16*  Xg = (bf16*)(BIG + 10485760);
    float* x1  = BIG + 12582912;               // 655,360 (dead after k_mix)
    float* w1t = BIG + 13238272;               // 262,144 (dead after w2-gemm)
    float* Mbuf = BIG;                         // full 16,777,216 after X dead
    float* ybuf = vbuf;                        // y f32 in place over v

    // weight conversion (hi/lo pairs)
    k_f2b2<<<256, 256, 0, stream>>>(r_w, rwb_h, rwb_l, 524288);
    k_f2b2<<<256, 256, 0, stream>>>(k_w, kwb_h, kwb_l, 524288);
    k_f2b2<<<512, 256, 0, stream>>>(v_w, vwb_h, vwb_l, 1048576);
    k_f2b2<<<512, 256, 0, stream>>>(g_w, gwb_h, gwb_l, 1048576);
    k_f2b2<<<512, 256, 0, stream>>>(o_w, owb_h, owb_l, 1048576);

    k_lora_x<<<NTOK, 256, 0, stream>>>(h, x_mu, xl_w1, xl_w2, xl_b2, x1);
    k_mix<<<dim3(NTOK / 64, HH / 64), 256, 0, stream>>>(h, x1, x_out_w, x_bias,
                                                        Xr, Xw, Xk, Xv, Xg);

    // projections: 2-pass split-weight MFMA for r/k/v/g, fp32 for the w path
    k_gemm_bf16<0><<<dim3(NTOK / 128, KDIM / 128), 256, 0, stream>>>(Xr, rwb_h, rbuf, NTOK, KDIM, HH);
    k_gemm_bf16<1><<<dim3(NTOK / 128, KDIM / 128), 256, 0, stream>>>(Xr, rwb_l, rbuf, NTOK, KDIM, HH);
    k_gemm_bf16<0><<<dim3(NTOK / 128, KDIM / 128), 256, 0, stream>>>(Xk, kwb_h, kbuf, NTOK, KDIM, HH);
    k_gemm_bf16<1><<<dim3(NTOK / 128, KDIM / 128), 256, 0, stream>>>(Xk, kwb_l, kbuf, NTOK, KDIM, HH);
    k_gemm_bf16<0><<<dim3(NTOK / 128, VDIM / 128), 256, 0, stream>>>(Xv, vwb_h, vbuf, NTOK, VDIM, HH);
    k_gemm_bf16<1><<<dim3(NTOK / 128, VDIM / 128), 256, 0, stream>>>(Xv, vwb_l, vbuf, NTOK, VDIM, HH);
    k_gemm_bf16<0><<<dim3(NTOK / 128, VDIM / 128), 256, 0, stream>>>(Xg, gwb_h, gbuf, NTOK, VDIM, HH);
    k_gemm_bf16<1><<<dim3(NTOK / 128, VDIM / 128), 256, 0, stream>>>(Xg, gwb_l, gbuf, NTOK, VDIM, HH);
    k_gemm<1><<<dim3(NTOK / 64, GG / 64), 256, 0, stream>>>(Xw, w_w1, nullptr, w1t, NTOK, GG, HH);
    k_gemm<2><<<dim3(NTOK / 64, KDIM / 64), 256, 0, stream>>>(w1t, w_w2, w_b, ebuf, NTOK, KDIM, GG);

    k_bonus<<<NTOK * NHD, 128, 0, stream>>>(rbuf, kbuf, bonus, ubuf);

    k_chunkA1<<<dim3(BB * NHD, NCK), 256, 0, stream>>>(ebuf, rbuf, kbuf, vbuf, Mbuf, Dbuf);
    k_chunkB<<<dim3(BB * NHD, 16), 256, 0, stream>>>(Mbuf, Dbuf);
    k_chunkCG<<<dim3(BB * NHD, NCK), 256, 0, stream>>>(rbuf, kbuf, vbuf, ubuf, Mbuf,
                                                       gbuf, gn_w, gn_b);

    k_gemm_out<<<dim3(NTOK / 128, HH / 128), 256, 0, stream>>>(ybuf, owb_h, owb_l, out, NTOK, HH, VDIM);
}

// Round 6
// 461.628 us; speedup vs baseline: 4.9360x; 1.3227x over previous
//
#include <hip/hip_runtime.h>
#include <hip/hip_bf16.h>
#include <math.h>

// Problem constants
static constexpr int BB = 4;
static constexpr int TT = 1024;
static constexpr int HH = 1024;
static constexpr int NHD = 4;
static constexpr int KDIM = 512;
static constexpr int VDIM = 1024;
static constexpr int DKH = 128;   // KD / NH
static constexpr int DVH = 256;   // VD / NH
static constexpr int RR = 32;
static constexpr int R5D = 160;
static constexpr int GG = 64;
static constexpr int NTOK = BB * TT;   // 4096
static constexpr int CK = 32;          // chunk length
static constexpr int NCK = TT / CK;    // 32 chunks per sequence

typedef __bf16 bf16x8 __attribute__((ext_vector_type(8)));
typedef float f32x4 __attribute__((ext_vector_type(4)));
typedef __hip_bfloat16 bf16;

static __device__ inline unsigned short f2u(float v) {
    __hip_bfloat16 b = __float2bfloat16(v);
    unsigned short u; __builtin_memcpy(&u, &b, 2); return u;
}
static __device__ inline float u2f(unsigned short u) {
    __hip_bfloat16 b; __builtin_memcpy(&b, &u, 2); return __bfloat162float(b);
}

// ---------------------------------------------------------------------------
// Kernel 0: f32 -> bf16 hi/lo pair (weights)
// ---------------------------------------------------------------------------
__global__ __launch_bounds__(256) void k_f2b2(
    const float* __restrict__ s, bf16* __restrict__ hi, bf16* __restrict__ lo, int n)
{
    int i = (blockIdx.x * 256 + threadIdx.x) * 8;
    if (i >= n) return;
    #pragma unroll
    for (int j = 0; j < 8; j++) {
        float v = s[i + j];
        bf16 h = __float2bfloat16(v);
        float r = v - __bfloat162float(h);
        hi[i + j] = h;
        lo[i + j] = __float2bfloat16(r);
    }
}

// ---------------------------------------------------------------------------
// Kernel 1a (k_x1mm): t0[4096x32] = tanh( x_lerp @ w1^T ) via bf16 MFMA.
// x_lerp computed + converted inline during A staging; w1 converted inline.
// 64 blocks x 64 tokens; 4 waves, wave owns 16 rows; acc 1x2 frags.
// ---------------------------------------------------------------------------
__global__ __launch_bounds__(256) void k_x1mm(
    const float* __restrict__ h, const float* __restrict__ mu,
    const float* __restrict__ w1, float* __restrict__ t0)
{
    __shared__ unsigned short Al[64][40];
    __shared__ unsigned short Bl[32][40];
    int tid = threadIdx.x;
    int m0 = blockIdx.x * 64;
    int lane = tid & 63, w = tid >> 6;
    f32x4 acc[2];
    acc[0] = (f32x4){0.f, 0.f, 0.f, 0.f};
    acc[1] = (f32x4){0.f, 0.f, 0.f, 0.f};
    int ar = tid >> 2, ac0 = (tid & 3) * 8;        // A stage: 64x32, 8 per thread
    int br = tid >> 3, bc0 = (tid & 7) * 4;        // B stage: 32x32, 4 per thread
    int fr = lane & 15, kb = lane >> 4;
    int mrow = m0 + ar;
    int trow = mrow & (TT - 1);
    const float* hp = h + (size_t)mrow * HH;
    for (int k0 = 0; k0 < HH; k0 += 32) {
        float av[8];
        #pragma unroll
        for (int j = 0; j < 8; j += 4) {
            float4 c4 = *(const float4*)(hp + k0 + ac0 + j);
            float4 p4 = make_float4(0.f, 0.f, 0.f, 0.f);
            if (trow > 0) p4 = *(const float4*)(hp + k0 + ac0 + j - HH);
            float4 m4 = *(const float4*)(mu + k0 + ac0 + j);
            av[j + 0] = c4.x + (p4.x - c4.x) * m4.x;
            av[j + 1] = c4.y + (p4.y - c4.y) * m4.y;
            av[j + 2] = c4.z + (p4.z - c4.z) * m4.z;
            av[j + 3] = c4.w + (p4.w - c4.w) * m4.w;
        }
        float4 b4 = *(const float4*)(w1 + (size_t)br * HH + k0 + bc0);
        __syncthreads();
        #pragma unroll
        for (int j = 0; j < 8; j++) Al[ar][ac0 + j] = f2u(av[j]);
        Bl[br][bc0 + 0] = f2u(b4.x); Bl[br][bc0 + 1] = f2u(b4.y);
        Bl[br][bc0 + 2] = f2u(b4.z); Bl[br][bc0 + 3] = f2u(b4.w);
        __syncthreads();
        bf16x8 af = *(const bf16x8*)(&Al[w * 16 + fr][kb * 8]);
        bf16x8 bf0 = *(const bf16x8*)(&Bl[fr][kb * 8]);
        bf16x8 bf1 = *(const bf16x8*)(&Bl[16 + fr][kb * 8]);
        acc[0] = __builtin_amdgcn_mfma_f32_16x16x32_bf16(af, bf0, acc[0], 0, 0, 0);
        acc[1] = __builtin_amdgcn_mfma_f32_16x16x32_bf16(af, bf1, acc[1], 0, 0, 0);
    }
    int er = (lane >> 4) * 4, ec = lane & 15;
    #pragma unroll
    for (int j = 0; j < 2; j++) {
        #pragma unroll
        for (int q = 0; q < 4; q++) {
            int gr = m0 + w * 16 + er + q;
            t0[(size_t)gr * RR + j * 16 + ec] = tanhf(acc[j][q]);
        }
    }
}

// ---------------------------------------------------------------------------
// Kernel 1b (k_x1b): x1[4096x160] = tanh( t0 @ w2^T + b2 ).  K=32.
// 64 blocks x 64 tokens; thread = (token, 40-col group).
// ---------------------------------------------------------------------------
__global__ __launch_bounds__(256) void k_x1b(
    const float* __restrict__ t0, const float* __restrict__ w2,
    const float* __restrict__ b2, float* __restrict__ x1out)
{
    __shared__ float t0s[64][33];
    __shared__ float w2s[R5D * RR];
    __shared__ float b2s[R5D];
    int tid = threadIdx.x;
    int m0 = blockIdx.x * 64;
    {
        int row = tid >> 2, c0 = (tid & 3) * 8;
        float4 a = *(const float4*)(t0 + (size_t)(m0 + row) * RR + c0);
        float4 b = *(const float4*)(t0 + (size_t)(m0 + row) * RR + c0 + 4);
        t0s[row][c0 + 0] = a.x; t0s[row][c0 + 1] = a.y;
        t0s[row][c0 + 2] = a.z; t0s[row][c0 + 3] = a.w;
        t0s[row][c0 + 4] = b.x; t0s[row][c0 + 5] = b.y;
        t0s[row][c0 + 6] = b.z; t0s[row][c0 + 7] = b.w;
    }
    for (int i = tid; i < R5D * RR; i += 256) w2s[i] = w2[i];
    if (tid < R5D) b2s[tid] = b2[tid];
    __syncthreads();
    int tt = tid & 63, cg = tid >> 6;
    float t0r[32];
    #pragma unroll
    for (int q = 0; q < 32; q++) t0r[q] = t0s[tt][q];
    float* xo = x1out + (size_t)(m0 + tt) * R5D + cg * 40;
    for (int c = 0; c < 40; c++) {
        const float* wr = w2s + (cg * 40 + c) * RR;
        float s = b2s[cg * 40 + c];
        #pragma unroll
        for (int q = 0; q < 32; q++) s += t0r[q] * wr[q];
        xo[c] = tanhf(s);
    }
}

// ---------------------------------------------------------------------------
// Kernel 2: tiled mix: mus = einsum(x1, x_out_w) + x_bias; X_n = h + delta*mu_n
// ---------------------------------------------------------------------------
__global__ __launch_bounds__(256) void k_mix(
    const float* __restrict__ h, const float* __restrict__ x1,
    const float* __restrict__ xow, const float* __restrict__ xb,
    bf16* __restrict__ xr, float* __restrict__ xw,
    bf16* __restrict__ xk, bf16* __restrict__ xv, bf16* __restrict__ xg)
{
    int m0 = blockIdx.x * 64;
    int h0 = blockIdx.y * 64;
    int tid = threadIdx.x;
    __shared__ float cur[64][65];
    __shared__ float dlt[64][65];
    __shared__ float x1s[64][33];
    __shared__ float xos[64][33];
    {
        int lr = tid >> 2, lc = (tid & 3) * 16;
        int m = m0 + lr;
        int t = m & (TT - 1);
        const float* hp = h + (size_t)m * HH + h0 + lc;
        #pragma unroll
        for (int j = 0; j < 16; j += 4) {
            float4 c4 = *(const float4*)(hp + j);
            float4 p4 = make_float4(0.f, 0.f, 0.f, 0.f);
            if (t > 0) p4 = *(const float4*)(hp + j - HH);
            cur[lr][lc + j + 0] = c4.x; dlt[lr][lc + j + 0] = p4.x - c4.x;
            cur[lr][lc + j + 1] = c4.y; dlt[lr][lc + j + 1] = p4.y - c4.y;
            cur[lr][lc + j + 2] = c4.z; dlt[lr][lc + j + 2] = p4.z - c4.z;
            cur[lr][lc + j + 3] = c4.w; dlt[lr][lc + j + 3] = p4.w - c4.w;
        }
    }
    int tx = tid & 15, ty = tid >> 4;
    int rr = tid >> 2, cc = (tid & 3) * 8;
    for (int n = 0; n < 5; n++) {
        float4 xa = *(const float4*)(x1 + (size_t)(m0 + rr) * R5D + n * 32 + cc);
        float4 xa2 = *(const float4*)(x1 + (size_t)(m0 + rr) * R5D + n * 32 + cc + 4);
        float4 wa = *(const float4*)(xow + (size_t)(h0 + rr) * R5D + n * 32 + cc);
        float4 wa2 = *(const float4*)(xow + (size_t)(h0 + rr) * R5D + n * 32 + cc + 4);
        __syncthreads();   // previous-iter reads done (also covers cur/dlt on n=0)
        x1s[rr][cc + 0] = xa.x;  x1s[rr][cc + 1] = xa.y;
        x1s[rr][cc + 2] = xa.z;  x1s[rr][cc + 3] = xa.w;
        x1s[rr][cc + 4] = xa2.x; x1s[rr][cc + 5] = xa2.y;
        x1s[rr][cc + 6] = xa2.z; x1s[rr][cc + 7] = xa2.w;
        xos[rr][cc + 0] = wa.x;  xos[rr][cc + 1] = wa.y;
        xos[rr][cc + 2] = wa.z;  xos[rr][cc + 3] = wa.w;
        xos[rr][cc + 4] = wa2.x; xos[rr][cc + 5] = wa2.y;
        xos[rr][cc + 6] = wa2.z; xos[rr][cc + 7] = wa2.w;
        __syncthreads();
        float acc[4][4] = {};
        #pragma unroll 8
        for (int r2 = 0; r2 < 32; r2++) {
            float a[4], b[4];
            #pragma unroll
            for (int i = 0; i < 4; i++) a[i] = x1s[ty * 4 + i][r2];
            #pragma unroll
            for (int j = 0; j < 4; j++) b[j] = xos[tx * 4 + j][r2];
            #pragma unroll
            for (int i = 0; i < 4; i++)
                #pragma unroll
                for (int j = 0; j < 4; j++)
                    acc[i][j] += a[i] * b[j];
        }
        #pragma unroll
        for (int i = 0; i < 4; i++) {
            int m = m0 + ty * 4 + i;
            #pragma unroll
            for (int j = 0; j < 4; j++) {
                int hh = h0 + tx * 4 + j;
                float muv = acc[i][j] + xb[n * HH + hh];
                float val = cur[ty * 4 + i][tx * 4 + j] + dlt[ty * 4 + i][tx * 4 + j] * muv;
                size_t idx = (size_t)m * HH + hh;
                if (n == 0)      xr[idx] = __float2bfloat16(val);
                else if (n == 1) xw[idx] = val;
                else if (n == 2) xk[idx] = __float2bfloat16(val);
                else if (n == 3) xv[idx] = __float2bfloat16(val);
                else             xg[idx] = __float2bfloat16(val);
            }
        }
    }
}

// ---------------------------------------------------------------------------
// Kernel 3a (k_gemm_hl): C[M,N] f32 = A[M,K]bf16 @ (Bh+Bl)[N,K]bf16^T
// single pass, 2 MFMA per fragment pair. 128x128 tile, BK=32, 4 waves.
// ---------------------------------------------------------------------------
__global__ __launch_bounds__(256) void k_gemm_hl(
    const bf16* __restrict__ A, const bf16* __restrict__ Bh,
    const bf16* __restrict__ Bl, float* __restrict__ C, int M, int N, int K)
{
    __shared__ unsigned short As[128 * 32];
    __shared__ unsigned short Bhs[128 * 32];
    __shared__ unsigned short Bls[128 * 32];
    int tid = threadIdx.x;
    int bm = blockIdx.x * 128, bn = blockIdx.y * 128;
    int lane = tid & 63, w = tid >> 6;
    int wr = w >> 1, wc = w & 1;
    const unsigned short* A16 = (const unsigned short*)A;
    const unsigned short* Bh16 = (const unsigned short*)Bh;
    const unsigned short* Bl16 = (const unsigned short*)Bl;
    f32x4 acc[4][4];
    #pragma unroll
    for (int i = 0; i < 4; i++)
        #pragma unroll
        for (int j = 0; j < 4; j++)
            acc[i][j] = (f32x4){0.f, 0.f, 0.f, 0.f};
    int ch0 = tid, ch1 = tid + 256;
    int r0c = ch0 >> 2, c0c = (ch0 & 3) * 8;
    int r1c = ch1 >> 2, c1c = (ch1 & 3) * 8;
    int fr = lane & 15, kb = (lane >> 4) * 8;
    for (int k0 = 0; k0 < K; k0 += 32) {
        uint4 a0 = *(const uint4*)(A16 + (size_t)(bm + r0c) * K + k0 + c0c);
        uint4 a1 = *(const uint4*)(A16 + (size_t)(bm + r1c) * K + k0 + c1c);
        uint4 bh0 = *(const uint4*)(Bh16 + (size_t)(bn + r0c) * K + k0 + c0c);
        uint4 bh1 = *(const uint4*)(Bh16 + (size_t)(bn + r1c) * K + k0 + c1c);
        uint4 bl0 = *(const uint4*)(Bl16 + (size_t)(bn + r0c) * K + k0 + c0c);
        uint4 bl1 = *(const uint4*)(Bl16 + (size_t)(bn + r1c) * K + k0 + c1c);
        __syncthreads();
        *(uint4*)(As + ch0 * 8) = a0;
        *(uint4*)(As + ch1 * 8) = a1;
        *(uint4*)(Bhs + ch0 * 8) = bh0;
        *(uint4*)(Bhs + ch1 * 8) = bh1;
        *(uint4*)(Bls + ch0 * 8) = bl0;
        *(uint4*)(Bls + ch1 * 8) = bl1;
        __syncthreads();
        bf16x8 af[4], bfh[4], bfl[4];
        #pragma unroll
        for (int i = 0; i < 4; i++) {
            af[i]  = *(const bf16x8*)(As + (wr * 64 + i * 16 + fr) * 32 + kb);
            bfh[i] = *(const bf16x8*)(Bhs + (wc * 64 + i * 16 + fr) * 32 + kb);
            bfl[i] = *(const bf16x8*)(Bls + (wc * 64 + i * 16 + fr) * 32 + kb);
        }
        #pragma unroll
        for (int i = 0; i < 4; i++)
            #pragma unroll
            for (int j = 0; j < 4; j++) {
                acc[i][j] = __builtin_amdgcn_mfma_f32_16x16x32_bf16(af[i], bfh[j], acc[i][j], 0, 0, 0);
                acc[i][j] = __builtin_amdgcn_mfma_f32_16x16x32_bf16(af[i], bfl[j], acc[i][j], 0, 0, 0);
            }
    }
    int er = (lane >> 4) * 4, ec = lane & 15;
    #pragma unroll
    for (int i = 0; i < 4; i++) {
        int gr = bm + wr * 64 + i * 16 + er;
        #pragma unroll
        for (int j = 0; j < 4; j++) {
            int gc = bn + wc * 64 + j * 16 + ec;
            #pragma unroll
            for (int q = 0; q < 4; q++)
                C[(size_t)(gr + q) * N + gc] = acc[i][j][q];
        }
    }
}

// ---------------------------------------------------------------------------
// Kernel 3b: fp32 GEMM (w-path only)  C = A @ B^T  (+ epilogue)
// EPI: 1 = tanh, 2 = exp(x + bias[col])
// ---------------------------------------------------------------------------
template <int EPI>
__global__ __launch_bounds__(256) void k_gemm(
    const float* __restrict__ A, const float* __restrict__ Bm,
    const float* __restrict__ bias, float* __restrict__ C,
    int M, int N, int K)
{
    __shared__ float As[16][68];
    __shared__ float Bs[16][68];
    int tid = threadIdx.x;
    int bm = blockIdx.x * 64, bn = blockIdx.y * 64;
    int tx = tid & 15, ty = tid >> 4;
    int lr = tid >> 2;
    int lk = (tid & 3) * 4;
    float acc[4][4] = {};
    for (int k0 = 0; k0 < K; k0 += 16) {
        float4 av = *(const float4*)(A + (size_t)(bm + lr) * K + k0 + lk);
        float4 bv = *(const float4*)(Bm + (size_t)(bn + lr) * K + k0 + lk);
        As[lk + 0][lr] = av.x; As[lk + 1][lr] = av.y;
        As[lk + 2][lr] = av.z; As[lk + 3][lr] = av.w;
        Bs[lk + 0][lr] = bv.x; Bs[lk + 1][lr] = bv.y;
        Bs[lk + 2][lr] = bv.z; Bs[lk + 3][lr] = bv.w;
        __syncthreads();
        #pragma unroll
        for (int kk = 0; kk < 16; kk++) {
            float4 a4 = *(const float4*)&As[kk][ty * 4];
            float4 b4 = *(const float4*)&Bs[kk][tx * 4];
            float aa[4] = {a4.x, a4.y, a4.z, a4.w};
            float bb[4] = {b4.x, b4.y, b4.z, b4.w};
            #pragma unroll
            for (int i = 0; i < 4; i++)
                #pragma unroll
                for (int j = 0; j < 4; j++)
                    acc[i][j] += aa[i] * bb[j];
        }
        __syncthreads();
    }
    #pragma unroll
    for (int i = 0; i < 4; i++) {
        int row = bm + ty * 4 + i;
        int col = bn + tx * 4;
        float4 ov;
        float vv[4];
        #pragma unroll
        for (int j = 0; j < 4; j++) {
            float v = acc[i][j];
            if (EPI == 1) v = tanhf(v);
            else if (EPI == 2) v = __expf(v + bias[col + j]);
            vv[j] = v;
        }
        ov.x = vv[0]; ov.y = vv[1]; ov.z = vv[2]; ov.w = vv[3];
        *(float4*)(C + (size_t)row * N + col) = ov;
    }
}

// ---------------------------------------------------------------------------
// Kernel 5a (chunkA1): cumsum decay; r~ and k~ IN PLACE (f32);
// M = (k~ * Dtot)^T v; Dtot out; u = sum r*bonus*k (fused, raw r,k).
// ---------------------------------------------------------------------------
__global__ __launch_bounds__(256) void k_chunkA1(
    const float* __restrict__ eb, float* __restrict__ rb,
    float* __restrict__ kb, const float* __restrict__ vb,
    const float* __restrict__ bonus, float* __restrict__ ub,
    float* __restrict__ Mb, float* __restrict__ Db)
{
    int bh = blockIdx.x;       // b*NH + h (h fast)
    int ck = blockIdx.y;       // 0..31
    int h = bh & 3, b = bh >> 2;
    int tok0 = b * TT + ck * CK;
    int tid = threadIdx.x;
    __shared__ float Ls[CK][128];
    __shared__ float kt[CK][129];
    __shared__ float vsm[CK][68];
    __shared__ float Dts[128];
    __shared__ float up[CK][8];
    {
        int c = tid & 127, r0 = tid >> 7;
        #pragma unroll
        for (int i = 0; i < 16; i++) {
            int t = r0 + 2 * i;
            Ls[t][c] = eb[(size_t)(tok0 + t) * KDIM + h * DKH + c];
        }
    }
    __syncthreads();
    if (tid < 128) {
        int c = tid;
        float bc = bonus[h * DKH + c];
        float run = 0.f;
        for (int t = 0; t < CK; t++) {
            size_t g = (size_t)(tok0 + t) * KDIM + h * DKH + c;
            float e = Ls[t][c];
            float rv = rb[g];
            float kv = kb[g];
            rb[g] = rv * __expf(-run);
            Ls[t][c] = rv * kv * bc;      // bonus partial (e already consumed)
            run += e;
            float ks = kv * __expf(run);
            kt[t][c] = ks;
            kb[g] = ks;
        }
        float dt = __expf(-run);
        Dts[c] = dt;
        Db[(size_t)(bh * NCK + ck) * 128 + c] = dt;
    }
    __syncthreads();
    // u reduction: 256 threads = 32 t x 8 segs of 16
    {
        int t = tid >> 3, seg = tid & 7;
        float s = 0.f;
        #pragma unroll
        for (int q = 0; q < 16; q++) s += Ls[t][seg * 16 + q];
        up[t][seg] = s;
    }
    __syncthreads();
    if (tid < CK) {
        float s = 0.f;
        #pragma unroll
        for (int q = 0; q < 8; q++) s += up[tid][q];
        ub[(size_t)(tok0 + tid) * NHD + h] = s;
    }
    for (int jb = 0; jb < 4; jb++) {
        {
            int j = tid & 63, r0 = tid >> 6;
            #pragma unroll
            for (int i = 0; i < 8; i++) {
                int s = r0 + 4 * i;
                vsm[s][j] = vb[(size_t)(tok0 + s) * VDIM + h * DVH + jb * 64 + j];
            }
        }
        __syncthreads();
        {
            int kk0 = (tid >> 3) * 4;
            int j0 = (tid & 7) * 8;
            float m[4][8] = {};
            for (int s = 0; s < CK; s++) {
                float4 kv = *(const float4*)&kt[s][kk0];
                float4 v0 = *(const float4*)&vsm[s][j0];
                float4 v1 = *(const float4*)&vsm[s][j0 + 4];
                float ka[4] = {kv.x, kv.y, kv.z, kv.w};
                float va[8] = {v0.x, v0.y, v0.z, v0.w, v1.x, v1.y, v1.z, v1.w};
                #pragma unroll
                for (int i = 0; i < 4; i++)
                    #pragma unroll
                    for (int jj = 0; jj < 8; jj++)
                        m[i][jj] += ka[i] * va[jj];
            }
            #pragma unroll
            for (int i = 0; i < 4; i++) {
                float d = Dts[kk0 + i];
                size_t mb = ((size_t)(bh * NCK + ck) * 128 + kk0 + i) * DVH + jb * 64 + j0;
                *(float4*)(Mb + mb)     = make_float4(m[i][0] * d, m[i][1] * d, m[i][2] * d, m[i][3] * d);
                *(float4*)(Mb + mb + 4) = make_float4(m[i][4] * d, m[i][5] * d, m[i][6] * d, m[i][7] * d);
            }
        }
        __syncthreads();
    }
}

// ---------------------------------------------------------------------------
// Kernel 5b (chunkB): sequential over chunks: in-place M -> pre-chunk S.
// ---------------------------------------------------------------------------
__global__ __launch_bounds__(256) void k_chunkB(
    float* __restrict__ MS, const float* __restrict__ Db)
{
    int bh = blockIdx.x;
    int jsl = blockIdx.y;
    int tid = threadIdx.x;
    int j = jsl * 16 + (tid & 15);
    int kk0 = (tid >> 4) * 8;
    float S[8] = {};
    for (int c = 0; c < NCK; c++) {
        size_t kbase = (size_t)(bh * NCK + c) * 128;
        #pragma unroll
        for (int i = 0; i < 8; i++) {
            size_t a = (kbase + kk0 + i) * DVH + j;
            float m = MS[a];
            MS[a] = S[i];
            S[i] = S[i] * Db[kbase + kk0 + i] + m;
        }
    }
}

// ---------------------------------------------------------------------------
// Kernel 5c (chunkCG, fused): P = mask(r~ k~^T, diag=u); o = P@v + r~@S (f32);
// groupnorm; silu(g) gate; y f32 IN PLACE over v.
// ---------------------------------------------------------------------------
__global__ __launch_bounds__(256) void k_chunkCG(
    const float* __restrict__ rb, const float* __restrict__ kb,
    float* __restrict__ vb, const float* __restrict__ ub,
    const float* __restrict__ Sb, const float* __restrict__ gb_,
    const float* __restrict__ gnw, const float* __restrict__ gnb)
{
    int bh = blockIdx.x, ck = blockIdx.y;
    int h = bh & 3, b = bh >> 2;
    int tok0 = b * TT + ck * CK;
    int tid = threadIdx.x;
    __shared__ float rt[CK][129];
    __shared__ float kt[CK][129];
    __shared__ float Ps[CK][33];
    __shared__ float vsm[CK][260];
    #pragma unroll
    for (int i = 0; i < 16; i++) {
        int idx = i * 256 + tid;
        int t = idx >> 7, c = idx & 127;
        size_t g = (size_t)(tok0 + t) * KDIM + h * DKH + c;
        rt[t][c] = rb[g];
        kt[t][c] = kb[g];
    }
    {
        int r0 = tid >> 3, c0 = (tid & 7) * 32;
        const float* vp = vb + (size_t)(tok0 + r0) * VDIM + h * DVH + c0;
        #pragma unroll
        for (int j = 0; j < 32; j += 4) {
            float4 v4 = *(const float4*)(vp + j);
            vsm[r0][c0 + j + 0] = v4.x; vsm[r0][c0 + j + 1] = v4.y;
            vsm[r0][c0 + j + 2] = v4.z; vsm[r0][c0 + j + 3] = v4.w;
        }
    }
    __syncthreads();
    {
        int p0 = tid * 4;
        int t = p0 >> 5, s0 = p0 & 31;
        float acc[4] = {0.f, 0.f, 0.f, 0.f};
        for (int k4 = 0; k4 < 128; k4 += 4) {
            float4 a = *(const float4*)&rt[t][k4];
            #pragma unroll
            for (int i = 0; i < 4; i++) {
                float4 bb = *(const float4*)&kt[s0 + i][k4];
                acc[i] += a.x * bb.x + a.y * bb.y + a.z * bb.z + a.w * bb.w;
            }
        }
        #pragma unroll
        for (int i = 0; i < 4; i++) {
            int s = s0 + i;
            Ps[t][s] = (s < t) ? acc[i]
                     : (s == t ? ub[(size_t)(tok0 + t) * NHD + h] : 0.f);
        }
    }
    __syncthreads();
    int t0 = (tid >> 5) * 4;
    int j0 = (tid & 31) * 8;
    float acc[4][8] = {};
    for (int s = 0; s < CK; s++) {
        float4 v0 = *(const float4*)&vsm[s][j0];
        float4 v1 = *(const float4*)&vsm[s][j0 + 4];
        float va[8] = {v0.x, v0.y, v0.z, v0.w, v1.x, v1.y, v1.z, v1.w};
        #pragma unroll
        for (int i = 0; i < 4; i++) {
            float p = Ps[t0 + i][s];
            #pragma unroll
            for (int jj = 0; jj < 8; jj++) acc[i][jj] += p * va[jj];
        }
    }
    size_t sbase = (size_t)(bh * NCK + ck) * 128 * DVH;
    for (int kk = 0; kk < 128; kk++) {
        const float* srow = Sb + sbase + (size_t)kk * DVH + j0;
        float4 s0v = *(const float4*)(srow);
        float4 s1v = *(const float4*)(srow + 4);
        float sv[8] = {s0v.x, s0v.y, s0v.z, s0v.w, s1v.x, s1v.y, s1v.z, s1v.w};
        float a0 = rt[t0 + 0][kk], a1 = rt[t0 + 1][kk];
        float a2 = rt[t0 + 2][kk], a3 = rt[t0 + 3][kk];
        #pragma unroll
        for (int jj = 0; jj < 8; jj++) {
            acc[0][jj] += a0 * sv[jj];
            acc[1][jj] += a1 * sv[jj];
            acc[2][jj] += a2 * sv[jj];
            acc[3][jj] += a3 * sv[jj];
        }
    }
    int c = h * DVH + j0;
    float4 gw0 = *(const float4*)(gnw + c);
    float4 gw1 = *(const float4*)(gnw + c + 4);
    float4 gb0 = *(const float4*)(gnb + c);
    float4 gb1 = *(const float4*)(gnb + c + 4);
    float gwv[8] = {gw0.x, gw0.y, gw0.z, gw0.w, gw1.x, gw1.y, gw1.z, gw1.w};
    float gbv[8] = {gb0.x, gb0.y, gb0.z, gb0.w, gb1.x, gb1.y, gb1.z, gb1.w};
    #pragma unroll
    for (int i = 0; i < 4; i++) {
        float sum = 0.f, sq = 0.f;
        #pragma unroll
        for (int jj = 0; jj < 8; jj++) { sum += acc[i][jj]; sq += acc[i][jj] * acc[i][jj]; }
        #pragma unroll
        for (int m = 1; m < 32; m <<= 1) {
            sum += __shfl_xor(sum, m);
            sq  += __shfl_xor(sq, m);
        }
        float mean = sum * (1.f / DVH);
        float var = sq * (1.f / DVH) - mean * mean;
        float inv = rsqrtf(var + 1e-5f);
        size_t mrow = (size_t)(tok0 + t0 + i) * VDIM + c;
        float4 g0 = *(const float4*)(gb_ + mrow);
        float4 g1 = *(const float4*)(gb_ + mrow + 4);
        float gv[8] = {g0.x, g0.y, g0.z, g0.w, g1.x, g1.y, g1.z, g1.w};
        float o8[8];
        #pragma unroll
        for (int jj = 0; jj < 8; jj++) {
            float gg = gv[jj];
            float sig = 1.f / (1.f + __expf(-gg));
            o8[jj] = ((acc[i][jj] - mean) * inv * gwv[jj] + gbv[jj]) * (gg * sig);
        }
        *(float4*)(vb + mrow)     = make_float4(o8[0], o8[1], o8[2], o8[3]);
        *(float4*)(vb + mrow + 4) = make_float4(o8[4], o8[5], o8[6], o8[7]);
    }
}

// ---------------------------------------------------------------------------
// Kernel 6: output GEMM, split precision: A f32 -> (hi+lo)bf16 on the fly;
// B hi/lo pair. acc = Ah@Bh + Al@Bh + Ah@Bl.
// ---------------------------------------------------------------------------
__global__ __launch_bounds__(256) void k_gemm_out(
    const float* __restrict__ A, const bf16* __restrict__ Bh,
    const bf16* __restrict__ Bl, float* __restrict__ C, int M, int N, int K)
{
    __shared__ unsigned short Ah[128 * 32];
    __shared__ unsigned short Al[128 * 32];
    __shared__ unsigned short Bhs[128 * 32];
    __shared__ unsigned short Bls[128 * 32];
    int tid = threadIdx.x;
    int bm = blockIdx.x * 128, bn = blockIdx.y * 128;
    int lane = tid & 63, w = tid >> 6;
    int wr = w >> 1, wc = w & 1;
    const unsigned short* Bh16 = (const unsigned short*)Bh;
    const unsigned short* Bl16 = (const unsigned short*)Bl;
    f32x4 acc[4][4];
    #pragma unroll
    for (int i = 0; i < 4; i++)
        #pragma unroll
        for (int j = 0; j < 4; j++)
            acc[i][j] = (f32x4){0.f, 0.f, 0.f, 0.f};
    int arow = tid >> 1, acol = (tid & 1) * 16;
    int ch0 = tid, ch1 = tid + 256;
    int r0c = ch0 >> 2, c0c = (ch0 & 3) * 8;
    int r1c = ch1 >> 2, c1c = (ch1 & 3) * 8;
    int fr = lane & 15, kb = (lane >> 4) * 8;
    for (int k0 = 0; k0 < K; k0 += 32) {
        float av[16];
        #pragma unroll
        for (int q = 0; q < 4; q++) {
            float4 t4 = *(const float4*)(A + (size_t)(bm + arow) * K + k0 + acol + q * 4);
            av[q * 4 + 0] = t4.x; av[q * 4 + 1] = t4.y;
            av[q * 4 + 2] = t4.z; av[q * 4 + 3] = t4.w;
        }
        uint4 bh0 = *(const uint4*)(Bh16 + (size_t)(bn + r0c) * K + k0 + c0c);
        uint4 bh1 = *(const uint4*)(Bh16 + (size_t)(bn + r1c) * K + k0 + c1c);
        uint4 bl0 = *(const uint4*)(Bl16 + (size_t)(bn + r0c) * K + k0 + c0c);
        uint4 bl1 = *(const uint4*)(Bl16 + (size_t)(bn + r1c) * K + k0 + c1c);
        __syncthreads();
        alignas(16) unsigned short th[16], tl[16];
        #pragma unroll
        for (int q = 0; q < 16; q++) {
            unsigned short hu = f2u(av[q]);
            th[q] = hu;
            tl[q] = f2u(av[q] - u2f(hu));
        }
        *(uint4*)(Ah + arow * 32 + acol)     = *(const uint4*)&th[0];
        *(uint4*)(Ah + arow * 32 + acol + 8) = *(const uint4*)&th[8];
        *(uint4*)(Al + arow * 32 + acol)     = *(const uint4*)&tl[0];
        *(uint4*)(Al + arow * 32 + acol + 8) = *(const uint4*)&tl[8];
        *(uint4*)(Bhs + ch0 * 8) = bh0;
        *(uint4*)(Bhs + ch1 * 8) = bh1;
        *(uint4*)(Bls + ch0 * 8) = bl0;
        *(uint4*)(Bls + ch1 * 8) = bl1;
        __syncthreads();
        bf16x8 afh[4], afl[4], bfh[4], bfl[4];
        #pragma unroll
        for (int i = 0; i < 4; i++) {
            afh[i] = *(const bf16x8*)(Ah + (wr * 64 + i * 16 + fr) * 32 + kb);
            afl[i] = *(const bf16x8*)(Al + (wr * 64 + i * 16 + fr) * 32 + kb);
            bfh[i] = *(const bf16x8*)(Bhs + (wc * 64 + i * 16 + fr) * 32 + kb);
            bfl[i] = *(const bf16x8*)(Bls + (wc * 64 + i * 16 + fr) * 32 + kb);
        }
        #pragma unroll
        for (int i = 0; i < 4; i++)
            #pragma unroll
            for (int j = 0; j < 4; j++) {
                acc[i][j] = __builtin_amdgcn_mfma_f32_16x16x32_bf16(afh[i], bfh[j], acc[i][j], 0, 0, 0);
                acc[i][j] = __builtin_amdgcn_mfma_f32_16x16x32_bf16(afl[i], bfh[j], acc[i][j], 0, 0, 0);
                acc[i][j] = __builtin_amdgcn_mfma_f32_16x16x32_bf16(afh[i], bfl[j], acc[i][j], 0, 0, 0);
            }
    }
    int er = (lane >> 4) * 4, ec = lane & 15;
    #pragma unroll
    for (int i = 0; i < 4; i++) {
        int gr = bm + wr * 64 + i * 16 + er;
        #pragma unroll
        for (int j = 0; j < 4; j++) {
            int gc = bn + wc * 64 + j * 16 + ec;
            #pragma unroll
            for (int q = 0; q < 4; q++)
                C[(size_t)(gr + q) * N + gc] = acc[i][j][q];
        }
    }
}

// ---------------------------------------------------------------------------
extern "C" void kernel_launch(void* const* d_in, const int* in_sizes, int n_in,
                              void* d_out, int out_size, void* d_ws, size_t ws_size,
                              hipStream_t stream)
{
    const float* h        = (const float*)d_in[0];
    const float* x_mu     = (const float*)d_in[1];
    const float* xl_w1    = (const float*)d_in[2];
    const float* xl_w2    = (const float*)d_in[3];
    const float* xl_b2    = (const float*)d_in[4];
    const float* x_out_w  = (const float*)d_in[5];
    const float* x_bias   = (const float*)d_in[6];
    const float* r_w      = (const float*)d_in[7];
    const float* w_w1     = (const float*)d_in[8];
    const float* w_w2     = (const float*)d_in[9];
    const float* w_b      = (const float*)d_in[10];
    const float* k_w      = (const float*)d_in[11];
    const float* v_w      = (const float*)d_in[12];
    const float* g_w      = (const float*)d_in[13];
    const float* bonus    = (const float*)d_in[14];
    const float* gn_w     = (const float*)d_in[15];
    const float* gn_b     = (const float*)d_in[16];
    const float* o_w      = (const float*)d_in[17];
    float* out = (float*)d_out;

    // Workspace overlay: total 35,733,504 floats = 142.9 MB (proven size)
    float* ws = (float*)d_ws;
    bf16*  wbf  = (bf16*)ws;                       // 8,388,608 bf16 = 4,194,304 slots
    float* rbuf = ws + 4194304;                    // 2,097,152
    float* vbuf = ws + 6291456;                    // 4,194,304 (y f32 in place later)
    float* gbuf = ws + 10485760;                   // 4,194,304
    float* kbuf = ws + 14680064;                   // 2,097,152
    float* ebuf = ws + 16777216;                   // 2,097,152
    float* ubuf = ws + 18874368;                   // 16,384
    float* Dbuf = ws + 18890752;                   // 65,536
    float* BIG  = ws + 18956288;                   // 16,777,216 (X phase / Mbuf)

    // weight hi/lo (bf16 element offsets within wbf)
    bf16* rwb_h = wbf;                  // 524,288
    bf16* kwb_h = wbf + 524288;
    bf16* vwb_h = wbf + 1048576;        // 1,048,576
    bf16* gwb_h = wbf + 2097152;
    bf16* owb_h = wbf + 3145728;
    bf16* rwb_l = wbf + 4194304;
    bf16* kwb_l = wbf + 4718592;
    bf16* vwb_l = wbf + 5242880;
    bf16* gwb_l = wbf + 6291456;
    bf16* owb_l = wbf + 7340032;

    // X phase inside BIG (each bf16 X = 2,097,152 float slots)
    float* Xw = BIG;                           // f32 [0 .. 4,194,304)
    bf16*  Xr = (bf16*)(BIG + 4194304);
    bf16*  Xk = (bf16*)(BIG + 6291456);
    bf16*  Xv = (bf16*)(BIG + 8388608);
    bf16*  Xg = (bf16*)(BIG + 10485760);
    float* x1   = BIG + 12582912;              // 655,360  (dead after k_mix)
    float* w1t  = BIG + 13238272;              // 262,144  (dead after w2-gemm)
    float* t0bf = BIG + 13500416;              // 131,072  (dead after k_x1b)
    float* Mbuf = BIG;                         // full 16,777,216 after X dead
    float* ybuf = vbuf;                        // y f32 in place over v

    // weight conversion (hi/lo pairs)
    k_f2b2<<<256, 256, 0, stream>>>(r_w, rwb_h, rwb_l, 524288);
    k_f2b2<<<256, 256, 0, stream>>>(k_w, kwb_h, kwb_l, 524288);
    k_f2b2<<<512, 256, 0, stream>>>(v_w, vwb_h, vwb_l, 1048576);
    k_f2b2<<<512, 256, 0, stream>>>(g_w, gwb_h, gwb_l, 1048576);
    k_f2b2<<<512, 256, 0, stream>>>(o_w, owb_h, owb_l, 1048576);

    // x1 path: MFMA phase-1 + small phase-2
    k_x1mm<<<NTOK / 64, 256, 0, stream>>>(h, x_mu, xl_w1, t0bf);
    k_x1b<<<NTOK / 64, 256, 0, stream>>>(t0bf, xl_w2, xl_b2, x1);

    k_mix<<<dim3(NTOK / 64, HH / 64), 256, 0, stream>>>(h, x1, x_out_w, x_bias,
                                                        Xr, Xw, Xk, Xv, Xg);

    // projections: fused hi/lo MFMA for r/k/v/g, fp32 for the w path
    k_gemm_hl<<<dim3(NTOK / 128, KDIM / 128), 256, 0, stream>>>(Xr, rwb_h, rwb_l, rbuf, NTOK, KDIM, HH);
    k_gemm_hl<<<dim3(NTOK / 128, KDIM / 128), 256, 0, stream>>>(Xk, kwb_h, kwb_l, kbuf, NTOK, KDIM, HH);
    k_gemm_hl<<<dim3(NTOK / 128, VDIM / 128), 256, 0, stream>>>(Xv, vwb_h, vwb_l, vbuf, NTOK, VDIM, HH);
    k_gemm_hl<<<dim3(NTOK / 128, VDIM / 128), 256, 0, stream>>>(Xg, gwb_h, gwb_l, gbuf, NTOK, VDIM, HH);
    k_gemm<1><<<dim3(NTOK / 64, GG / 64), 256, 0, stream>>>(Xw, w_w1, nullptr, w1t, NTOK, GG, HH);
    k_gemm<2><<<dim3(NTOK / 64, KDIM / 64), 256, 0, stream>>>(w1t, w_w2, w_b, ebuf, NTOK, KDIM, GG);

    k_chunkA1<<<dim3(BB * NHD, NCK), 256, 0, stream>>>(ebuf, rbuf, kbuf, vbuf,
                                                       bonus, ubuf, Mbuf, Dbuf);
    k_chunkB<<<dim3(BB * NHD, 16), 256, 0, stream>>>(Mbuf, Dbuf);
    k_chunkCG<<<dim3(BB * NHD, NCK), 256, 0, stream>>>(rbuf, kbuf, vbuf, ubuf, Mbuf,
                                                       gbuf, gn_w, gn_b);

    k_gemm_out<<<dim3(NTOK / 128, HH / 128), 256, 0, stream>>>(ybuf, owb_h, owb_l, out, NTOK, HH, VDIM);
}

// Round 7
// 449.654 us; speedup vs baseline: 5.0674x; 1.0266x over previous
//
#include <hip/hip_runtime.h>
#include <hip/hip_bf16.h>
#include <math.h>

// Problem constants
static constexpr int BB = 4;
static constexpr int TT = 1024;
static constexpr int HH = 1024;
static constexpr int NHD = 4;
static constexpr int KDIM = 512;
static constexpr int VDIM = 1024;
static constexpr int DKH = 128;   // KD / NH
static constexpr int DVH = 256;   // VD / NH
static constexpr int RR = 32;
static constexpr int R5D = 160;
static constexpr int GG = 64;
static constexpr int NTOK = BB * TT;   // 4096
static constexpr int CK = 32;          // chunk length
static constexpr int NCK = TT / CK;    // 32 chunks per sequence

typedef __bf16 bf16x8 __attribute__((ext_vector_type(8)));
typedef float f32x4 __attribute__((ext_vector_type(4)));
typedef __hip_bfloat16 bf16;

static __device__ inline unsigned short f2u(float v) {
    __hip_bfloat16 b = __float2bfloat16(v);
    unsigned short u; __builtin_memcpy(&u, &b, 2); return u;
}
static __device__ inline float u2f(unsigned short u) {
    __hip_bfloat16 b; __builtin_memcpy(&b, &u, 2); return __bfloat162float(b);
}

// ---------------------------------------------------------------------------
// Kernel 0: f32 -> bf16 hi/lo pair (weights)
// ---------------------------------------------------------------------------
__global__ __launch_bounds__(256) void k_f2b2(
    const float* __restrict__ s, bf16* __restrict__ hi, bf16* __restrict__ lo, int n)
{
    int i = (blockIdx.x * 256 + threadIdx.x) * 8;
    if (i >= n) return;
    #pragma unroll
    for (int j = 0; j < 8; j++) {
        float v = s[i + j];
        bf16 h = __float2bfloat16(v);
        float r = v - __bfloat162float(h);
        hi[i + j] = h;
        lo[i + j] = __float2bfloat16(r);
    }
}

// ---------------------------------------------------------------------------
// Kernel 1a (k_x1mm): t0[4096x32] = tanh( x_lerp @ w1^T ) via bf16 MFMA.
// ---------------------------------------------------------------------------
__global__ __launch_bounds__(256) void k_x1mm(
    const float* __restrict__ h, const float* __restrict__ mu,
    const float* __restrict__ w1, float* __restrict__ t0)
{
    __shared__ unsigned short Al[64][40];
    __shared__ unsigned short Bl[32][40];
    int tid = threadIdx.x;
    int m0 = blockIdx.x * 64;
    int lane = tid & 63, w = tid >> 6;
    f32x4 acc[2];
    acc[0] = (f32x4){0.f, 0.f, 0.f, 0.f};
    acc[1] = (f32x4){0.f, 0.f, 0.f, 0.f};
    int ar = tid >> 2, ac0 = (tid & 3) * 8;        // A stage: 64x32, 8 per thread
    int br = tid >> 3, bc0 = (tid & 7) * 4;        // B stage: 32x32, 4 per thread
    int fr = lane & 15, kb = lane >> 4;
    int mrow = m0 + ar;
    int trow = mrow & (TT - 1);
    const float* hp = h + (size_t)mrow * HH;
    for (int k0 = 0; k0 < HH; k0 += 32) {
        float av[8];
        #pragma unroll
        for (int j = 0; j < 8; j += 4) {
            float4 c4 = *(const float4*)(hp + k0 + ac0 + j);
            float4 p4 = make_float4(0.f, 0.f, 0.f, 0.f);
            if (trow > 0) p4 = *(const float4*)(hp + k0 + ac0 + j - HH);
            float4 m4 = *(const float4*)(mu + k0 + ac0 + j);
            av[j + 0] = c4.x + (p4.x - c4.x) * m4.x;
            av[j + 1] = c4.y + (p4.y - c4.y) * m4.y;
            av[j + 2] = c4.z + (p4.z - c4.z) * m4.z;
            av[j + 3] = c4.w + (p4.w - c4.w) * m4.w;
        }
        float4 b4 = *(const float4*)(w1 + (size_t)br * HH + k0 + bc0);
        __syncthreads();
        #pragma unroll
        for (int j = 0; j < 8; j++) Al[ar][ac0 + j] = f2u(av[j]);
        Bl[br][bc0 + 0] = f2u(b4.x); Bl[br][bc0 + 1] = f2u(b4.y);
        Bl[br][bc0 + 2] = f2u(b4.z); Bl[br][bc0 + 3] = f2u(b4.w);
        __syncthreads();
        bf16x8 af = *(const bf16x8*)(&Al[w * 16 + fr][kb * 8]);
        bf16x8 bf0 = *(const bf16x8*)(&Bl[fr][kb * 8]);
        bf16x8 bf1 = *(const bf16x8*)(&Bl[16 + fr][kb * 8]);
        acc[0] = __builtin_amdgcn_mfma_f32_16x16x32_bf16(af, bf0, acc[0], 0, 0, 0);
        acc[1] = __builtin_amdgcn_mfma_f32_16x16x32_bf16(af, bf1, acc[1], 0, 0, 0);
    }
    int er = (lane >> 4) * 4, ec = lane & 15;
    #pragma unroll
    for (int j = 0; j < 2; j++) {
        #pragma unroll
        for (int q = 0; q < 4; q++) {
            int gr = m0 + w * 16 + er + q;
            t0[(size_t)gr * RR + j * 16 + ec] = tanhf(acc[j][q]);
        }
    }
}

// ---------------------------------------------------------------------------
// Kernel 1b (k_x1b): x1[4096x160] = tanh( t0 @ w2^T + b2 ).  K=32.
// ---------------------------------------------------------------------------
__global__ __launch_bounds__(256) void k_x1b(
    const float* __restrict__ t0, const float* __restrict__ w2,
    const float* __restrict__ b2, float* __restrict__ x1out)
{
    __shared__ float t0s[64][33];
    __shared__ float w2s[R5D * RR];
    __shared__ float b2s[R5D];
    int tid = threadIdx.x;
    int m0 = blockIdx.x * 64;
    {
        int row = tid >> 2, c0 = (tid & 3) * 8;
        float4 a = *(const float4*)(t0 + (size_t)(m0 + row) * RR + c0);
        float4 b = *(const float4*)(t0 + (size_t)(m0 + row) * RR + c0 + 4);
        t0s[row][c0 + 0] = a.x; t0s[row][c0 + 1] = a.y;
        t0s[row][c0 + 2] = a.z; t0s[row][c0 + 3] = a.w;
        t0s[row][c0 + 4] = b.x; t0s[row][c0 + 5] = b.y;
        t0s[row][c0 + 6] = b.z; t0s[row][c0 + 7] = b.w;
    }
    for (int i = tid; i < R5D * RR; i += 256) w2s[i] = w2[i];
    if (tid < R5D) b2s[tid] = b2[tid];
    __syncthreads();
    int tt = tid & 63, cg = tid >> 6;
    float t0r[32];
    #pragma unroll
    for (int q = 0; q < 32; q++) t0r[q] = t0s[tt][q];
    float* xo = x1out + (size_t)(m0 + tt) * R5D + cg * 40;
    for (int c = 0; c < 40; c++) {
        const float* wr = w2s + (cg * 40 + c) * RR;
        float s = b2s[cg * 40 + c];
        #pragma unroll
        for (int q = 0; q < 32; q++) s += t0r[q] * wr[q];
        xo[c] = tanhf(s);
    }
}

// ---------------------------------------------------------------------------
// Kernel 2: tiled mix (reg-resident cur/dlt, transposed LDS, packed stores)
// ---------------------------------------------------------------------------
__global__ __launch_bounds__(256) void k_mix(
    const float* __restrict__ h, const float* __restrict__ x1,
    const float* __restrict__ xow, const float* __restrict__ xb,
    bf16* __restrict__ xr, float* __restrict__ xw,
    bf16* __restrict__ xk, bf16* __restrict__ xv, bf16* __restrict__ xg)
{
    int m0 = blockIdx.x * 64;
    int h0 = blockIdx.y * 64;
    int tid = threadIdx.x;
    __shared__ float x1sT[32][68];
    __shared__ float xosT[32][68];
    int tx = tid & 15, ty = tid >> 4;
    float creg[4][4], dreg[4][4];
    #pragma unroll
    for (int i = 0; i < 4; i++) {
        int m = m0 + ty * 4 + i;
        int t = m & (TT - 1);
        const float* hp = h + (size_t)m * HH + h0 + tx * 4;
        float4 c4 = *(const float4*)hp;
        float4 p4 = make_float4(0.f, 0.f, 0.f, 0.f);
        if (t > 0) p4 = *(const float4*)(hp - HH);
        creg[i][0] = c4.x; dreg[i][0] = p4.x - c4.x;
        creg[i][1] = c4.y; dreg[i][1] = p4.y - c4.y;
        creg[i][2] = c4.z; dreg[i][2] = p4.z - c4.z;
        creg[i][3] = c4.w; dreg[i][3] = p4.w - c4.w;
    }
    int rr = tid >> 2, cc = (tid & 3) * 8;
    for (int n = 0; n < 5; n++) {
        const float* xp = x1 + (size_t)(m0 + rr) * R5D + n * 32 + cc;
        const float* wp = xow + (size_t)(h0 + rr) * R5D + n * 32 + cc;
        float4 xa = *(const float4*)xp;
        float4 xa2 = *(const float4*)(xp + 4);
        float4 wa = *(const float4*)wp;
        float4 wa2 = *(const float4*)(wp + 4);
        __syncthreads();   // prev iter's reads complete
        x1sT[cc + 0][rr] = xa.x;  x1sT[cc + 1][rr] = xa.y;
        x1sT[cc + 2][rr] = xa.z;  x1sT[cc + 3][rr] = xa.w;
        x1sT[cc + 4][rr] = xa2.x; x1sT[cc + 5][rr] = xa2.y;
        x1sT[cc + 6][rr] = xa2.z; x1sT[cc + 7][rr] = xa2.w;
        xosT[cc + 0][rr] = wa.x;  xosT[cc + 1][rr] = wa.y;
        xosT[cc + 2][rr] = wa.z;  xosT[cc + 3][rr] = wa.w;
        xosT[cc + 4][rr] = wa2.x; xosT[cc + 5][rr] = wa2.y;
        xosT[cc + 6][rr] = wa2.z; xosT[cc + 7][rr] = wa2.w;
        __syncthreads();
        float acc[4][4] = {};
        #pragma unroll
        for (int r2 = 0; r2 < 32; r2++) {
            float4 a4 = *(const float4*)&x1sT[r2][ty * 4];
            float4 b4 = *(const float4*)&xosT[r2][tx * 4];
            float aa[4] = {a4.x, a4.y, a4.z, a4.w};
            float bb[4] = {b4.x, b4.y, b4.z, b4.w};
            #pragma unroll
            for (int i = 0; i < 4; i++)
                #pragma unroll
                for (int j = 0; j < 4; j++)
                    acc[i][j] += aa[i] * bb[j];
        }
        float4 xb4 = *(const float4*)(xb + n * HH + h0 + tx * 4);
        float xbv[4] = {xb4.x, xb4.y, xb4.z, xb4.w};
        #pragma unroll
        for (int i = 0; i < 4; i++) {
            size_t idx = (size_t)(m0 + ty * 4 + i) * HH + h0 + tx * 4;
            float v[4];
            #pragma unroll
            for (int j = 0; j < 4; j++)
                v[j] = creg[i][j] + dreg[i][j] * (acc[i][j] + xbv[j]);
            if (n == 1) {
                *(float4*)(xw + idx) = make_float4(v[0], v[1], v[2], v[3]);
            } else {
                uint2 pk;
                unsigned short* ps = (unsigned short*)&pk;
                ps[0] = f2u(v[0]); ps[1] = f2u(v[1]);
                ps[2] = f2u(v[2]); ps[3] = f2u(v[3]);
                if (n == 0)      *(uint2*)(xr + idx) = pk;
                else if (n == 2) *(uint2*)(xk + idx) = pk;
                else if (n == 3) *(uint2*)(xv + idx) = pk;
                else             *(uint2*)(xg + idx) = pk;
            }
        }
    }
}

// ---------------------------------------------------------------------------
// Kernel 3a (k_gemm_hl): C[M,N] f32 = A[M,K]bf16 @ (Bh+Bl)[N,K]bf16^T
// ---------------------------------------------------------------------------
__global__ __launch_bounds__(256) void k_gemm_hl(
    const bf16* __restrict__ A, const bf16* __restrict__ Bh,
    const bf16* __restrict__ Bl, float* __restrict__ C, int M, int N, int K)
{
    __shared__ unsigned short As[128 * 32];
    __shared__ unsigned short Bhs[128 * 32];
    __shared__ unsigned short Bls[128 * 32];
    int tid = threadIdx.x;
    int bm = blockIdx.x * 128, bn = blockIdx.y * 128;
    int lane = tid & 63, w = tid >> 6;
    int wr = w >> 1, wc = w & 1;
    const unsigned short* A16 = (const unsigned short*)A;
    const unsigned short* Bh16 = (const unsigned short*)Bh;
    const unsigned short* Bl16 = (const unsigned short*)Bl;
    f32x4 acc[4][4];
    #pragma unroll
    for (int i = 0; i < 4; i++)
        #pragma unroll
        for (int j = 0; j < 4; j++)
            acc[i][j] = (f32x4){0.f, 0.f, 0.f, 0.f};
    int ch0 = tid, ch1 = tid + 256;
    int r0c = ch0 >> 2, c0c = (ch0 & 3) * 8;
    int r1c = ch1 >> 2, c1c = (ch1 & 3) * 8;
    int fr = lane & 15, kb = (lane >> 4) * 8;
    for (int k0 = 0; k0 < K; k0 += 32) {
        uint4 a0 = *(const uint4*)(A16 + (size_t)(bm + r0c) * K + k0 + c0c);
        uint4 a1 = *(const uint4*)(A16 + (size_t)(bm + r1c) * K + k0 + c1c);
        uint4 bh0 = *(const uint4*)(Bh16 + (size_t)(bn + r0c) * K + k0 + c0c);
        uint4 bh1 = *(const uint4*)(Bh16 + (size_t)(bn + r1c) * K + k0 + c1c);
        uint4 bl0 = *(const uint4*)(Bl16 + (size_t)(bn + r0c) * K + k0 + c0c);
        uint4 bl1 = *(const uint4*)(Bl16 + (size_t)(bn + r1c) * K + k0 + c1c);
        __syncthreads();
        *(uint4*)(As + ch0 * 8) = a0;
        *(uint4*)(As + ch1 * 8) = a1;
        *(uint4*)(Bhs + ch0 * 8) = bh0;
        *(uint4*)(Bhs + ch1 * 8) = bh1;
        *(uint4*)(Bls + ch0 * 8) = bl0;
        *(uint4*)(Bls + ch1 * 8) = bl1;
        __syncthreads();
        bf16x8 af[4], bfh[4], bfl[4];
        #pragma unroll
        for (int i = 0; i < 4; i++) {
            af[i]  = *(const bf16x8*)(As + (wr * 64 + i * 16 + fr) * 32 + kb);
            bfh[i] = *(const bf16x8*)(Bhs + (wc * 64 + i * 16 + fr) * 32 + kb);
            bfl[i] = *(const bf16x8*)(Bls + (wc * 64 + i * 16 + fr) * 32 + kb);
        }
        #pragma unroll
        for (int i = 0; i < 4; i++)
            #pragma unroll
            for (int j = 0; j < 4; j++) {
                acc[i][j] = __builtin_amdgcn_mfma_f32_16x16x32_bf16(af[i], bfh[j], acc[i][j], 0, 0, 0);
                acc[i][j] = __builtin_amdgcn_mfma_f32_16x16x32_bf16(af[i], bfl[j], acc[i][j], 0, 0, 0);
            }
    }
    int er = (lane >> 4) * 4, ec = lane & 15;
    #pragma unroll
    for (int i = 0; i < 4; i++) {
        int gr = bm + wr * 64 + i * 16 + er;
        #pragma unroll
        for (int j = 0; j < 4; j++) {
            int gc = bn + wc * 64 + j * 16 + ec;
            #pragma unroll
            for (int q = 0; q < 4; q++)
                C[(size_t)(gr + q) * N + gc] = acc[i][j][q];
        }
    }
}

// ---------------------------------------------------------------------------
// Kernel 3b: fp32 GEMM (w-path only)  C = A @ B^T  (+ epilogue)
// ---------------------------------------------------------------------------
template <int EPI>
__global__ __launch_bounds__(256) void k_gemm(
    const float* __restrict__ A, const float* __restrict__ Bm,
    const float* __restrict__ bias, float* __restrict__ C,
    int M, int N, int K)
{
    __shared__ float As[16][68];
    __shared__ float Bs[16][68];
    int tid = threadIdx.x;
    int bm = blockIdx.x * 64, bn = blockIdx.y * 64;
    int tx = tid & 15, ty = tid >> 4;
    int lr = tid >> 2;
    int lk = (tid & 3) * 4;
    float acc[4][4] = {};
    for (int k0 = 0; k0 < K; k0 += 16) {
        float4 av = *(const float4*)(A + (size_t)(bm + lr) * K + k0 + lk);
        float4 bv = *(const float4*)(Bm + (size_t)(bn + lr) * K + k0 + lk);
        As[lk + 0][lr] = av.x; As[lk + 1][lr] = av.y;
        As[lk + 2][lr] = av.z; As[lk + 3][lr] = av.w;
        Bs[lk + 0][lr] = bv.x; Bs[lk + 1][lr] = bv.y;
        Bs[lk + 2][lr] = bv.z; Bs[lk + 3][lr] = bv.w;
        __syncthreads();
        #pragma unroll
        for (int kk = 0; kk < 16; kk++) {
            float4 a4 = *(const float4*)&As[kk][ty * 4];
            float4 b4 = *(const float4*)&Bs[kk][tx * 4];
            float aa[4] = {a4.x, a4.y, a4.z, a4.w};
            float bb[4] = {b4.x, b4.y, b4.z, b4.w};
            #pragma unroll
            for (int i = 0; i < 4; i++)
                #pragma unroll
                for (int j = 0; j < 4; j++)
                    acc[i][j] += aa[i] * bb[j];
        }
        __syncthreads();
    }
    #pragma unroll
    for (int i = 0; i < 4; i++) {
        int row = bm + ty * 4 + i;
        int col = bn + tx * 4;
        float4 ov;
        float vv[4];
        #pragma unroll
        for (int j = 0; j < 4; j++) {
            float v = acc[i][j];
            if (EPI == 1) v = tanhf(v);
            else if (EPI == 2) v = __expf(v + bias[col + j]);
            vv[j] = v;
        }
        ov.x = vv[0]; ov.y = vv[1]; ov.z = vv[2]; ov.w = vv[3];
        *(float4*)(C + (size_t)row * N + col) = ov;
    }
}

// ---------------------------------------------------------------------------
// Kernel 5a (chunkA1): LDS-staged r/k/e; 2-way-parallel cumsum; r~,k~ in place;
// M = (k~ * Dtot)^T v; Dtot out; u fused.
// ---------------------------------------------------------------------------
__global__ __launch_bounds__(256) void k_chunkA1(
    const float* __restrict__ eb, float* __restrict__ rb,
    float* __restrict__ kb, const float* __restrict__ vb,
    const float* __restrict__ bonus, float* __restrict__ ub,
    float* __restrict__ Mb, float* __restrict__ Db)
{
    int bh = blockIdx.x;       // b*NH + h (h fast)
    int ck = blockIdx.y;       // 0..31
    int h = bh & 3, b = bh >> 2;
    int tok0 = b * TT + ck * CK;
    int tid = threadIdx.x;
    __shared__ float Ls[CK][128];
    __shared__ float rs[CK][129];
    __shared__ float kt[CK][129];
    __shared__ float vsm[CK][68];
    __shared__ float Dts[128];
    __shared__ float up[CK][8];
    #pragma unroll
    for (int i = 0; i < 16; i++) {
        int idx = i * 256 + tid;
        int t = idx >> 7, c = idx & 127;
        size_t g = (size_t)(tok0 + t) * KDIM + h * DKH + c;
        Ls[t][c] = eb[g];
        rs[t][c] = rb[g];
        kt[t][c] = kb[g];
    }
    __syncthreads();
    {
        int c = tid & 127, hf = tid >> 7;
        float run = 0.f;
        if (hf) {
            #pragma unroll
            for (int t = 0; t < 16; t++) run += Ls[t][c];
        }
        __syncthreads();    // prefix reads of Ls done before overwrites below
        float bc = bonus[h * DKH + c];
        #pragma unroll
        for (int tt2 = 0; tt2 < 16; tt2++) {
            int t = hf * 16 + tt2;
            size_t g = (size_t)(tok0 + t) * KDIM + h * DKH + c;
            float e = Ls[t][c];
            float rv = rs[t][c];
            float kv = kt[t][c];
            rb[g] = rv * __expf(-run);
            Ls[t][c] = rv * kv * bc;          // bonus partial
            run += e;
            float ks = kv * __expf(run);
            kt[t][c] = ks;
            kb[g] = ks;
        }
        if (hf) {
            float dt = __expf(-run);
            Dts[c] = dt;
            Db[(size_t)(bh * NCK + ck) * 128 + c] = dt;
        }
    }
    __syncthreads();
    // u reduction: 256 threads = 32 t x 8 segs of 16
    {
        int t = tid >> 3, seg = tid & 7;
        float s = 0.f;
        #pragma unroll
        for (int q = 0; q < 16; q++) s += Ls[t][seg * 16 + q];
        up[t][seg] = s;
    }
    __syncthreads();
    if (tid < CK) {
        float s = 0.f;
        #pragma unroll
        for (int q = 0; q < 8; q++) s += up[tid][q];
        ub[(size_t)(tok0 + tid) * NHD + h] = s;
    }
    for (int jb = 0; jb < 4; jb++) {
        {
            int j = tid & 63, r0 = tid >> 6;
            #pragma unroll
            for (int i = 0; i < 8; i++) {
                int s = r0 + 4 * i;
                vsm[s][j] = vb[(size_t)(tok0 + s) * VDIM + h * DVH + jb * 64 + j];
            }
        }
        __syncthreads();
        {
            int kk0 = (tid >> 3) * 4;
            int j0 = (tid & 7) * 8;
            float m[4][8] = {};
            for (int s = 0; s < CK; s++) {
                float4 kv = *(const float4*)&kt[s][kk0];
                float4 v0 = *(const float4*)&vsm[s][j0];
                float4 v1 = *(const float4*)&vsm[s][j0 + 4];
                float ka[4] = {kv.x, kv.y, kv.z, kv.w};
                float va[8] = {v0.x, v0.y, v0.z, v0.w, v1.x, v1.y, v1.z, v1.w};
                #pragma unroll
                for (int i = 0; i < 4; i++)
                    #pragma unroll
                    for (int jj = 0; jj < 8; jj++)
                        m[i][jj] += ka[i] * va[jj];
            }
            #pragma unroll
            for (int i = 0; i < 4; i++) {
                float d = Dts[kk0 + i];
                size_t mb = ((size_t)(bh * NCK + ck) * 128 + kk0 + i) * DVH + jb * 64 + j0;
                *(float4*)(Mb + mb)     = make_float4(m[i][0] * d, m[i][1] * d, m[i][2] * d, m[i][3] * d);
                *(float4*)(Mb + mb + 4) = make_float4(m[i][4] * d, m[i][5] * d, m[i][6] * d, m[i][7] * d);
            }
        }
        __syncthreads();
    }
}

// ---------------------------------------------------------------------------
// Kernel 5b (chunkB): sequential over chunks with register prefetch.
// ---------------------------------------------------------------------------
__global__ __launch_bounds__(256) void k_chunkB(
    float* __restrict__ MS, const float* __restrict__ Db)
{
    int bh = blockIdx.x;
    int jsl = blockIdx.y;
    int tid = threadIdx.x;
    int j = jsl * 16 + (tid & 15);
    int kk0 = (tid >> 4) * 8;
    float S[8] = {};
    float m[8], d[8];
    {
        size_t kb0 = (size_t)(bh * NCK) * 128;
        #pragma unroll
        for (int i = 0; i < 8; i++) {
            m[i] = MS[(kb0 + kk0 + i) * DVH + j];
            d[i] = Db[kb0 + kk0 + i];
        }
    }
    for (int c = 0; c < NCK; c++) {
        size_t kbc = (size_t)(bh * NCK + c) * 128;
        float mc[8], dc[8];
        #pragma unroll
        for (int i = 0; i < 8; i++) { mc[i] = m[i]; dc[i] = d[i]; }
        if (c + 1 < NCK) {
            size_t kbn = (size_t)(bh * NCK + c + 1) * 128;
            #pragma unroll
            for (int i = 0; i < 8; i++) {
                m[i] = MS[(kbn + kk0 + i) * DVH + j];
                d[i] = Db[kbn + kk0 + i];
            }
        }
        #pragma unroll
        for (int i = 0; i < 8; i++) {
            MS[(kbc + kk0 + i) * DVH + j] = S[i];
            S[i] = S[i] * dc[i] + mc[i];
        }
    }
}

// ---------------------------------------------------------------------------
// Kernel 5c (chunkCG, fused, 512 threads): P = mask(r~ k~^T, diag=u);
// o = P@v + r~@S (f32 regs); groupnorm; silu(g) gate; y f32 IN PLACE over v.
// Thread owns 2 tokens x 8 cols.
// ---------------------------------------------------------------------------
__global__ __launch_bounds__(512) void k_chunkCG(
    const float* __restrict__ rb, const float* __restrict__ kb,
    float* __restrict__ vb, const float* __restrict__ ub,
    const float* __restrict__ Sb, const float* __restrict__ gb_,
    const float* __restrict__ gnw, const float* __restrict__ gnb)
{
    int bh = blockIdx.x, ck = blockIdx.y;
    int h = bh & 3, b = bh >> 2;
    int tok0 = b * TT + ck * CK;
    int tid = threadIdx.x;
    __shared__ float rt[CK][129];
    __shared__ float kt[CK][129];
    __shared__ float Ps[CK][33];
    __shared__ float vsm[CK][256];
    #pragma unroll
    for (int i = 0; i < 8; i++) {
        int idx = i * 512 + tid;
        int t = idx >> 7, c = idx & 127;
        size_t g = (size_t)(tok0 + t) * KDIM + h * DKH + c;
        rt[t][c] = rb[g];
        kt[t][c] = kb[g];
    }
    {
        int r0 = tid >> 4, c0 = (tid & 15) * 16;
        const float* vp = vb + (size_t)(tok0 + r0) * VDIM + h * DVH + c0;
        #pragma unroll
        for (int j = 0; j < 16; j += 4) {
            float4 v4 = *(const float4*)(vp + j);
            vsm[r0][c0 + j + 0] = v4.x; vsm[r0][c0 + j + 1] = v4.y;
            vsm[r0][c0 + j + 2] = v4.z; vsm[r0][c0 + j + 3] = v4.w;
        }
    }
    __syncthreads();
    // P: 2 entries per thread
    {
        int t = tid >> 4;
        int s0 = (tid & 15) * 2;
        float a0 = 0.f, a1 = 0.f;
        for (int k4 = 0; k4 < 128; k4 += 4) {
            float4 a = *(const float4*)&rt[t][k4];
            float4 b0 = *(const float4*)&kt[s0][k4];
            float4 b1 = *(const float4*)&kt[s0 + 1][k4];
            a0 += a.x * b0.x + a.y * b0.y + a.z * b0.z + a.w * b0.w;
            a1 += a.x * b1.x + a.y * b1.y + a.z * b1.z + a.w * b1.w;
        }
        float u0 = ub[(size_t)(tok0 + t) * NHD + h];
        Ps[t][s0]     = (s0 < t)     ? a0 : (s0 == t     ? u0 : 0.f);
        Ps[t][s0 + 1] = (s0 + 1 < t) ? a1 : (s0 + 1 == t ? u0 : 0.f);
    }
    __syncthreads();
    int t0 = (tid >> 5) * 2;
    int j0 = (tid & 31) * 8;
    float acc[2][8] = {};
    // intra-chunk: P @ v
    for (int s = 0; s < CK; s++) {
        float va[8];
        #pragma unroll
        for (int jj = 0; jj < 8; jj++) va[jj] = vsm[s][j0 + jj];
        float p0 = Ps[t0][s], p1 = Ps[t0 + 1][s];
        #pragma unroll
        for (int jj = 0; jj < 8; jj++) {
            acc[0][jj] += p0 * va[jj];
            acc[1][jj] += p1 * va[jj];
        }
    }
    // inter-chunk: r~ @ S
    size_t sbase = (size_t)(bh * NCK + ck) * 128 * DVH;
    for (int kk = 0; kk < 128; kk++) {
        const float* srow = Sb + sbase + (size_t)kk * DVH + j0;
        float4 s0v = *(const float4*)(srow);
        float4 s1v = *(const float4*)(srow + 4);
        float sv[8] = {s0v.x, s0v.y, s0v.z, s0v.w, s1v.x, s1v.y, s1v.z, s1v.w};
        float a0 = rt[t0][kk], a1 = rt[t0 + 1][kk];
        #pragma unroll
        for (int jj = 0; jj < 8; jj++) {
            acc[0][jj] += a0 * sv[jj];
            acc[1][jj] += a1 * sv[jj];
        }
    }
    // groupnorm + affine + silu(g) gate, y f32 in place over v
    int c = h * DVH + j0;
    float4 gw0 = *(const float4*)(gnw + c);
    float4 gw1 = *(const float4*)(gnw + c + 4);
    float4 gb0 = *(const float4*)(gnb + c);
    float4 gb1 = *(const float4*)(gnb + c + 4);
    float gwv[8] = {gw0.x, gw0.y, gw0.z, gw0.w, gw1.x, gw1.y, gw1.z, gw1.w};
    float gbv[8] = {gb0.x, gb0.y, gb0.z, gb0.w, gb1.x, gb1.y, gb1.z, gb1.w};
    #pragma unroll
    for (int i = 0; i < 2; i++) {
        float sum = 0.f, sq = 0.f;
        #pragma unroll
        for (int jj = 0; jj < 8; jj++) { sum += acc[i][jj]; sq += acc[i][jj] * acc[i][jj]; }
        #pragma unroll
        for (int m = 1; m < 32; m <<= 1) {
            sum += __shfl_xor(sum, m);
            sq  += __shfl_xor(sq, m);
        }
        float mean = sum * (1.f / DVH);
        float var = sq * (1.f / DVH) - mean * mean;
        float inv = rsqrtf(var + 1e-5f);
        size_t mrow = (size_t)(tok0 + t0 + i) * VDIM + c;
        float4 g0 = *(const float4*)(gb_ + mrow);
        float4 g1 = *(const float4*)(gb_ + mrow + 4);
        float gv[8] = {g0.x, g0.y, g0.z, g0.w, g1.x, g1.y, g1.z, g1.w};
        float o8[8];
        #pragma unroll
        for (int jj = 0; jj < 8; jj++) {
            float gg = gv[jj];
            float sig = 1.f / (1.f + __expf(-gg));
            o8[jj] = ((acc[i][jj] - mean) * inv * gwv[jj] + gbv[jj]) * (gg * sig);
        }
        *(float4*)(vb + mrow)     = make_float4(o8[0], o8[1], o8[2], o8[3]);
        *(float4*)(vb + mrow + 4) = make_float4(o8[4], o8[5], o8[6], o8[7]);
    }
}

// ---------------------------------------------------------------------------
// Kernel 6: output GEMM, split precision
// ---------------------------------------------------------------------------
__global__ __launch_bounds__(256) void k_gemm_out(
    const float* __restrict__ A, const bf16* __restrict__ Bh,
    const bf16* __restrict__ Bl, float* __restrict__ C, int M, int N, int K)
{
    __shared__ unsigned short Ah[128 * 32];
    __shared__ unsigned short Al[128 * 32];
    __shared__ unsigned short Bhs[128 * 32];
    __shared__ unsigned short Bls[128 * 32];
    int tid = threadIdx.x;
    int bm = blockIdx.x * 128, bn = blockIdx.y * 128;
    int lane = tid & 63, w = tid >> 6;
    int wr = w >> 1, wc = w & 1;
    const unsigned short* Bh16 = (const unsigned short*)Bh;
    const unsigned short* Bl16 = (const unsigned short*)Bl;
    f32x4 acc[4][4];
    #pragma unroll
    for (int i = 0; i < 4; i++)
        #pragma unroll
        for (int j = 0; j < 4; j++)
            acc[i][j] = (f32x4){0.f, 0.f, 0.f, 0.f};
    int arow = tid >> 1, acol = (tid & 1) * 16;
    int ch0 = tid, ch1 = tid + 256;
    int r0c = ch0 >> 2, c0c = (ch0 & 3) * 8;
    int r1c = ch1 >> 2, c1c = (ch1 & 3) * 8;
    int fr = lane & 15, kb = (lane >> 4) * 8;
    for (int k0 = 0; k0 < K; k0 += 32) {
        float av[16];
        #pragma unroll
        for (int q = 0; q < 4; q++) {
            float4 t4 = *(const float4*)(A + (size_t)(bm + arow) * K + k0 + acol + q * 4);
            av[q * 4 + 0] = t4.x; av[q * 4 + 1] = t4.y;
            av[q * 4 + 2] = t4.z; av[q * 4 + 3] = t4.w;
        }
        uint4 bh0 = *(const uint4*)(Bh16 + (size_t)(bn + r0c) * K + k0 + c0c);
        uint4 bh1 = *(const uint4*)(Bh16 + (size_t)(bn + r1c) * K + k0 + c1c);
        uint4 bl0 = *(const uint4*)(Bl16 + (size_t)(bn + r0c) * K + k0 + c0c);
        uint4 bl1 = *(const uint4*)(Bl16 + (size_t)(bn + r1c) * K + k0 + c1c);
        __syncthreads();
        alignas(16) unsigned short th[16], tl[16];
        #pragma unroll
        for (int q = 0; q < 16; q++) {
            unsigned short hu = f2u(av[q]);
            th[q] = hu;
            tl[q] = f2u(av[q] - u2f(hu));
        }
        *(uint4*)(Ah + arow * 32 + acol)     = *(const uint4*)&th[0];
        *(uint4*)(Ah + arow * 32 + acol + 8) = *(const uint4*)&th[8];
        *(uint4*)(Al + arow * 32 + acol)     = *(const uint4*)&tl[0];
        *(uint4*)(Al + arow * 32 + acol + 8) = *(const uint4*)&tl[8];
        *(uint4*)(Bhs + ch0 * 8) = bh0;
        *(uint4*)(Bhs + ch1 * 8) = bh1;
        *(uint4*)(Bls + ch0 * 8) = bl0;
        *(uint4*)(Bls + ch1 * 8) = bl1;
        __syncthreads();
        bf16x8 afh[4], afl[4], bfh[4], bfl[4];
        #pragma unroll
        for (int i = 0; i < 4; i++) {
            afh[i] = *(const bf16x8*)(Ah + (wr * 64 + i * 16 + fr) * 32 + kb);
            afl[i] = *(const bf16x8*)(Al + (wr * 64 + i * 16 + fr) * 32 + kb);
            bfh[i] = *(const bf16x8*)(Bhs + (wc * 64 + i * 16 + fr) * 32 + kb);
            bfl[i] = *(const bf16x8*)(Bls + (wc * 64 + i * 16 + fr) * 32 + kb);
        }
        #pragma unroll
        for (int i = 0; i < 4; i++)
            #pragma unroll
            for (int j = 0; j < 4; j++) {
                acc[i][j] = __builtin_amdgcn_mfma_f32_16x16x32_bf16(afh[i], bfh[j], acc[i][j], 0, 0, 0);
                acc[i][j] = __builtin_amdgcn_mfma_f32_16x16x32_bf16(afl[i], bfh[j], acc[i][j], 0, 0, 0);
                acc[i][j] = __builtin_amdgcn_mfma_f32_16x16x32_bf16(afh[i], bfl[j], acc[i][j], 0, 0, 0);
            }
    }
    int er = (lane >> 4) * 4, ec = lane & 15;
    #pragma unroll
    for (int i = 0; i < 4; i++) {
        int gr = bm + wr * 64 + i * 16 + er;
        #pragma unroll
        for (int j = 0; j < 4; j++) {
            int gc = bn + wc * 64 + j * 16 + ec;
            #pragma unroll
            for (int q = 0; q < 4; q++)
                C[(size_t)(gr + q) * N + gc] = acc[i][j][q];
        }
    }
}

// ---------------------------------------------------------------------------
extern "C" void kernel_launch(void* const* d_in, const int* in_sizes, int n_in,
                              void* d_out, int out_size, void* d_ws, size_t ws_size,
                              hipStream_t stream)
{
    const float* h        = (const float*)d_in[0];
    const float* x_mu     = (const float*)d_in[1];
    const float* xl_w1    = (const float*)d_in[2];
    const float* xl_w2    = (const float*)d_in[3];
    const float* xl_b2    = (const float*)d_in[4];
    const float* x_out_w  = (const float*)d_in[5];
    const float* x_bias   = (const float*)d_in[6];
    const float* r_w      = (const float*)d_in[7];
    const float* w_w1     = (const float*)d_in[8];
    const float* w_w2     = (const float*)d_in[9];
    const float* w_b      = (const float*)d_in[10];
    const float* k_w      = (const float*)d_in[11];
    const float* v_w      = (const float*)d_in[12];
    const float* g_w      = (const float*)d_in[13];
    const float* bonus    = (const float*)d_in[14];
    const float* gn_w     = (const float*)d_in[15];
    const float* gn_b     = (const float*)d_in[16];
    const float* o_w      = (const float*)d_in[17];
    float* out = (float*)d_out;

    // Workspace overlay: total 35,733,504 floats = 142.9 MB (proven size)
    float* ws = (float*)d_ws;
    bf16*  wbf  = (bf16*)ws;                       // 8,388,608 bf16 = 4,194,304 slots
    float* rbuf = ws + 4194304;                    // 2,097,152
    float* vbuf = ws + 6291456;                    // 4,194,304 (y f32 in place later)
    float* gbuf = ws + 10485760;                   // 4,194,304
    float* kbuf = ws + 14680064;                   // 2,097,152
    float* ebuf = ws + 16777216;                   // 2,097,152
    float* ubuf = ws + 18874368;                   // 16,384
    float* Dbuf = ws + 18890752;                   // 65,536
    float* BIG  = ws + 18956288;                   // 16,777,216 (X phase / Mbuf)

    // weight hi/lo (bf16 element offsets within wbf)
    bf16* rwb_h = wbf;                  // 524,288
    bf16* kwb_h = wbf + 524288;
    bf16* vwb_h = wbf + 1048576;        // 1,048,576
    bf16* gwb_h = wbf + 2097152;
    bf16* owb_h = wbf + 3145728;
    bf16* rwb_l = wbf + 4194304;
    bf16* kwb_l = wbf + 4718592;
    bf16* vwb_l = wbf + 5242880;
    bf16* gwb_l = wbf + 6291456;
    bf16* owb_l = wbf + 7340032;

    // X phase inside BIG (each bf16 X = 2,097,152 float slots)
    float* Xw = BIG;                           // f32 [0 .. 4,194,304)
    bf16*  Xr = (bf16*)(BIG + 4194304);
    bf16*  Xk = (bf16*)(BIG + 6291456);
    bf16*  Xv = (bf16*)(BIG + 8388608);
    bf16*  Xg = (bf16*)(BIG + 10485760);
    float* x1   = BIG + 12582912;              // 655,360  (dead after k_mix)
    float* w1t  = BIG + 13238272;              // 262,144  (dead after w2-gemm)
    float* t0bf = BIG + 13500416;              // 131,072  (dead after k_x1b)
    float* Mbuf = BIG;                         // full 16,777,216 after X dead
    float* ybuf = vbuf;                        // y f32 in place over v

    // weight conversion (hi/lo pairs)
    k_f2b2<<<256, 256, 0, stream>>>(r_w, rwb_h, rwb_l, 524288);
    k_f2b2<<<256, 256, 0, stream>>>(k_w, kwb_h, kwb_l, 524288);
    k_f2b2<<<512, 256, 0, stream>>>(v_w, vwb_h, vwb_l, 1048576);
    k_f2b2<<<512, 256, 0, stream>>>(g_w, gwb_h, gwb_l, 1048576);
    k_f2b2<<<512, 256, 0, stream>>>(o_w, owb_h, owb_l, 1048576);

    // x1 path: MFMA phase-1 + small phase-2
    k_x1mm<<<NTOK / 64, 256, 0, stream>>>(h, x_mu, xl_w1, t0bf);
    k_x1b<<<NTOK / 64, 256, 0, stream>>>(t0bf, xl_w2, xl_b2, x1);

    k_mix<<<dim3(NTOK / 64, HH / 64), 256, 0, stream>>>(h, x1, x_out_w, x_bias,
                                                        Xr, Xw, Xk, Xv, Xg);

    // projections: fused hi/lo MFMA for r/k/v/g, fp32 for the w path
    k_gemm_hl<<<dim3(NTOK / 128, KDIM / 128), 256, 0, stream>>>(Xr, rwb_h, rwb_l, rbuf, NTOK, KDIM, HH);
    k_gemm_hl<<<dim3(NTOK / 128, KDIM / 128), 256, 0, stream>>>(Xk, kwb_h, kwb_l, kbuf, NTOK, KDIM, HH);
    k_gemm_hl<<<dim3(NTOK / 128, VDIM / 128), 256, 0, stream>>>(Xv, vwb_h, vwb_l, vbuf, NTOK, VDIM, HH);
    k_gemm_hl<<<dim3(NTOK / 128, VDIM / 128), 256, 0, stream>>>(Xg, gwb_h, gwb_l, gbuf, NTOK, VDIM, HH);
    k_gemm<1><<<dim3(NTOK / 64, GG / 64), 256, 0, stream>>>(Xw, w_w1, nullptr, w1t, NTOK, GG, HH);
    k_gemm<2><<<dim3(NTOK / 64, KDIM / 64), 256, 0, stream>>>(w1t, w_w2, w_b, ebuf, NTOK, KDIM, GG);

    k_chunkA1<<<dim3(BB * NHD, NCK), 256, 0, stream>>>(ebuf, rbuf, kbuf, vbuf,
                                                       bonus, ubuf, Mbuf, Dbuf);
    k_chunkB<<<dim3(BB * NHD, 16), 256, 0, stream>>>(Mbuf, Dbuf);
    k_chunkCG<<<dim3(BB * NHD, NCK), 512, 0, stream>>>(rbuf, kbuf, vbuf, ubuf, Mbuf,
                                                       gbuf, gn_w, gn_b);

    k_gemm_out<<<dim3(NTOK / 128, HH / 128), 256, 0, stream>>>(ybuf, owb_h, owb_l, out, NTOK, HH, VDIM);
}

// Round 8
// 423.143 us; speedup vs baseline: 5.3849x; 1.0627x over previous
//
#include <hip/hip_runtime.h>
#include <hip/hip_bf16.h>
#include <math.h>

// Problem constants
static constexpr int BB = 4;
static constexpr int TT = 1024;
static constexpr int HH = 1024;
static constexpr int NHD = 4;
static constexpr int KDIM = 512;
static constexpr int VDIM = 1024;
static constexpr int DKH = 128;   // KD / NH
static constexpr int DVH = 256;   // VD / NH
static constexpr int RR = 32;
static constexpr int R5D = 160;
static constexpr int GG = 64;
static constexpr int NTOK = BB * TT;   // 4096
static constexpr int CK = 32;          // chunk length
static constexpr int NCK = TT / CK;    // 32 chunks per sequence

typedef __bf16 bf16x8 __attribute__((ext_vector_type(8)));
typedef float f32x4 __attribute__((ext_vector_type(4)));
typedef __hip_bfloat16 bf16;

static __device__ inline unsigned short f2u(float v) {
    __hip_bfloat16 b = __float2bfloat16(v);
    unsigned short u; __builtin_memcpy(&u, &b, 2); return u;
}
static __device__ inline float u2f(unsigned short u) {
    __hip_bfloat16 b; __builtin_memcpy(&b, &u, 2); return __bfloat162float(b);
}

// ---------------------------------------------------------------------------
// Kernel 0: f32 -> bf16 hi/lo pairs, all 5 weights in one launch
// total = 2*524288 + 3*1048576 = 4,194,304 elems; 2048 blocks x 256 thr x 8
// ---------------------------------------------------------------------------
__global__ __launch_bounds__(256) void k_f2b2_all(
    const float* __restrict__ r_w, const float* __restrict__ k_w,
    const float* __restrict__ v_w, const float* __restrict__ g_w,
    const float* __restrict__ o_w,
    bf16* __restrict__ rh, bf16* __restrict__ rl,
    bf16* __restrict__ kh, bf16* __restrict__ kl,
    bf16* __restrict__ vh, bf16* __restrict__ vl,
    bf16* __restrict__ gh, bf16* __restrict__ gl,
    bf16* __restrict__ oh, bf16* __restrict__ ol)
{
    size_t g = ((size_t)blockIdx.x * 256 + threadIdx.x) * 8;
    const float* s; bf16 *hi, *lo; size_t off;
    if (g < 524288)       { s = r_w; hi = rh; lo = rl; off = g; }
    else if (g < 1048576) { s = k_w; hi = kh; lo = kl; off = g - 524288; }
    else if (g < 2097152) { s = v_w; hi = vh; lo = vl; off = g - 1048576; }
    else if (g < 3145728) { s = g_w; hi = gh; lo = gl; off = g - 2097152; }
    else                  { s = o_w; hi = oh; lo = ol; off = g - 3145728; }
    #pragma unroll
    for (int j = 0; j < 8; j++) {
        float v = s[off + j];
        bf16 hb = __float2bfloat16(v);
        hi[off + j] = hb;
        lo[off + j] = __float2bfloat16(v - __bfloat162float(hb));
    }
}

// ---------------------------------------------------------------------------
// Kernel 1a (k_x1mm): t0[4096x32] = tanh( x_lerp @ w1^T ) via bf16 MFMA.
// ---------------------------------------------------------------------------
__global__ __launch_bounds__(256) void k_x1mm(
    const float* __restrict__ h, const float* __restrict__ mu,
    const float* __restrict__ w1, float* __restrict__ t0)
{
    __shared__ unsigned short Al[64][40];
    __shared__ unsigned short Bl[32][40];
    int tid = threadIdx.x;
    int m0 = blockIdx.x * 64;
    int lane = tid & 63, w = tid >> 6;
    f32x4 acc[2];
    acc[0] = (f32x4){0.f, 0.f, 0.f, 0.f};
    acc[1] = (f32x4){0.f, 0.f, 0.f, 0.f};
    int ar = tid >> 2, ac0 = (tid & 3) * 8;        // A stage: 64x32, 8 per thread
    int br = tid >> 3, bc0 = (tid & 7) * 4;        // B stage: 32x32, 4 per thread
    int fr = lane & 15, kb = lane >> 4;
    int mrow = m0 + ar;
    int trow = mrow & (TT - 1);
    const float* hp = h + (size_t)mrow * HH;
    for (int k0 = 0; k0 < HH; k0 += 32) {
        float av[8];
        #pragma unroll
        for (int j = 0; j < 8; j += 4) {
            float4 c4 = *(const float4*)(hp + k0 + ac0 + j);
            float4 p4 = make_float4(0.f, 0.f, 0.f, 0.f);
            if (trow > 0) p4 = *(const float4*)(hp + k0 + ac0 + j - HH);
            float4 m4 = *(const float4*)(mu + k0 + ac0 + j);
            av[j + 0] = c4.x + (p4.x - c4.x) * m4.x;
            av[j + 1] = c4.y + (p4.y - c4.y) * m4.y;
            av[j + 2] = c4.z + (p4.z - c4.z) * m4.z;
            av[j + 3] = c4.w + (p4.w - c4.w) * m4.w;
        }
        float4 b4 = *(const float4*)(w1 + (size_t)br * HH + k0 + bc0);
        __syncthreads();
        #pragma unroll
        for (int j = 0; j < 8; j++) Al[ar][ac0 + j] = f2u(av[j]);
        Bl[br][bc0 + 0] = f2u(b4.x); Bl[br][bc0 + 1] = f2u(b4.y);
        Bl[br][bc0 + 2] = f2u(b4.z); Bl[br][bc0 + 3] = f2u(b4.w);
        __syncthreads();
        bf16x8 af = *(const bf16x8*)(&Al[w * 16 + fr][kb * 8]);
        bf16x8 bf0 = *(const bf16x8*)(&Bl[fr][kb * 8]);
        bf16x8 bf1 = *(const bf16x8*)(&Bl[16 + fr][kb * 8]);
        acc[0] = __builtin_amdgcn_mfma_f32_16x16x32_bf16(af, bf0, acc[0], 0, 0, 0);
        acc[1] = __builtin_amdgcn_mfma_f32_16x16x32_bf16(af, bf1, acc[1], 0, 0, 0);
    }
    int er = (lane >> 4) * 4, ec = lane & 15;
    #pragma unroll
    for (int j = 0; j < 2; j++) {
        #pragma unroll
        for (int q = 0; q < 4; q++) {
            int gr = m0 + w * 16 + er + q;
            t0[(size_t)gr * RR + j * 16 + ec] = tanhf(acc[j][q]);
        }
    }
}

// ---------------------------------------------------------------------------
// Kernel 1b (k_x1b): x1[4096x160] = tanh( t0 @ w2^T + b2 ).  K=32.
// ---------------------------------------------------------------------------
__global__ __launch_bounds__(256) void k_x1b(
    const float* __restrict__ t0, const float* __restrict__ w2,
    const float* __restrict__ b2, float* __restrict__ x1out)
{
    __shared__ float t0s[64][33];
    __shared__ float w2s[R5D * RR];
    __shared__ float b2s[R5D];
    int tid = threadIdx.x;
    int m0 = blockIdx.x * 64;
    {
        int row = tid >> 2, c0 = (tid & 3) * 8;
        float4 a = *(const float4*)(t0 + (size_t)(m0 + row) * RR + c0);
        float4 b = *(const float4*)(t0 + (size_t)(m0 + row) * RR + c0 + 4);
        t0s[row][c0 + 0] = a.x; t0s[row][c0 + 1] = a.y;
        t0s[row][c0 + 2] = a.z; t0s[row][c0 + 3] = a.w;
        t0s[row][c0 + 4] = b.x; t0s[row][c0 + 5] = b.y;
        t0s[row][c0 + 6] = b.z; t0s[row][c0 + 7] = b.w;
    }
    for (int i = tid; i < R5D * RR; i += 256) w2s[i] = w2[i];
    if (tid < R5D) b2s[tid] = b2[tid];
    __syncthreads();
    int tt = tid & 63, cg = tid >> 6;
    float t0r[32];
    #pragma unroll
    for (int q = 0; q < 32; q++) t0r[q] = t0s[tt][q];
    float* xo = x1out + (size_t)(m0 + tt) * R5D + cg * 40;
    for (int c = 0; c < 40; c++) {
        const float* wr = w2s + (cg * 40 + c) * RR;
        float s = b2s[cg * 40 + c];
        #pragma unroll
        for (int q = 0; q < 32; q++) s += t0r[q] * wr[q];
        xo[c] = tanhf(s);
    }
}

// ---------------------------------------------------------------------------
// Kernel 2a (k_mixw): n=1 slice only (w path, f32 exact).
// Transposed LDS [32][68] with wave-aligned writers (conflict-free).
// ---------------------------------------------------------------------------
__global__ __launch_bounds__(256) void k_mixw(
    const float* __restrict__ h, const float* __restrict__ x1,
    const float* __restrict__ xow, const float* __restrict__ xb,
    float* __restrict__ xw)
{
    int m0 = blockIdx.x * 64;
    int h0 = blockIdx.y * 64;
    int tid = threadIdx.x;
    __shared__ float x1sT[32][68];
    __shared__ float xosT[32][68];
    int rr = tid & 63, cg = tid >> 6;    // cg = wave id, 8 cols each
    {
        const float* xp = x1 + (size_t)(m0 + rr) * R5D + 32 + cg * 8;
        const float* wp = xow + (size_t)(h0 + rr) * R5D + 32 + cg * 8;
        float4 a0 = *(const float4*)xp, a1 = *(const float4*)(xp + 4);
        float4 b0 = *(const float4*)wp, b1 = *(const float4*)(wp + 4);
        x1sT[cg * 8 + 0][rr] = a0.x; x1sT[cg * 8 + 1][rr] = a0.y;
        x1sT[cg * 8 + 2][rr] = a0.z; x1sT[cg * 8 + 3][rr] = a0.w;
        x1sT[cg * 8 + 4][rr] = a1.x; x1sT[cg * 8 + 5][rr] = a1.y;
        x1sT[cg * 8 + 6][rr] = a1.z; x1sT[cg * 8 + 7][rr] = a1.w;
        xosT[cg * 8 + 0][rr] = b0.x; xosT[cg * 8 + 1][rr] = b0.y;
        xosT[cg * 8 + 2][rr] = b0.z; xosT[cg * 8 + 3][rr] = b0.w;
        xosT[cg * 8 + 4][rr] = b1.x; xosT[cg * 8 + 5][rr] = b1.y;
        xosT[cg * 8 + 6][rr] = b1.z; xosT[cg * 8 + 7][rr] = b1.w;
    }
    int tx = tid & 15, ty = tid >> 4;
    float creg[4][4], dreg[4][4];
    #pragma unroll
    for (int i = 0; i < 4; i++) {
        int m = m0 + ty * 4 + i;
        int t = m & (TT - 1);
        const float* hp = h + (size_t)m * HH + h0 + tx * 4;
        float4 c4 = *(const float4*)hp;
        float4 p4 = make_float4(0.f, 0.f, 0.f, 0.f);
        if (t > 0) p4 = *(const float4*)(hp - HH);
        creg[i][0] = c4.x; dreg[i][0] = p4.x - c4.x;
        creg[i][1] = c4.y; dreg[i][1] = p4.y - c4.y;
        creg[i][2] = c4.z; dreg[i][2] = p4.z - c4.z;
        creg[i][3] = c4.w; dreg[i][3] = p4.w - c4.w;
    }
    __syncthreads();
    float acc[4][4] = {};
    #pragma unroll
    for (int r2 = 0; r2 < 32; r2++) {
        float4 a4 = *(const float4*)&x1sT[r2][ty * 4];
        float4 b4 = *(const float4*)&xosT[r2][tx * 4];
        float aa[4] = {a4.x, a4.y, a4.z, a4.w};
        float bb[4] = {b4.x, b4.y, b4.z, b4.w};
        #pragma unroll
        for (int i = 0; i < 4; i++)
            #pragma unroll
            for (int j = 0; j < 4; j++)
                acc[i][j] += aa[i] * bb[j];
    }
    float4 xb4 = *(const float4*)(xb + HH + h0 + tx * 4);   // n=1 row of x_bias
    float xbv[4] = {xb4.x, xb4.y, xb4.z, xb4.w};
    #pragma unroll
    for (int i = 0; i < 4; i++) {
        size_t idx = (size_t)(m0 + ty * 4 + i) * HH + h0 + tx * 4;
        float v[4];
        #pragma unroll
        for (int j = 0; j < 4; j++)
            v[j] = creg[i][j] + dreg[i][j] * (acc[i][j] + xbv[j]);
        *(float4*)(xw + idx) = make_float4(v[0], v[1], v[2], v[3]);
    }
}

// ---------------------------------------------------------------------------
// Kernel 2b (k_mix4): n in {0,2,3,4} via direct-from-global MFMA fragments.
// No LDS, no barriers. Wave w owns tokens m0+w*16..+15, all 64 h of the tile.
// ---------------------------------------------------------------------------
__global__ __launch_bounds__(256) void k_mix4(
    const float* __restrict__ h, const float* __restrict__ x1,
    const float* __restrict__ xow, const float* __restrict__ xb,
    bf16* __restrict__ xr, bf16* __restrict__ xk,
    bf16* __restrict__ xv, bf16* __restrict__ xg)
{
    int m0 = blockIdx.x * 64;
    int h0 = blockIdx.y * 64;
    int tid = threadIdx.x;
    int lane = tid & 63, w = tid >> 6;
    int fr = lane & 15, kb = (lane >> 4) * 8;
    int er = (lane >> 4) * 4, ec = lane & 15;
    // cur/dlt for the OUTPUT positions: rows m0+w*16+er+q, cols h0+j*16+ec
    float creg[4][4], dreg[4][4];
    #pragma unroll
    for (int q = 0; q < 4; q++) {
        int m = m0 + w * 16 + er + q;
        int t = m & (TT - 1);
        const float* hp = h + (size_t)m * HH;
        #pragma unroll
        for (int j = 0; j < 4; j++) {
            int hh = h0 + j * 16 + ec;
            float c = hp[hh];
            float p = (t > 0) ? hp[hh - HH] : 0.f;
            creg[q][j] = c;
            dreg[q][j] = p - c;
        }
    }
    bf16* outs[4] = {xr, xk, xv, xg};
    const int ns[4] = {0, 2, 3, 4};
    #pragma unroll
    for (int ni = 0; ni < 4; ni++) {
        int n = ns[ni];
        // A fragment: x1 row m0+w*16+fr, k = n*32+kb..+7 (f32 -> bf16 in reg)
        const float* ap = x1 + (size_t)(m0 + w * 16 + fr) * R5D + n * 32 + kb;
        float4 a0 = *(const float4*)ap;
        float4 a1 = *(const float4*)(ap + 4);
        alignas(16) unsigned short ta[8];
        ta[0] = f2u(a0.x); ta[1] = f2u(a0.y); ta[2] = f2u(a0.z); ta[3] = f2u(a0.w);
        ta[4] = f2u(a1.x); ta[5] = f2u(a1.y); ta[6] = f2u(a1.z); ta[7] = f2u(a1.w);
        bf16x8 af = *(const bf16x8*)ta;
        f32x4 accj[4];
        #pragma unroll
        for (int j = 0; j < 4; j++) {
            const float* bp = xow + (size_t)(h0 + j * 16 + fr) * R5D + n * 32 + kb;
            float4 b0 = *(const float4*)bp;
            float4 b1 = *(const float4*)(bp + 4);
            alignas(16) unsigned short tb[8];
            tb[0] = f2u(b0.x); tb[1] = f2u(b0.y); tb[2] = f2u(b0.z); tb[3] = f2u(b0.w);
            tb[4] = f2u(b1.x); tb[5] = f2u(b1.y); tb[6] = f2u(b1.z); tb[7] = f2u(b1.w);
            bf16x8 bf_ = *(const bf16x8*)tb;
            f32x4 z = (f32x4){0.f, 0.f, 0.f, 0.f};
            accj[j] = __builtin_amdgcn_mfma_f32_16x16x32_bf16(af, bf_, z, 0, 0, 0);
        }
        bf16* op = outs[ni];
        #pragma unroll
        for (int j = 0; j < 4; j++) {
            float xbv = xb[n * HH + h0 + j * 16 + ec];
            #pragma unroll
            for (int q = 0; q < 4; q++) {
                float val = creg[q][j] + dreg[q][j] * (accj[j][q] + xbv);
                op[(size_t)(m0 + w * 16 + er + q) * HH + h0 + j * 16 + ec] =
                    __float2bfloat16(val);
            }
        }
    }
}

// ---------------------------------------------------------------------------
// Kernel 3a (k_gemm_hl): C[M,N] f32 = A[M,K]bf16 @ (Bh+Bl)[N,K]bf16^T
// ---------------------------------------------------------------------------
__global__ __launch_bounds__(256) void k_gemm_hl(
    const bf16* __restrict__ A, const bf16* __restrict__ Bh,
    const bf16* __restrict__ Bl, float* __restrict__ C, int M, int N, int K)
{
    __shared__ unsigned short As[128 * 32];
    __shared__ unsigned short Bhs[128 * 32];
    __shared__ unsigned short Bls[128 * 32];
    int tid = threadIdx.x;
    int bm = blockIdx.x * 128, bn = blockIdx.y * 128;
    int lane = tid & 63, w = tid >> 6;
    int wr = w >> 1, wc = w & 1;
    const unsigned short* A16 = (const unsigned short*)A;
    const unsigned short* Bh16 = (const unsigned short*)Bh;
    const unsigned short* Bl16 = (const unsigned short*)Bl;
    f32x4 acc[4][4];
    #pragma unroll
    for (int i = 0; i < 4; i++)
        #pragma unroll
        for (int j = 0; j < 4; j++)
            acc[i][j] = (f32x4){0.f, 0.f, 0.f, 0.f};
    int ch0 = tid, ch1 = tid + 256;
    int r0c = ch0 >> 2, c0c = (ch0 & 3) * 8;
    int r1c = ch1 >> 2, c1c = (ch1 & 3) * 8;
    int fr = lane & 15, kb = (lane >> 4) * 8;
    for (int k0 = 0; k0 < K; k0 += 32) {
        uint4 a0 = *(const uint4*)(A16 + (size_t)(bm + r0c) * K + k0 + c0c);
        uint4 a1 = *(const uint4*)(A16 + (size_t)(bm + r1c) * K + k0 + c1c);
        uint4 bh0 = *(const uint4*)(Bh16 + (size_t)(bn + r0c) * K + k0 + c0c);
        uint4 bh1 = *(const uint4*)(Bh16 + (size_t)(bn + r1c) * K + k0 + c1c);
        uint4 bl0 = *(const uint4*)(Bl16 + (size_t)(bn + r0c) * K + k0 + c0c);
        uint4 bl1 = *(const uint4*)(Bl16 + (size_t)(bn + r1c) * K + k0 + c1c);
        __syncthreads();
        *(uint4*)(As + ch0 * 8) = a0;
        *(uint4*)(As + ch1 * 8) = a1;
        *(uint4*)(Bhs + ch0 * 8) = bh0;
        *(uint4*)(Bhs + ch1 * 8) = bh1;
        *(uint4*)(Bls + ch0 * 8) = bl0;
        *(uint4*)(Bls + ch1 * 8) = bl1;
        __syncthreads();
        bf16x8 af[4], bfh[4], bfl[4];
        #pragma unroll
        for (int i = 0; i < 4; i++) {
            af[i]  = *(const bf16x8*)(As + (wr * 64 + i * 16 + fr) * 32 + kb);
            bfh[i] = *(const bf16x8*)(Bhs + (wc * 64 + i * 16 + fr) * 32 + kb);
            bfl[i] = *(const bf16x8*)(Bls + (wc * 64 + i * 16 + fr) * 32 + kb);
        }
        #pragma unroll
        for (int i = 0; i < 4; i++)
            #pragma unroll
            for (int j = 0; j < 4; j++) {
                acc[i][j] = __builtin_amdgcn_mfma_f32_16x16x32_bf16(af[i], bfh[j], acc[i][j], 0, 0, 0);
                acc[i][j] = __builtin_amdgcn_mfma_f32_16x16x32_bf16(af[i], bfl[j], acc[i][j], 0, 0, 0);
            }
    }
    int er = (lane >> 4) * 4, ec = lane & 15;
    #pragma unroll
    for (int i = 0; i < 4; i++) {
        int gr = bm + wr * 64 + i * 16 + er;
        #pragma unroll
        for (int j = 0; j < 4; j++) {
            int gc = bn + wc * 64 + j * 16 + ec;
            #pragma unroll
            for (int q = 0; q < 4; q++)
                C[(size_t)(gr + q) * N + gc] = acc[i][j][q];
        }
    }
}

// ---------------------------------------------------------------------------
// Kernel 3b: fp32 GEMM (w-path only)  C = A @ B^T  (+ epilogue)
// ---------------------------------------------------------------------------
template <int EPI>
__global__ __launch_bounds__(256) void k_gemm(
    const float* __restrict__ A, const float* __restrict__ Bm,
    const float* __restrict__ bias, float* __restrict__ C,
    int M, int N, int K)
{
    __shared__ float As[16][68];
    __shared__ float Bs[16][68];
    int tid = threadIdx.x;
    int bm = blockIdx.x * 64, bn = blockIdx.y * 64;
    int tx = tid & 15, ty = tid >> 4;
    int lr = tid >> 2;
    int lk = (tid & 3) * 4;
    float acc[4][4] = {};
    for (int k0 = 0; k0 < K; k0 += 16) {
        float4 av = *(const float4*)(A + (size_t)(bm + lr) * K + k0 + lk);
        float4 bv = *(const float4*)(Bm + (size_t)(bn + lr) * K + k0 + lk);
        As[lk + 0][lr] = av.x; As[lk + 1][lr] = av.y;
        As[lk + 2][lr] = av.z; As[lk + 3][lr] = av.w;
        Bs[lk + 0][lr] = bv.x; Bs[lk + 1][lr] = bv.y;
        Bs[lk + 2][lr] = bv.z; Bs[lk + 3][lr] = bv.w;
        __syncthreads();
        #pragma unroll
        for (int kk = 0; kk < 16; kk++) {
            float4 a4 = *(const float4*)&As[kk][ty * 4];
            float4 b4 = *(const float4*)&Bs[kk][tx * 4];
            float aa[4] = {a4.x, a4.y, a4.z, a4.w};
            float bb[4] = {b4.x, b4.y, b4.z, b4.w};
            #pragma unroll
            for (int i = 0; i < 4; i++)
                #pragma unroll
                for (int j = 0; j < 4; j++)
                    acc[i][j] += aa[i] * bb[j];
        }
        __syncthreads();
    }
    #pragma unroll
    for (int i = 0; i < 4; i++) {
        int row = bm + ty * 4 + i;
        int col = bn + tx * 4;
        float4 ov;
        float vv[4];
        #pragma unroll
        for (int j = 0; j < 4; j++) {
            float v = acc[i][j];
            if (EPI == 1) v = tanhf(v);
            else if (EPI == 2) v = __expf(v + bias[col + j]);
            vv[j] = v;
        }
        ov.x = vv[0]; ov.y = vv[1]; ov.z = vv[2]; ov.w = vv[3];
        *(float4*)(C + (size_t)row * N + col) = ov;
    }
}

// ---------------------------------------------------------------------------
// Kernel 5a (chunkA1): LDS-staged r/k/e; 2-way-parallel cumsum; r~,k~ in place;
// M = (k~ * Dtot)^T v; Dtot out; u fused.
// ---------------------------------------------------------------------------
__global__ __launch_bounds__(256) void k_chunkA1(
    const float* __restrict__ eb, float* __restrict__ rb,
    float* __restrict__ kb, const float* __restrict__ vb,
    const float* __restrict__ bonus, float* __restrict__ ub,
    float* __restrict__ Mb, float* __restrict__ Db)
{
    int bh = blockIdx.x;       // b*NH + h (h fast)
    int ck = blockIdx.y;       // 0..31
    int h = bh & 3, b = bh >> 2;
    int tok0 = b * TT + ck * CK;
    int tid = threadIdx.x;
    __shared__ float Ls[CK][128];
    __shared__ float rs[CK][129];
    __shared__ float kt[CK][129];
    __shared__ float vsm[CK][68];
    __shared__ float Dts[128];
    __shared__ float up[CK][8];
    #pragma unroll
    for (int i = 0; i < 16; i++) {
        int idx = i * 256 + tid;
        int t = idx >> 7, c = idx & 127;
        size_t g = (size_t)(tok0 + t) * KDIM + h * DKH + c;
        Ls[t][c] = eb[g];
        rs[t][c] = rb[g];
        kt[t][c] = kb[g];
    }
    __syncthreads();
    {
        int c = tid & 127, hf = tid >> 7;
        float run = 0.f;
        if (hf) {
            #pragma unroll
            for (int t = 0; t < 16; t++) run += Ls[t][c];
        }
        __syncthreads();    // prefix reads of Ls done before overwrites below
        float bc = bonus[h * DKH + c];
        #pragma unroll
        for (int tt2 = 0; tt2 < 16; tt2++) {
            int t = hf * 16 + tt2;
            size_t g = (size_t)(tok0 + t) * KDIM + h * DKH + c;
            float e = Ls[t][c];
            float rv = rs[t][c];
            float kv = kt[t][c];
            rb[g] = rv * __expf(-run);
            Ls[t][c] = rv * kv * bc;          // bonus partial
            run += e;
            float ks = kv * __expf(run);
            kt[t][c] = ks;
            kb[g] = ks;
        }
        if (hf) {
            float dt = __expf(-run);
            Dts[c] = dt;
            Db[(size_t)(bh * NCK + ck) * 128 + c] = dt;
        }
    }
    __syncthreads();
    // u reduction: 256 threads = 32 t x 8 segs of 16
    {
        int t = tid >> 3, seg = tid & 7;
        float s = 0.f;
        #pragma unroll
        for (int q = 0; q < 16; q++) s += Ls[t][seg * 16 + q];
        up[t][seg] = s;
    }
    __syncthreads();
    if (tid < CK) {
        float s = 0.f;
        #pragma unroll
        for (int q = 0; q < 8; q++) s += up[tid][q];
        ub[(size_t)(tok0 + tid) * NHD + h] = s;
    }
    for (int jb = 0; jb < 4; jb++) {
        {
            int j = tid & 63, r0 = tid >> 6;
            #pragma unroll
            for (int i = 0; i < 8; i++) {
                int s = r0 + 4 * i;
                vsm[s][j] = vb[(size_t)(tok0 + s) * VDIM + h * DVH + jb * 64 + j];
            }
        }
        __syncthreads();
        {
            int kk0 = (tid >> 3) * 4;
            int j0 = (tid & 7) * 8;
            float m[4][8] = {};
            for (int s = 0; s < CK; s++) {
                float4 kv = *(const float4*)&kt[s][kk0];
                float4 v0 = *(const float4*)&vsm[s][j0];
                float4 v1 = *(const float4*)&vsm[s][j0 + 4];
                float ka[4] = {kv.x, kv.y, kv.z, kv.w};
                float va[8] = {v0.x, v0.y, v0.z, v0.w, v1.x, v1.y, v1.z, v1.w};
                #pragma unroll
                for (int i = 0; i < 4; i++)
                    #pragma unroll
                    for (int jj = 0; jj < 8; jj++)
                        m[i][jj] += ka[i] * va[jj];
            }
            #pragma unroll
            for (int i = 0; i < 4; i++) {
                float d = Dts[kk0 + i];
                size_t mb = ((size_t)(bh * NCK + ck) * 128 + kk0 + i) * DVH + jb * 64 + j0;
                *(float4*)(Mb + mb)     = make_float4(m[i][0] * d, m[i][1] * d, m[i][2] * d, m[i][3] * d);
                *(float4*)(Mb + mb + 4) = make_float4(m[i][4] * d, m[i][5] * d, m[i][6] * d, m[i][7] * d);
            }
        }
        __syncthreads();
    }
}

// ---------------------------------------------------------------------------
// Kernel 5b (chunkB): sequential over chunks with register prefetch.
// grid (16 bh, 32 j-slices of 8), 4 kk per thread.
// ---------------------------------------------------------------------------
__global__ __launch_bounds__(256) void k_chunkB(
    float* __restrict__ MS, const float* __restrict__ Db)
{
    int bh = blockIdx.x;
    int jsl = blockIdx.y;
    int tid = threadIdx.x;
    int j = jsl * 8 + (tid & 7);
    int kk0 = (tid >> 3) * 4;
    float S[4] = {};
    float m[4], d[4];
    {
        size_t kb0 = (size_t)(bh * NCK) * 128;
        #pragma unroll
        for (int i = 0; i < 4; i++) {
            m[i] = MS[(kb0 + kk0 + i) * DVH + j];
            d[i] = Db[kb0 + kk0 + i];
        }
    }
    for (int c = 0; c < NCK; c++) {
        size_t kbc = (size_t)(bh * NCK + c) * 128;
        float mc[4], dc[4];
        #pragma unroll
        for (int i = 0; i < 4; i++) { mc[i] = m[i]; dc[i] = d[i]; }
        if (c + 1 < NCK) {
            size_t kbn = (size_t)(bh * NCK + c + 1) * 128;
            #pragma unroll
            for (int i = 0; i < 4; i++) {
                m[i] = MS[(kbn + kk0 + i) * DVH + j];
                d[i] = Db[kbn + kk0 + i];
            }
        }
        #pragma unroll
        for (int i = 0; i < 4; i++) {
            MS[(kbc + kk0 + i) * DVH + j] = S[i];
            S[i] = S[i] * dc[i] + mc[i];
        }
    }
}

// ---------------------------------------------------------------------------
// Kernel 5c (chunkCG, fused, 512 threads): P = mask(r~ k~^T, diag=u);
// o = P@v + r~@S (f32 regs); groupnorm; silu(g) gate; y f32 IN PLACE over v.
// ---------------------------------------------------------------------------
__global__ __launch_bounds__(512) void k_chunkCG(
    const float* __restrict__ rb, const float* __restrict__ kb,
    float* __restrict__ vb, const float* __restrict__ ub,
    const float* __restrict__ Sb, const float* __restrict__ gb_,
    const float* __restrict__ gnw, const float* __restrict__ gnb)
{
    int bh = blockIdx.x, ck = blockIdx.y;
    int h = bh & 3, b = bh >> 2;
    int tok0 = b * TT + ck * CK;
    int tid = threadIdx.x;
    __shared__ float rt[CK][129];
    __shared__ float kt[CK][129];
    __shared__ float Ps[CK][33];
    __shared__ float vsm[CK][256];
    #pragma unroll
    for (int i = 0; i < 8; i++) {
        int idx = i * 512 + tid;
        int t = idx >> 7, c = idx & 127;
        size_t g = (size_t)(tok0 + t) * KDIM + h * DKH + c;
        rt[t][c] = rb[g];
        kt[t][c] = kb[g];
    }
    {
        int r0 = tid >> 4, c0 = (tid & 15) * 16;
        const float* vp = vb + (size_t)(tok0 + r0) * VDIM + h * DVH + c0;
        #pragma unroll
        for (int j = 0; j < 16; j += 4) {
            float4 v4 = *(const float4*)(vp + j);
            vsm[r0][c0 + j + 0] = v4.x; vsm[r0][c0 + j + 1] = v4.y;
            vsm[r0][c0 + j + 2] = v4.z; vsm[r0][c0 + j + 3] = v4.w;
        }
    }
    __syncthreads();
    // P: 2 entries per thread
    {
        int t = tid >> 4;
        int s0 = (tid & 15) * 2;
        float a0 = 0.f, a1 = 0.f;
        for (int k4 = 0; k4 < 128; k4 += 4) {
            float4 a = *(const float4*)&rt[t][k4];
            float4 b0 = *(const float4*)&kt[s0][k4];
            float4 b1 = *(const float4*)&kt[s0 + 1][k4];
            a0 += a.x * b0.x + a.y * b0.y + a.z * b0.z + a.w * b0.w;
            a1 += a.x * b1.x + a.y * b1.y + a.z * b1.z + a.w * b1.w;
        }
        float u0 = ub[(size_t)(tok0 + t) * NHD + h];
        Ps[t][s0]     = (s0 < t)     ? a0 : (s0 == t     ? u0 : 0.f);
        Ps[t][s0 + 1] = (s0 + 1 < t) ? a1 : (s0 + 1 == t ? u0 : 0.f);
    }
    __syncthreads();
    int t0 = (tid >> 5) * 2;
    int j0 = (tid & 31) * 8;
    float acc[2][8] = {};
    // intra-chunk: P @ v
    for (int s = 0; s < CK; s++) {
        float va[8];
        #pragma unroll
        for (int jj = 0; jj < 8; jj++) va[jj] = vsm[s][j0 + jj];
        float p0 = Ps[t0][s], p1 = Ps[t0 + 1][s];
        #pragma unroll
        for (int jj = 0; jj < 8; jj++) {
            acc[0][jj] += p0 * va[jj];
            acc[1][jj] += p1 * va[jj];
        }
    }
    // inter-chunk: r~ @ S
    size_t sbase = (size_t)(bh * NCK + ck) * 128 * DVH;
    for (int kk = 0; kk < 128; kk++) {
        const float* srow = Sb + sbase + (size_t)kk * DVH + j0;
        float4 s0v = *(const float4*)(srow);
        float4 s1v = *(const float4*)(srow + 4);
        float sv[8] = {s0v.x, s0v.y, s0v.z, s0v.w, s1v.x, s1v.y, s1v.z, s1v.w};
        float a0 = rt[t0][kk], a1 = rt[t0 + 1][kk];
        #pragma unroll
        for (int jj = 0; jj < 8; jj++) {
            acc[0][jj] += a0 * sv[jj];
            acc[1][jj] += a1 * sv[jj];
        }
    }
    // groupnorm + affine + silu(g) gate, y f32 in place over v
    int c = h * DVH + j0;
    float4 gw0 = *(const float4*)(gnw + c);
    float4 gw1 = *(const float4*)(gnw + c + 4);
    float4 gb0 = *(const float4*)(gnb + c);
    float4 gb1 = *(const float4*)(gnb + c + 4);
    float gwv[8] = {gw0.x, gw0.y, gw0.z, gw0.w, gw1.x, gw1.y, gw1.z, gw1.w};
    float gbv[8] = {gb0.x, gb0.y, gb0.z, gb0.w, gb1.x, gb1.y, gb1.z, gb1.w};
    #pragma unroll
    for (int i = 0; i < 2; i++) {
        float sum = 0.f, sq = 0.f;
        #pragma unroll
        for (int jj = 0; jj < 8; jj++) { sum += acc[i][jj]; sq += acc[i][jj] * acc[i][jj]; }
        #pragma unroll
        for (int m = 1; m < 32; m <<= 1) {
            sum += __shfl_xor(sum, m);
            sq  += __shfl_xor(sq, m);
        }
        float mean = sum * (1.f / DVH);
        float var = sq * (1.f / DVH) - mean * mean;
        float inv = rsqrtf(var + 1e-5f);
        size_t mrow = (size_t)(tok0 + t0 + i) * VDIM + c;
        float4 g0 = *(const float4*)(gb_ + mrow);
        float4 g1 = *(const float4*)(gb_ + mrow + 4);
        float gv[8] = {g0.x, g0.y, g0.z, g0.w, g1.x, g1.y, g1.z, g1.w};
        float o8[8];
        #pragma unroll
        for (int jj = 0; jj < 8; jj++) {
            float gg = gv[jj];
            float sig = 1.f / (1.f + __expf(-gg));
            o8[jj] = ((acc[i][jj] - mean) * inv * gwv[jj] + gbv[jj]) * (gg * sig);
        }
        *(float4*)(vb + mrow)     = make_float4(o8[0], o8[1], o8[2], o8[3]);
        *(float4*)(vb + mrow + 4) = make_float4(o8[4], o8[5], o8[6], o8[7]);
    }
}

// ---------------------------------------------------------------------------
// Kernel 6: output GEMM, split precision
// ---------------------------------------------------------------------------
__global__ __launch_bounds__(256) void k_gemm_out(
    const float* __restrict__ A, const bf16* __restrict__ Bh,
    const bf16* __restrict__ Bl, float* __restrict__ C, int M, int N, int K)
{
    __shared__ unsigned short Ah[128 * 32];
    __shared__ unsigned short Al[128 * 32];
    __shared__ unsigned short Bhs[128 * 32];
    __shared__ unsigned short Bls[128 * 32];
    int tid = threadIdx.x;
    int bm = blockIdx.x * 128, bn = blockIdx.y * 128;
    int lane = tid & 63, w = tid >> 6;
    int wr = w >> 1, wc = w & 1;
    const unsigned short* Bh16 = (const unsigned short*)Bh;
    const unsigned short* Bl16 = (const unsigned short*)Bl;
    f32x4 acc[4][4];
    #pragma unroll
    for (int i = 0; i < 4; i++)
        #pragma unroll
        for (int j = 0; j < 4; j++)
            acc[i][j] = (f32x4){0.f, 0.f, 0.f, 0.f};
    int arow = tid >> 1, acol = (tid & 1) * 16;
    int ch0 = tid, ch1 = tid + 256;
    int r0c = ch0 >> 2, c0c = (ch0 & 3) * 8;
    int r1c = ch1 >> 2, c1c = (ch1 & 3) * 8;
    int fr = lane & 15, kb = (lane >> 4) * 8;
    for (int k0 = 0; k0 < K; k0 += 32) {
        float av[16];
        #pragma unroll
        for (int q = 0; q < 4; q++) {
            float4 t4 = *(const float4*)(A + (size_t)(bm + arow) * K + k0 + acol + q * 4);
            av[q * 4 + 0] = t4.x; av[q * 4 + 1] = t4.y;
            av[q * 4 + 2] = t4.z; av[q * 4 + 3] = t4.w;
        }
        uint4 bh0 = *(const uint4*)(Bh16 + (size_t)(bn + r0c) * K + k0 + c0c);
        uint4 bh1 = *(const uint4*)(Bh16 + (size_t)(bn + r1c) * K + k0 + c1c);
        uint4 bl0 = *(const uint4*)(Bl16 + (size_t)(bn + r0c) * K + k0 + c0c);
        uint4 bl1 = *(const uint4*)(Bl16 + (size_t)(bn + r1c) * K + k0 + c1c);
        __syncthreads();
        alignas(16) unsigned short th[16], tl[16];
        #pragma unroll
        for (int q = 0; q < 16; q++) {
            unsigned short hu = f2u(av[q]);
            th[q] = hu;
            tl[q] = f2u(av[q] - u2f(hu));
        }
        *(uint4*)(Ah + arow * 32 + acol)     = *(const uint4*)&th[0];
        *(uint4*)(Ah + arow * 32 + acol + 8) = *(const uint4*)&th[8];
        *(uint4*)(Al + arow * 32 + acol)     = *(const uint4*)&tl[0];
        *(uint4*)(Al + arow * 32 + acol + 8) = *(const uint4*)&tl[8];
        *(uint4*)(Bhs + ch0 * 8) = bh0;
        *(uint4*)(Bhs + ch1 * 8) = bh1;
        *(uint4*)(Bls + ch0 * 8) = bl0;
        *(uint4*)(Bls + ch1 * 8) = bl1;
        __syncthreads();
        bf16x8 afh[4], afl[4], bfh[4], bfl[4];
        #pragma unroll
        for (int i = 0; i < 4; i++) {
            afh[i] = *(const bf16x8*)(Ah + (wr * 64 + i * 16 + fr) * 32 + kb);
            afl[i] = *(const bf16x8*)(Al + (wr * 64 + i * 16 + fr) * 32 + kb);
            bfh[i] = *(const bf16x8*)(Bhs + (wc * 64 + i * 16 + fr) * 32 + kb);
            bfl[i] = *(const bf16x8*)(Bls + (wc * 64 + i * 16 + fr) * 32 + kb);
        }
        #pragma unroll
        for (int i = 0; i < 4; i++)
            #pragma unroll
            for (int j = 0; j < 4; j++) {
                acc[i][j] = __builtin_amdgcn_mfma_f32_16x16x32_bf16(afh[i], bfh[j], acc[i][j], 0, 0, 0);
                acc[i][j] = __builtin_amdgcn_mfma_f32_16x16x32_bf16(afl[i], bfh[j], acc[i][j], 0, 0, 0);
                acc[i][j] = __builtin_amdgcn_mfma_f32_16x16x32_bf16(afh[i], bfl[j], acc[i][j], 0, 0, 0);
            }
    }
    int er = (lane >> 4) * 4, ec = lane & 15;
    #pragma unroll
    for (int i = 0; i < 4; i++) {
        int gr = bm + wr * 64 + i * 16 + er;
        #pragma unroll
        for (int j = 0; j < 4; j++) {
            int gc = bn + wc * 64 + j * 16 + ec;
            #pragma unroll
            for (int q = 0; q < 4; q++)
                C[(size_t)(gr + q) * N + gc] = acc[i][j][q];
        }
    }
}

// ---------------------------------------------------------------------------
extern "C" void kernel_launch(void* const* d_in, const int* in_sizes, int n_in,
                              void* d_out, int out_size, void* d_ws, size_t ws_size,
                              hipStream_t stream)
{
    const float* h        = (const float*)d_in[0];
    const float* x_mu     = (const float*)d_in[1];
    const float* xl_w1    = (const float*)d_in[2];
    const float* xl_w2    = (const float*)d_in[3];
    const float* xl_b2    = (const float*)d_in[4];
    const float* x_out_w  = (const float*)d_in[5];
    const float* x_bias   = (const float*)d_in[6];
    const float* r_w      = (const float*)d_in[7];
    const float* w_w1     = (const float*)d_in[8];
    const float* w_w2     = (const float*)d_in[9];
    const float* w_b      = (const float*)d_in[10];
    const float* k_w      = (const float*)d_in[11];
    const float* v_w      = (const float*)d_in[12];
    const float* g_w      = (const float*)d_in[13];
    const float* bonus    = (const float*)d_in[14];
    const float* gn_w     = (const float*)d_in[15];
    const float* gn_b     = (const float*)d_in[16];
    const float* o_w      = (const float*)d_in[17];
    float* out = (float*)d_out;

    // Workspace overlay: total 35,733,504 floats = 142.9 MB (proven size)
    float* ws = (float*)d_ws;
    bf16*  wbf  = (bf16*)ws;                       // 8,388,608 bf16 = 4,194,304 slots
    float* rbuf = ws + 4194304;                    // 2,097,152
    float* vbuf = ws + 6291456;                    // 4,194,304 (y f32 in place later)
    float* gbuf = ws + 10485760;                   // 4,194,304
    float* kbuf = ws + 14680064;                   // 2,097,152
    float* ebuf = ws + 16777216;                   // 2,097,152
    float* ubuf = ws + 18874368;                   // 16,384
    float* Dbuf = ws + 18890752;                   // 65,536
    float* BIG  = ws + 18956288;                   // 16,777,216 (X phase / Mbuf)

    // weight hi/lo (bf16 element offsets within wbf)
    bf16* rwb_h = wbf;                  // 524,288
    bf16* kwb_h = wbf + 524288;
    bf16* vwb_h = wbf + 1048576;        // 1,048,576
    bf16* gwb_h = wbf + 2097152;
    bf16* owb_h = wbf + 3145728;
    bf16* rwb_l = wbf + 4194304;
    bf16* kwb_l = wbf + 4718592;
    bf16* vwb_l = wbf + 5242880;
    bf16* gwb_l = wbf + 6291456;
    bf16* owb_l = wbf + 7340032;

    // X phase inside BIG (each bf16 X = 2,097,152 float slots)
    float* Xw = BIG;                           // f32 [0 .. 4,194,304)
    bf16*  Xr = (bf16*)(BIG + 4194304);
    bf16*  Xk = (bf16*)(BIG + 6291456);
    bf16*  Xv = (bf16*)(BIG + 8388608);
    bf16*  Xg = (bf16*)(BIG + 10485760);
    float* x1   = BIG + 12582912;              // 655,360  (dead after mix)
    float* t0bf = BIG + 13238272;              // 131,072  (dead after k_x1b)
    float* Mbuf = BIG;                         // full 16,777,216 after X dead
    float* ybuf = vbuf;                        // y f32 in place over v

    // weight conversion (hi/lo pairs), single launch
    k_f2b2_all<<<2048, 256, 0, stream>>>(r_w, k_w, v_w, g_w, o_w,
                                         rwb_h, rwb_l, kwb_h, kwb_l,
                                         vwb_h, vwb_l, gwb_h, gwb_l,
                                         owb_h, owb_l);

    // x1 path: MFMA phase-1 + small phase-2
    k_x1mm<<<NTOK / 64, 256, 0, stream>>>(h, x_mu, xl_w1, t0bf);
    k_x1b<<<NTOK / 64, 256, 0, stream>>>(t0bf, xl_w2, xl_b2, x1);

    // mix: f32 w-slice + MFMA bf16 four-slice
    k_mixw<<<dim3(NTOK / 64, HH / 64), 256, 0, stream>>>(h, x1, x_out_w, x_bias, Xw);
    k_mix4<<<dim3(NTOK / 64, HH / 64), 256, 0, stream>>>(h, x1, x_out_w, x_bias,
                                                         Xr, Xk, Xv, Xg);

    // projections: fused hi/lo MFMA for r/k/v/g, fp32 for the w path
    k_gemm_hl<<<dim3(NTOK / 128, KDIM / 128), 256, 0, stream>>>(Xr, rwb_h, rwb_l, rbuf, NTOK, KDIM, HH);
    k_gemm_hl<<<dim3(NTOK / 128, KDIM / 128), 256, 0, stream>>>(Xk, kwb_h, kwb_l, kbuf, NTOK, KDIM, HH);
    k_gemm_hl<<<dim3(NTOK / 128, VDIM / 128), 256, 0, stream>>>(Xv, vwb_h, vwb_l, vbuf, NTOK, VDIM, HH);
    k_gemm_hl<<<dim3(NTOK / 128, VDIM / 128), 256, 0, stream>>>(Xg, gwb_h, gwb_l, gbuf, NTOK, VDIM, HH);
    k_gemm<1><<<dim3(NTOK / 64, GG / 64), 256, 0, stream>>>(Xw, w_w1, nullptr, x1, NTOK, GG, HH);
    k_gemm<2><<<dim3(NTOK / 64, KDIM / 64), 256, 0, stream>>>(x1, w_w2, w_b, ebuf, NTOK, KDIM, GG);

    k_chunkA1<<<dim3(BB * NHD, NCK), 256, 0, stream>>>(ebuf, rbuf, kbuf, vbuf,
                                                       bonus, ubuf, Mbuf, Dbuf);
    k_chunkB<<<dim3(BB * NHD, 32), 256, 0, stream>>>(Mbuf, Dbuf);
    k_chunkCG<<<dim3(BB * NHD, NCK), 512, 0, stream>>>(rbuf, kbuf, vbuf, ubuf, Mbuf,
                                                       gbuf, gn_w, gn_b);

    k_gemm_out<<<dim3(NTOK / 128, HH / 128), 256, 0, stream>>>(ybuf, owb_h, owb_l, out, NTOK, HH, VDIM);
}

// Round 9
// 391.154 us; speedup vs baseline: 5.8253x; 1.0818x over previous
//
#include <hip/hip_runtime.h>
#include <hip/hip_bf16.h>
#include <math.h>

// Problem constants
static constexpr int BB = 4;
static constexpr int TT = 1024;
static constexpr int HH = 1024;
static constexpr int NHD = 4;
static constexpr int KDIM = 512;
static constexpr int VDIM = 1024;
static constexpr int DKH = 128;   // KD / NH
static constexpr int DVH = 256;   // VD / NH
static constexpr int RR = 32;
static constexpr int R5D = 160;
static constexpr int GG = 64;
static constexpr int NTOK = BB * TT;   // 4096
static constexpr int CK = 32;          // chunk length
static constexpr int NCK = TT / CK;    // 32 chunks per sequence
static constexpr int WKS = 8;          // split-K factor for the w1 gemm

typedef __bf16 bf16x8 __attribute__((ext_vector_type(8)));
typedef float f32x4 __attribute__((ext_vector_type(4)));
typedef __hip_bfloat16 bf16;

static __device__ inline unsigned short f2u(float v) {
    __hip_bfloat16 b = __float2bfloat16(v);
    unsigned short u; __builtin_memcpy(&u, &b, 2); return u;
}
static __device__ inline float u2f(unsigned short u) {
    __hip_bfloat16 b; __builtin_memcpy(&b, &u, 2); return __bfloat162float(b);
}

// ---------------------------------------------------------------------------
// Kernel 0: f32 -> bf16 hi/lo pairs, all 5 weights in one launch
// ---------------------------------------------------------------------------
__global__ __launch_bounds__(256) void k_f2b2_all(
    const float* __restrict__ r_w, const float* __restrict__ k_w,
    const float* __restrict__ v_w, const float* __restrict__ g_w,
    const float* __restrict__ o_w,
    bf16* __restrict__ rh, bf16* __restrict__ rl,
    bf16* __restrict__ kh, bf16* __restrict__ kl,
    bf16* __restrict__ vh, bf16* __restrict__ vl,
    bf16* __restrict__ gh, bf16* __restrict__ gl,
    bf16* __restrict__ oh, bf16* __restrict__ ol)
{
    size_t g = ((size_t)blockIdx.x * 256 + threadIdx.x) * 8;
    const float* s; bf16 *hi, *lo; size_t off;
    if (g < 524288)       { s = r_w; hi = rh; lo = rl; off = g; }
    else if (g < 1048576) { s = k_w; hi = kh; lo = kl; off = g - 524288; }
    else if (g < 2097152) { s = v_w; hi = vh; lo = vl; off = g - 1048576; }
    else if (g < 3145728) { s = g_w; hi = gh; lo = gl; off = g - 2097152; }
    else                  { s = o_w; hi = oh; lo = ol; off = g - 3145728; }
    #pragma unroll
    for (int j = 0; j < 8; j++) {
        float v = s[off + j];
        bf16 hb = __float2bfloat16(v);
        hi[off + j] = hb;
        lo[off + j] = __float2bfloat16(v - __bfloat162float(hb));
    }
}

// ---------------------------------------------------------------------------
// Kernel 1a (k_x1mm): t0[4096x32] = tanh( x_lerp @ w1^T ) via bf16 MFMA.
// ---------------------------------------------------------------------------
__global__ __launch_bounds__(256) void k_x1mm(
    const float* __restrict__ h, const float* __restrict__ mu,
    const float* __restrict__ w1, float* __restrict__ t0)
{
    __shared__ unsigned short Al[64][40];
    __shared__ unsigned short Bl[32][40];
    int tid = threadIdx.x;
    int m0 = blockIdx.x * 64;
    int lane = tid & 63, w = tid >> 6;
    f32x4 acc[2];
    acc[0] = (f32x4){0.f, 0.f, 0.f, 0.f};
    acc[1] = (f32x4){0.f, 0.f, 0.f, 0.f};
    int ar = tid >> 2, ac0 = (tid & 3) * 8;        // A stage: 64x32, 8 per thread
    int br = tid >> 3, bc0 = (tid & 7) * 4;        // B stage: 32x32, 4 per thread
    int fr = lane & 15, kb = lane >> 4;
    int mrow = m0 + ar;
    int trow = mrow & (TT - 1);
    const float* hp = h + (size_t)mrow * HH;
    for (int k0 = 0; k0 < HH; k0 += 32) {
        float av[8];
        #pragma unroll
        for (int j = 0; j < 8; j += 4) {
            float4 c4 = *(const float4*)(hp + k0 + ac0 + j);
            float4 p4 = make_float4(0.f, 0.f, 0.f, 0.f);
            if (trow > 0) p4 = *(const float4*)(hp + k0 + ac0 + j - HH);
            float4 m4 = *(const float4*)(mu + k0 + ac0 + j);
            av[j + 0] = c4.x + (p4.x - c4.x) * m4.x;
            av[j + 1] = c4.y + (p4.y - c4.y) * m4.y;
            av[j + 2] = c4.z + (p4.z - c4.z) * m4.z;
            av[j + 3] = c4.w + (p4.w - c4.w) * m4.w;
        }
        float4 b4 = *(const float4*)(w1 + (size_t)br * HH + k0 + bc0);
        __syncthreads();
        #pragma unroll
        for (int j = 0; j < 8; j++) Al[ar][ac0 + j] = f2u(av[j]);
        Bl[br][bc0 + 0] = f2u(b4.x); Bl[br][bc0 + 1] = f2u(b4.y);
        Bl[br][bc0 + 2] = f2u(b4.z); Bl[br][bc0 + 3] = f2u(b4.w);
        __syncthreads();
        bf16x8 af = *(const bf16x8*)(&Al[w * 16 + fr][kb * 8]);
        bf16x8 bf0 = *(const bf16x8*)(&Bl[fr][kb * 8]);
        bf16x8 bf1 = *(const bf16x8*)(&Bl[16 + fr][kb * 8]);
        acc[0] = __builtin_amdgcn_mfma_f32_16x16x32_bf16(af, bf0, acc[0], 0, 0, 0);
        acc[1] = __builtin_amdgcn_mfma_f32_16x16x32_bf16(af, bf1, acc[1], 0, 0, 0);
    }
    int er = (lane >> 4) * 4, ec = lane & 15;
    #pragma unroll
    for (int j = 0; j < 2; j++) {
        #pragma unroll
        for (int q = 0; q < 4; q++) {
            int gr = m0 + w * 16 + er + q;
            t0[(size_t)gr * RR + j * 16 + ec] = tanhf(acc[j][q]);
        }
    }
}

// ---------------------------------------------------------------------------
// Kernel 1b (k_x1b): x1[4096x160] = tanh( t0 @ w2^T + b2 ).  K=32.
// ---------------------------------------------------------------------------
__global__ __launch_bounds__(256) void k_x1b(
    const float* __restrict__ t0, const float* __restrict__ w2,
    const float* __restrict__ b2, float* __restrict__ x1out)
{
    __shared__ float t0s[64][33];
    __shared__ float w2s[R5D * RR];
    __shared__ float b2s[R5D];
    int tid = threadIdx.x;
    int m0 = blockIdx.x * 64;
    {
        int row = tid >> 2, c0 = (tid & 3) * 8;
        float4 a = *(const float4*)(t0 + (size_t)(m0 + row) * RR + c0);
        float4 b = *(const float4*)(t0 + (size_t)(m0 + row) * RR + c0 + 4);
        t0s[row][c0 + 0] = a.x; t0s[row][c0 + 1] = a.y;
        t0s[row][c0 + 2] = a.z; t0s[row][c0 + 3] = a.w;
        t0s[row][c0 + 4] = b.x; t0s[row][c0 + 5] = b.y;
        t0s[row][c0 + 6] = b.z; t0s[row][c0 + 7] = b.w;
    }
    for (int i = tid; i < R5D * RR; i += 256) w2s[i] = w2[i];
    if (tid < R5D) b2s[tid] = b2[tid];
    __syncthreads();
    int tt = tid & 63, cg = tid >> 6;
    float t0r[32];
    #pragma unroll
    for (int q = 0; q < 32; q++) t0r[q] = t0s[tt][q];
    float* xo = x1out + (size_t)(m0 + tt) * R5D + cg * 40;
    for (int c = 0; c < 40; c++) {
        const float* wr = w2s + (cg * 40 + c) * RR;
        float s = b2s[cg * 40 + c];
        #pragma unroll
        for (int q = 0; q < 32; q++) s += t0r[q] * wr[q];
        xo[c] = tanhf(s);
    }
}

// ---------------------------------------------------------------------------
// Kernel 2a (k_mixw): n=1 slice only (w path, f32 exact).
// ---------------------------------------------------------------------------
__global__ __launch_bounds__(256) void k_mixw(
    const float* __restrict__ h, const float* __restrict__ x1,
    const float* __restrict__ xow, const float* __restrict__ xb,
    float* __restrict__ xw)
{
    int m0 = blockIdx.x * 64;
    int h0 = blockIdx.y * 64;
    int tid = threadIdx.x;
    __shared__ float x1sT[32][68];
    __shared__ float xosT[32][68];
    int rr = tid & 63, cg = tid >> 6;    // cg = wave id, 8 cols each
    {
        const float* xp = x1 + (size_t)(m0 + rr) * R5D + 32 + cg * 8;
        const float* wp = xow + (size_t)(h0 + rr) * R5D + 32 + cg * 8;
        float4 a0 = *(const float4*)xp, a1 = *(const float4*)(xp + 4);
        float4 b0 = *(const float4*)wp, b1 = *(const float4*)(wp + 4);
        x1sT[cg * 8 + 0][rr] = a0.x; x1sT[cg * 8 + 1][rr] = a0.y;
        x1sT[cg * 8 + 2][rr] = a0.z; x1sT[cg * 8 + 3][rr] = a0.w;
        x1sT[cg * 8 + 4][rr] = a1.x; x1sT[cg * 8 + 5][rr] = a1.y;
        x1sT[cg * 8 + 6][rr] = a1.z; x1sT[cg * 8 + 7][rr] = a1.w;
        xosT[cg * 8 + 0][rr] = b0.x; xosT[cg * 8 + 1][rr] = b0.y;
        xosT[cg * 8 + 2][rr] = b0.z; xosT[cg * 8 + 3][rr] = b0.w;
        xosT[cg * 8 + 4][rr] = b1.x; xosT[cg * 8 + 5][rr] = b1.y;
        xosT[cg * 8 + 6][rr] = b1.z; xosT[cg * 8 + 7][rr] = b1.w;
    }
    int tx = tid & 15, ty = tid >> 4;
    float creg[4][4], dreg[4][4];
    #pragma unroll
    for (int i = 0; i < 4; i++) {
        int m = m0 + ty * 4 + i;
        int t = m & (TT - 1);
        const float* hp = h + (size_t)m * HH + h0 + tx * 4;
        float4 c4 = *(const float4*)hp;
        float4 p4 = make_float4(0.f, 0.f, 0.f, 0.f);
        if (t > 0) p4 = *(const float4*)(hp - HH);
        creg[i][0] = c4.x; dreg[i][0] = p4.x - c4.x;
        creg[i][1] = c4.y; dreg[i][1] = p4.y - c4.y;
        creg[i][2] = c4.z; dreg[i][2] = p4.z - c4.z;
        creg[i][3] = c4.w; dreg[i][3] = p4.w - c4.w;
    }
    __syncthreads();
    float acc[4][4] = {};
    #pragma unroll
    for (int r2 = 0; r2 < 32; r2++) {
        float4 a4 = *(const float4*)&x1sT[r2][ty * 4];
        float4 b4 = *(const float4*)&xosT[r2][tx * 4];
        float aa[4] = {a4.x, a4.y, a4.z, a4.w};
        float bb[4] = {b4.x, b4.y, b4.z, b4.w};
        #pragma unroll
        for (int i = 0; i < 4; i++)
            #pragma unroll
            for (int j = 0; j < 4; j++)
                acc[i][j] += aa[i] * bb[j];
    }
    float4 xb4 = *(const float4*)(xb + HH + h0 + tx * 4);   // n=1 row of x_bias
    float xbv[4] = {xb4.x, xb4.y, xb4.z, xb4.w};
    #pragma unroll
    for (int i = 0; i < 4; i++) {
        size_t idx = (size_t)(m0 + ty * 4 + i) * HH + h0 + tx * 4;
        float v[4];
        #pragma unroll
        for (int j = 0; j < 4; j++)
            v[j] = creg[i][j] + dreg[i][j] * (acc[i][j] + xbv[j]);
        *(float4*)(xw + idx) = make_float4(v[0], v[1], v[2], v[3]);
    }
}

// ---------------------------------------------------------------------------
// Kernel 2b (k_mix4): n in {0,2,3,4} via direct-from-global MFMA fragments.
// ---------------------------------------------------------------------------
__global__ __launch_bounds__(256) void k_mix4(
    const float* __restrict__ h, const float* __restrict__ x1,
    const float* __restrict__ xow, const float* __restrict__ xb,
    bf16* __restrict__ xr, bf16* __restrict__ xk,
    bf16* __restrict__ xv, bf16* __restrict__ xg)
{
    int m0 = blockIdx.x * 64;
    int h0 = blockIdx.y * 64;
    int tid = threadIdx.x;
    int lane = tid & 63, w = tid >> 6;
    int fr = lane & 15, kb = (lane >> 4) * 8;
    int er = (lane >> 4) * 4, ec = lane & 15;
    float creg[4][4], dreg[4][4];
    #pragma unroll
    for (int q = 0; q < 4; q++) {
        int m = m0 + w * 16 + er + q;
        int t = m & (TT - 1);
        const float* hp = h + (size_t)m * HH;
        #pragma unroll
        for (int j = 0; j < 4; j++) {
            int hh = h0 + j * 16 + ec;
            float c = hp[hh];
            float p = (t > 0) ? hp[hh - HH] : 0.f;
            creg[q][j] = c;
            dreg[q][j] = p - c;
        }
    }
    bf16* outs[4] = {xr, xk, xv, xg};
    const int ns[4] = {0, 2, 3, 4};
    #pragma unroll
    for (int ni = 0; ni < 4; ni++) {
        int n = ns[ni];
        const float* ap = x1 + (size_t)(m0 + w * 16 + fr) * R5D + n * 32 + kb;
        float4 a0 = *(const float4*)ap;
        float4 a1 = *(const float4*)(ap + 4);
        alignas(16) unsigned short ta[8];
        ta[0] = f2u(a0.x); ta[1] = f2u(a0.y); ta[2] = f2u(a0.z); ta[3] = f2u(a0.w);
        ta[4] = f2u(a1.x); ta[5] = f2u(a1.y); ta[6] = f2u(a1.z); ta[7] = f2u(a1.w);
        bf16x8 af = *(const bf16x8*)ta;
        f32x4 accj[4];
        #pragma unroll
        for (int j = 0; j < 4; j++) {
            const float* bp = xow + (size_t)(h0 + j * 16 + fr) * R5D + n * 32 + kb;
            float4 b0 = *(const float4*)bp;
            float4 b1 = *(const float4*)(bp + 4);
            alignas(16) unsigned short tb[8];
            tb[0] = f2u(b0.x); tb[1] = f2u(b0.y); tb[2] = f2u(b0.z); tb[3] = f2u(b0.w);
            tb[4] = f2u(b1.x); tb[5] = f2u(b1.y); tb[6] = f2u(b1.z); tb[7] = f2u(b1.w);
            bf16x8 bf_ = *(const bf16x8*)tb;
            f32x4 z = (f32x4){0.f, 0.f, 0.f, 0.f};
            accj[j] = __builtin_amdgcn_mfma_f32_16x16x32_bf16(af, bf_, z, 0, 0, 0);
        }
        bf16* op = outs[ni];
        #pragma unroll
        for (int j = 0; j < 4; j++) {
            float xbv = xb[n * HH + h0 + j * 16 + ec];
            #pragma unroll
            for (int q = 0; q < 4; q++) {
                float val = creg[q][j] + dreg[q][j] * (accj[j][q] + xbv);
                op[(size_t)(m0 + w * 16 + er + q) * HH + h0 + j * 16 + ec] =
                    __float2bfloat16(val);
            }
        }
    }
}

// ---------------------------------------------------------------------------
// Kernel 3a (k_gemm_hl): C[M,N] f32 = A[M,K]bf16 @ (Bh+Bl)[N,K]bf16^T
// ---------------------------------------------------------------------------
__global__ __launch_bounds__(256) void k_gemm_hl(
    const bf16* __restrict__ A, const bf16* __restrict__ Bh,
    const bf16* __restrict__ Bl, float* __restrict__ C, int M, int N, int K)
{
    __shared__ unsigned short As[128 * 32];
    __shared__ unsigned short Bhs[128 * 32];
    __shared__ unsigned short Bls[128 * 32];
    int tid = threadIdx.x;
    int bm = blockIdx.x * 128, bn = blockIdx.y * 128;
    int lane = tid & 63, w = tid >> 6;
    int wr = w >> 1, wc = w & 1;
    const unsigned short* A16 = (const unsigned short*)A;
    const unsigned short* Bh16 = (const unsigned short*)Bh;
    const unsigned short* Bl16 = (const unsigned short*)Bl;
    f32x4 acc[4][4];
    #pragma unroll
    for (int i = 0; i < 4; i++)
        #pragma unroll
        for (int j = 0; j < 4; j++)
            acc[i][j] = (f32x4){0.f, 0.f, 0.f, 0.f};
    int ch0 = tid, ch1 = tid + 256;
    int r0c = ch0 >> 2, c0c = (ch0 & 3) * 8;
    int r1c = ch1 >> 2, c1c = (ch1 & 3) * 8;
    int fr = lane & 15, kb = (lane >> 4) * 8;
    for (int k0 = 0; k0 < K; k0 += 32) {
        uint4 a0 = *(const uint4*)(A16 + (size_t)(bm + r0c) * K + k0 + c0c);
        uint4 a1 = *(const uint4*)(A16 + (size_t)(bm + r1c) * K + k0 + c1c);
        uint4 bh0 = *(const uint4*)(Bh16 + (size_t)(bn + r0c) * K + k0 + c0c);
        uint4 bh1 = *(const uint4*)(Bh16 + (size_t)(bn + r1c) * K + k0 + c1c);
        uint4 bl0 = *(const uint4*)(Bl16 + (size_t)(bn + r0c) * K + k0 + c0c);
        uint4 bl1 = *(const uint4*)(Bl16 + (size_t)(bn + r1c) * K + k0 + c1c);
        __syncthreads();
        *(uint4*)(As + ch0 * 8) = a0;
        *(uint4*)(As + ch1 * 8) = a1;
        *(uint4*)(Bhs + ch0 * 8) = bh0;
        *(uint4*)(Bhs + ch1 * 8) = bh1;
        *(uint4*)(Bls + ch0 * 8) = bl0;
        *(uint4*)(Bls + ch1 * 8) = bl1;
        __syncthreads();
        bf16x8 af[4], bfh[4], bfl[4];
        #pragma unroll
        for (int i = 0; i < 4; i++) {
            af[i]  = *(const bf16x8*)(As + (wr * 64 + i * 16 + fr) * 32 + kb);
            bfh[i] = *(const bf16x8*)(Bhs + (wc * 64 + i * 16 + fr) * 32 + kb);
            bfl[i] = *(const bf16x8*)(Bls + (wc * 64 + i * 16 + fr) * 32 + kb);
        }
        #pragma unroll
        for (int i = 0; i < 4; i++)
            #pragma unroll
            for (int j = 0; j < 4; j++) {
                acc[i][j] = __builtin_amdgcn_mfma_f32_16x16x32_bf16(af[i], bfh[j], acc[i][j], 0, 0, 0);
                acc[i][j] = __builtin_amdgcn_mfma_f32_16x16x32_bf16(af[i], bfl[j], acc[i][j], 0, 0, 0);
            }
    }
    int er = (lane >> 4) * 4, ec = lane & 15;
    #pragma unroll
    for (int i = 0; i < 4; i++) {
        int gr = bm + wr * 64 + i * 16 + er;
        #pragma unroll
        for (int j = 0; j < 4; j++) {
            int gc = bn + wc * 64 + j * 16 + ec;
            #pragma unroll
            for (int q = 0; q < 4; q++)
                C[(size_t)(gr + q) * N + gc] = acc[i][j][q];
        }
    }
}

// ---------------------------------------------------------------------------
// Kernel 3b (k_w1): split-K partial GEMM for the w path.
// P[ks][4096][64] = Xw[.., ks*128..+128) @ w_w1[.., same)^T.  grid (64, 8).
// ---------------------------------------------------------------------------
__global__ __launch_bounds__(256) void k_w1(
    const float* __restrict__ A, const float* __restrict__ Bm,
    float* __restrict__ P)
{
    __shared__ float As[16][68];
    __shared__ float Bs[16][68];
    int tid = threadIdx.x;
    int bm = blockIdx.x * 64;
    int ks = blockIdx.y;
    int kbase = ks * (HH / WKS);       // 128-wide K slice
    int tx = tid & 15, ty = tid >> 4;
    int lr = tid >> 2;
    int lk = (tid & 3) * 4;
    float acc[4][4] = {};
    for (int k0 = 0; k0 < HH / WKS; k0 += 16) {
        float4 av = *(const float4*)(A + (size_t)(bm + lr) * HH + kbase + k0 + lk);
        float4 bv = *(const float4*)(Bm + (size_t)lr * HH + kbase + k0 + lk);
        As[lk + 0][lr] = av.x; As[lk + 1][lr] = av.y;
        As[lk + 2][lr] = av.z; As[lk + 3][lr] = av.w;
        Bs[lk + 0][lr] = bv.x; Bs[lk + 1][lr] = bv.y;
        Bs[lk + 2][lr] = bv.z; Bs[lk + 3][lr] = bv.w;
        __syncthreads();
        #pragma unroll
        for (int kk = 0; kk < 16; kk++) {
            float4 a4 = *(const float4*)&As[kk][ty * 4];
            float4 b4 = *(const float4*)&Bs[kk][tx * 4];
            float aa[4] = {a4.x, a4.y, a4.z, a4.w};
            float bb[4] = {b4.x, b4.y, b4.z, b4.w};
            #pragma unroll
            for (int i = 0; i < 4; i++)
                #pragma unroll
                for (int j = 0; j < 4; j++)
                    acc[i][j] += aa[i] * bb[j];
        }
        __syncthreads();
    }
    #pragma unroll
    for (int i = 0; i < 4; i++) {
        size_t row = (size_t)ks * NTOK + bm + ty * 4 + i;
        *(float4*)(P + row * GG + tx * 4) =
            make_float4(acc[i][0], acc[i][1], acc[i][2], acc[i][3]);
    }
}

// ---------------------------------------------------------------------------
// Kernel 3c (k_we): e = exp( tanh(sum_ks P) @ w_w2^T + w_b ).
// M=4096, N=512, K=64; 64x64 tile; grid (64, 8).
// ---------------------------------------------------------------------------
__global__ __launch_bounds__(256) void k_we(
    const float* __restrict__ P, const float* __restrict__ w_w2,
    const float* __restrict__ w_b, float* __restrict__ eb)
{
    __shared__ float As[64][65];
    __shared__ float Bs[64][65];
    int tid = threadIdx.x;
    int bm = blockIdx.x * 64, bn = blockIdx.y * 64;
    {
        int r = tid >> 2, c0 = (tid & 3) * 16;
        float s[16];
        #pragma unroll
        for (int j = 0; j < 16; j++) s[j] = 0.f;
        for (int ks = 0; ks < WKS; ks++) {
            const float* pp = P + ((size_t)ks * NTOK + bm + r) * GG + c0;
            #pragma unroll
            for (int j = 0; j < 16; j += 4) {
                float4 v = *(const float4*)(pp + j);
                s[j + 0] += v.x; s[j + 1] += v.y; s[j + 2] += v.z; s[j + 3] += v.w;
            }
        }
        #pragma unroll
        for (int j = 0; j < 16; j++) As[r][c0 + j] = tanhf(s[j]);
        const float* bp = w_w2 + (size_t)(bn + r) * GG + c0;
        #pragma unroll
        for (int j = 0; j < 16; j += 4) {
            float4 v = *(const float4*)(bp + j);
            Bs[r][c0 + j + 0] = v.x; Bs[r][c0 + j + 1] = v.y;
            Bs[r][c0 + j + 2] = v.z; Bs[r][c0 + j + 3] = v.w;
        }
    }
    __syncthreads();
    int tx = tid & 15, ty = tid >> 4;
    float acc[4][4] = {};
    #pragma unroll 8
    for (int kk = 0; kk < GG; kk++) {
        float aa[4], bb[4];
        #pragma unroll
        for (int i = 0; i < 4; i++) aa[i] = As[ty * 4 + i][kk];
        #pragma unroll
        for (int j = 0; j < 4; j++) bb[j] = Bs[tx * 4 + j][kk];
        #pragma unroll
        for (int i = 0; i < 4; i++)
            #pragma unroll
            for (int j = 0; j < 4; j++)
                acc[i][j] += aa[i] * bb[j];
    }
    float4 wb4 = *(const float4*)(w_b + bn + tx * 4);
    float wbv[4] = {wb4.x, wb4.y, wb4.z, wb4.w};
    #pragma unroll
    for (int i = 0; i < 4; i++) {
        float v[4];
        #pragma unroll
        for (int j = 0; j < 4; j++) v[j] = __expf(acc[i][j] + wbv[j]);
        *(float4*)(eb + (size_t)(bm + ty * 4 + i) * KDIM + bn + tx * 4) =
            make_float4(v[0], v[1], v[2], v[3]);
    }
}

// ---------------------------------------------------------------------------
// Kernel 5a (chunkA1): LDS-staged r/k/e; 2-way-parallel cumsum; r~,k~ in place;
// M = (k~ * Dtot)^T v; Dtot out; u fused.
// ---------------------------------------------------------------------------
__global__ __launch_bounds__(256) void k_chunkA1(
    const float* __restrict__ eb, float* __restrict__ rb,
    float* __restrict__ kb, const float* __restrict__ vb,
    const float* __restrict__ bonus, float* __restrict__ ub,
    float* __restrict__ Mb, float* __restrict__ Db)
{
    int bh = blockIdx.x;       // b*NH + h (h fast)
    int ck = blockIdx.y;       // 0..31
    int h = bh & 3, b = bh >> 2;
    int tok0 = b * TT + ck * CK;
    int tid = threadIdx.x;
    __shared__ float Ls[CK][128];
    __shared__ float rs[CK][129];
    __shared__ float kt[CK][129];
    __shared__ float vsm[CK][68];
    __shared__ float Dts[128];
    __shared__ float up[CK][8];
    #pragma unroll
    for (int i = 0; i < 16; i++) {
        int idx = i * 256 + tid;
        int t = idx >> 7, c = idx & 127;
        size_t g = (size_t)(tok0 + t) * KDIM + h * DKH + c;
        Ls[t][c] = eb[g];
        rs[t][c] = rb[g];
        kt[t][c] = kb[g];
    }
    __syncthreads();
    {
        int c = tid & 127, hf = tid >> 7;
        float run = 0.f;
        if (hf) {
            #pragma unroll
            for (int t = 0; t < 16; t++) run += Ls[t][c];
        }
        __syncthreads();    // prefix reads of Ls done before overwrites below
        float bc = bonus[h * DKH + c];
        #pragma unroll
        for (int tt2 = 0; tt2 < 16; tt2++) {
            int t = hf * 16 + tt2;
            size_t g = (size_t)(tok0 + t) * KDIM + h * DKH + c;
            float e = Ls[t][c];
            float rv = rs[t][c];
            float kv = kt[t][c];
            rb[g] = rv * __expf(-run);
            Ls[t][c] = rv * kv * bc;          // bonus partial
            run += e;
            float ks = kv * __expf(run);
            kt[t][c] = ks;
            kb[g] = ks;
        }
        if (hf) {
            float dt = __expf(-run);
            Dts[c] = dt;
            Db[(size_t)(bh * NCK + ck) * 128 + c] = dt;
        }
    }
    __syncthreads();
    {
        int t = tid >> 3, seg = tid & 7;
        float s = 0.f;
        #pragma unroll
        for (int q = 0; q < 16; q++) s += Ls[t][seg * 16 + q];
        up[t][seg] = s;
    }
    __syncthreads();
    if (tid < CK) {
        float s = 0.f;
        #pragma unroll
        for (int q = 0; q < 8; q++) s += up[tid][q];
        ub[(size_t)(tok0 + tid) * NHD + h] = s;
    }
    for (int jb = 0; jb < 4; jb++) {
        {
            int j = tid & 63, r0 = tid >> 6;
            #pragma unroll
            for (int i = 0; i < 8; i++) {
                int s = r0 + 4 * i;
                vsm[s][j] = vb[(size_t)(tok0 + s) * VDIM + h * DVH + jb * 64 + j];
            }
        }
        __syncthreads();
        {
            int kk0 = (tid >> 3) * 4;
            int j0 = (tid & 7) * 8;
            float m[4][8] = {};
            for (int s = 0; s < CK; s++) {
                float4 kv = *(const float4*)&kt[s][kk0];
                float4 v0 = *(const float4*)&vsm[s][j0];
                float4 v1 = *(const float4*)&vsm[s][j0 + 4];
                float ka[4] = {kv.x, kv.y, kv.z, kv.w};
                float va[8] = {v0.x, v0.y, v0.z, v0.w, v1.x, v1.y, v1.z, v1.w};
                #pragma unroll
                for (int i = 0; i < 4; i++)
                    #pragma unroll
                    for (int jj = 0; jj < 8; jj++)
                        m[i][jj] += ka[i] * va[jj];
            }
            #pragma unroll
            for (int i = 0; i < 4; i++) {
                float d = Dts[kk0 + i];
                size_t mb = ((size_t)(bh * NCK + ck) * 128 + kk0 + i) * DVH + jb * 64 + j0;
                *(float4*)(Mb + mb)     = make_float4(m[i][0] * d, m[i][1] * d, m[i][2] * d, m[i][3] * d);
                *(float4*)(Mb + mb + 4) = make_float4(m[i][4] * d, m[i][5] * d, m[i][6] * d, m[i][7] * d);
            }
        }
        __syncthreads();
    }
}

// ---------------------------------------------------------------------------
// Kernel 5b (chunkB): sequential over chunks with register prefetch.
// grid (16 bh, 32 j-slices of 8), 4 kk per thread.
// ---------------------------------------------------------------------------
__global__ __launch_bounds__(256) void k_chunkB(
    float* __restrict__ MS, const float* __restrict__ Db)
{
    int bh = blockIdx.x;
    int jsl = blockIdx.y;
    int tid = threadIdx.x;
    int j = jsl * 8 + (tid & 7);
    int kk0 = (tid >> 3) * 4;
    float S[4] = {};
    float m[4], d[4];
    {
        size_t kb0 = (size_t)(bh * NCK) * 128;
        #pragma unroll
        for (int i = 0; i < 4; i++) {
            m[i] = MS[(kb0 + kk0 + i) * DVH + j];
            d[i] = Db[kb0 + kk0 + i];
        }
    }
    for (int c = 0; c < NCK; c++) {
        size_t kbc = (size_t)(bh * NCK + c) * 128;
        float mc[4], dc[4];
        #pragma unroll
        for (int i = 0; i < 4; i++) { mc[i] = m[i]; dc[i] = d[i]; }
        if (c + 1 < NCK) {
            size_t kbn = (size_t)(bh * NCK + c + 1) * 128;
            #pragma unroll
            for (int i = 0; i < 4; i++) {
                m[i] = MS[(kbn + kk0 + i) * DVH + j];
                d[i] = Db[kbn + kk0 + i];
            }
        }
        #pragma unroll
        for (int i = 0; i < 4; i++) {
            MS[(kbc + kk0 + i) * DVH + j] = S[i];
            S[i] = S[i] * dc[i] + mc[i];
        }
    }
}

// ---------------------------------------------------------------------------
// Kernel 5c (chunkCG, fused, 512 threads): P = mask(r~ k~^T, diag=u);
// o = P@v + r~@S (f32 regs); groupnorm; silu(g) gate; y f32 IN PLACE over v.
// ---------------------------------------------------------------------------
__global__ __launch_bounds__(512) void k_chunkCG(
    const float* __restrict__ rb, const float* __restrict__ kb,
    float* __restrict__ vb, const float* __restrict__ ub,
    const float* __restrict__ Sb, const float* __restrict__ gb_,
    const float* __restrict__ gnw, const float* __restrict__ gnb)
{
    int bh = blockIdx.x, ck = blockIdx.y;
    int h = bh & 3, b = bh >> 2;
    int tok0 = b * TT + ck * CK;
    int tid = threadIdx.x;
    __shared__ float rt[CK][129];
    __shared__ float kt[CK][129];
    __shared__ float Ps[CK][33];
    __shared__ float vsm[CK][256];
    #pragma unroll
    for (int i = 0; i < 8; i++) {
        int idx = i * 512 + tid;
        int t = idx >> 7, c = idx & 127;
        size_t g = (size_t)(tok0 + t) * KDIM + h * DKH + c;
        rt[t][c] = rb[g];
        kt[t][c] = kb[g];
    }
    {
        int r0 = tid >> 4, c0 = (tid & 15) * 16;
        const float* vp = vb + (size_t)(tok0 + r0) * VDIM + h * DVH + c0;
        #pragma unroll
        for (int j = 0; j < 16; j += 4) {
            float4 v4 = *(const float4*)(vp + j);
            vsm[r0][c0 + j + 0] = v4.x; vsm[r0][c0 + j + 1] = v4.y;
            vsm[r0][c0 + j + 2] = v4.z; vsm[r0][c0 + j + 3] = v4.w;
        }
    }
    __syncthreads();
    {
        int t = tid >> 4;
        int s0 = (tid & 15) * 2;
        float a0 = 0.f, a1 = 0.f;
        for (int k4 = 0; k4 < 128; k4 += 4) {
            float4 a = *(const float4*)&rt[t][k4];
            float4 b0 = *(const float4*)&kt[s0][k4];
            float4 b1 = *(const float4*)&kt[s0 + 1][k4];
            a0 += a.x * b0.x + a.y * b0.y + a.z * b0.z + a.w * b0.w;
            a1 += a.x * b1.x + a.y * b1.y + a.z * b1.z + a.w * b1.w;
        }
        float u0 = ub[(size_t)(tok0 + t) * NHD + h];
        Ps[t][s0]     = (s0 < t)     ? a0 : (s0 == t     ? u0 : 0.f);
        Ps[t][s0 + 1] = (s0 + 1 < t) ? a1 : (s0 + 1 == t ? u0 : 0.f);
    }
    __syncthreads();
    int t0 = (tid >> 5) * 2;
    int j0 = (tid & 31) * 8;
    float acc[2][8] = {};
    for (int s = 0; s < CK; s++) {
        float va[8];
        #pragma unroll
        for (int jj = 0; jj < 8; jj++) va[jj] = vsm[s][j0 + jj];
        float p0 = Ps[t0][s], p1 = Ps[t0 + 1][s];
        #pragma unroll
        for (int jj = 0; jj < 8; jj++) {
            acc[0][jj] += p0 * va[jj];
            acc[1][jj] += p1 * va[jj];
        }
    }
    size_t sbase = (size_t)(bh * NCK + ck) * 128 * DVH;
    for (int kk = 0; kk < 128; kk++) {
        const float* srow = Sb + sbase + (size_t)kk * DVH + j0;
        float4 s0v = *(const float4*)(srow);
        float4 s1v = *(const float4*)(srow + 4);
        float sv[8] = {s0v.x, s0v.y, s0v.z, s0v.w, s1v.x, s1v.y, s1v.z, s1v.w};
        float a0 = rt[t0][kk], a1 = rt[t0 + 1][kk];
        #pragma unroll
        for (int jj = 0; jj < 8; jj++) {
            acc[0][jj] += a0 * sv[jj];
            acc[1][jj] += a1 * sv[jj];
        }
    }
    int c = h * DVH + j0;
    float4 gw0 = *(const float4*)(gnw + c);
    float4 gw1 = *(const float4*)(gnw + c + 4);
    float4 gb0 = *(const float4*)(gnb + c);
    float4 gb1 = *(const float4*)(gnb + c + 4);
    float gwv[8] = {gw0.x, gw0.y, gw0.z, gw0.w, gw1.x, gw1.y, gw1.z, gw1.w};
    float gbv[8] = {gb0.x, gb0.y, gb0.z, gb0.w, gb1.x, gb1.y, gb1.z, gb1.w};
    #pragma unroll
    for (int i = 0; i < 2; i++) {
        float sum = 0.f, sq = 0.f;
        #pragma unroll
        for (int jj = 0; jj < 8; jj++) { sum += acc[i][jj]; sq += acc[i][jj] * acc[i][jj]; }
        #pragma unroll
        for (int m = 1; m < 32; m <<= 1) {
            sum += __shfl_xor(sum, m);
            sq  += __shfl_xor(sq, m);
        }
        float mean = sum * (1.f / DVH);
        float var = sq * (1.f / DVH) - mean * mean;
        float inv = rsqrtf(var + 1e-5f);
        size_t mrow = (size_t)(tok0 + t0 + i) * VDIM + c;
        float4 g0 = *(const float4*)(gb_ + mrow);
        float4 g1 = *(const float4*)(gb_ + mrow + 4);
        float gv[8] = {g0.x, g0.y, g0.z, g0.w, g1.x, g1.y, g1.z, g1.w};
        float o8[8];
        #pragma unroll
        for (int jj = 0; jj < 8; jj++) {
            float gg = gv[jj];
            float sig = 1.f / (1.f + __expf(-gg));
            o8[jj] = ((acc[i][jj] - mean) * inv * gwv[jj] + gbv[jj]) * (gg * sig);
        }
        *(float4*)(vb + mrow)     = make_float4(o8[0], o8[1], o8[2], o8[3]);
        *(float4*)(vb + mrow + 4) = make_float4(o8[4], o8[5], o8[6], o8[7]);
    }
}

// ---------------------------------------------------------------------------
// Kernel 6: output GEMM, split precision
// ---------------------------------------------------------------------------
__global__ __launch_bounds__(256) void k_gemm_out(
    const float* __restrict__ A, const bf16* __restrict__ Bh,
    const bf16* __restrict__ Bl, float* __restrict__ C, int M, int N, int K)
{
    __shared__ unsigned short Ah[128 * 32];
    __shared__ unsigned short Al[128 * 32];
    __shared__ unsigned short Bhs[128 * 32];
    __shared__ unsigned short Bls[128 * 32];
    int tid = threadIdx.x;
    int bm = blockIdx.x * 128, bn = blockIdx.y * 128;
    int lane = tid & 63, w = tid >> 6;
    int wr = w >> 1, wc = w & 1;
    const unsigned short* Bh16 = (const unsigned short*)Bh;
    const unsigned short* Bl16 = (const unsigned short*)Bl;
    f32x4 acc[4][4];
    #pragma unroll
    for (int i = 0; i < 4; i++)
        #pragma unroll
        for (int j = 0; j < 4; j++)
            acc[i][j] = (f32x4){0.f, 0.f, 0.f, 0.f};
    int arow = tid >> 1, acol = (tid & 1) * 16;
    int ch0 = tid, ch1 = tid + 256;
    int r0c = ch0 >> 2, c0c = (ch0 & 3) * 8;
    int r1c = ch1 >> 2, c1c = (ch1 & 3) * 8;
    int fr = lane & 15, kb = (lane >> 4) * 8;
    for (int k0 = 0; k0 < K; k0 += 32) {
        float av[16];
        #pragma unroll
        for (int q = 0; q < 4; q++) {
            float4 t4 = *(const float4*)(A + (size_t)(bm + arow) * K + k0 + acol + q * 4);
            av[q * 4 + 0] = t4.x; av[q * 4 + 1] = t4.y;
            av[q * 4 + 2] = t4.z; av[q * 4 + 3] = t4.w;
        }
        uint4 bh0 = *(const uint4*)(Bh16 + (size_t)(bn + r0c) * K + k0 + c0c);
        uint4 bh1 = *(const uint4*)(Bh16 + (size_t)(bn + r1c) * K + k0 + c1c);
        uint4 bl0 = *(const uint4*)(Bl16 + (size_t)(bn + r0c) * K + k0 + c0c);
        uint4 bl1 = *(const uint4*)(Bl16 + (size_t)(bn + r1c) * K + k0 + c1c);
        __syncthreads();
        alignas(16) unsigned short th[16], tl[16];
        #pragma unroll
        for (int q = 0; q < 16; q++) {
            unsigned short hu = f2u(av[q]);
            th[q] = hu;
            tl[q] = f2u(av[q] - u2f(hu));
        }
        *(uint4*)(Ah + arow * 32 + acol)     = *(const uint4*)&th[0];
        *(uint4*)(Ah + arow * 32 + acol + 8) = *(const uint4*)&th[8];
        *(uint4*)(Al + arow * 32 + acol)     = *(const uint4*)&tl[0];
        *(uint4*)(Al + arow * 32 + acol + 8) = *(const uint4*)&tl[8];
        *(uint4*)(Bhs + ch0 * 8) = bh0;
        *(uint4*)(Bhs + ch1 * 8) = bh1;
        *(uint4*)(Bls + ch0 * 8) = bl0;
        *(uint4*)(Bls + ch1 * 8) = bl1;
        __syncthreads();
        bf16x8 afh[4], afl[4], bfh[4], bfl[4];
        #pragma unroll
        for (int i = 0; i < 4; i++) {
            afh[i] = *(const bf16x8*)(Ah + (wr * 64 + i * 16 + fr) * 32 + kb);
            afl[i] = *(const bf16x8*)(Al + (wr * 64 + i * 16 + fr) * 32 + kb);
            bfh[i] = *(const bf16x8*)(Bhs + (wc * 64 + i * 16 + fr) * 32 + kb);
            bfl[i] = *(const bf16x8*)(Bls + (wc * 64 + i * 16 + fr) * 32 + kb);
        }
        #pragma unroll
        for (int i = 0; i < 4; i++)
            #pragma unroll
            for (int j = 0; j < 4; j++) {
                acc[i][j] = __builtin_amdgcn_mfma_f32_16x16x32_bf16(afh[i], bfh[j], acc[i][j], 0, 0, 0);
                acc[i][j] = __builtin_amdgcn_mfma_f32_16x16x32_bf16(afl[i], bfh[j], acc[i][j], 0, 0, 0);
                acc[i][j] = __builtin_amdgcn_mfma_f32_16x16x32_bf16(afh[i], bfl[j], acc[i][j], 0, 0, 0);
            }
    }
    int er = (lane >> 4) * 4, ec = lane & 15;
    #pragma unroll
    for (int i = 0; i < 4; i++) {
        int gr = bm + wr * 64 + i * 16 + er;
        #pragma unroll
        for (int j = 0; j < 4; j++) {
            int gc = bn + wc * 64 + j * 16 + ec;
            #pragma unroll
            for (int q = 0; q < 4; q++)
                C[(size_t)(gr + q) * N + gc] = acc[i][j][q];
        }
    }
}

// ---------------------------------------------------------------------------
extern "C" void kernel_launch(void* const* d_in, const int* in_sizes, int n_in,
                              void* d_out, int out_size, void* d_ws, size_t ws_size,
                              hipStream_t stream)
{
    const float* h        = (const float*)d_in[0];
    const float* x_mu     = (const float*)d_in[1];
    const float* xl_w1    = (const float*)d_in[2];
    const float* xl_w2    = (const float*)d_in[3];
    const float* xl_b2    = (const float*)d_in[4];
    const float* x_out_w  = (const float*)d_in[5];
    const float* x_bias   = (const float*)d_in[6];
    const float* r_w      = (const float*)d_in[7];
    const float* w_w1     = (const float*)d_in[8];
    const float* w_w2     = (const float*)d_in[9];
    const float* w_b      = (const float*)d_in[10];
    const float* k_w      = (const float*)d_in[11];
    const float* v_w      = (const float*)d_in[12];
    const float* g_w      = (const float*)d_in[13];
    const float* bonus    = (const float*)d_in[14];
    const float* gn_w     = (const float*)d_in[15];
    const float* gn_b     = (const float*)d_in[16];
    const float* o_w      = (const float*)d_in[17];
    float* out = (float*)d_out;

    // Workspace overlay: total 35,733,504 floats = 142.9 MB (proven size)
    float* ws = (float*)d_ws;
    bf16*  wbf  = (bf16*)ws;                       // 8,388,608 bf16 = 4,194,304 slots
    float* rbuf = ws + 4194304;                    // 2,097,152
    float* vbuf = ws + 6291456;                    // 4,194,304 (y f32 in place later)
    float* gbuf = ws + 10485760;                   // 4,194,304
    float* kbuf = ws + 14680064;                   // 2,097,152
    float* ebuf = ws + 16777216;                   // 2,097,152
    float* ubuf = ws + 18874368;                   // 16,384
    float* Dbuf = ws + 18890752;                   // 65,536
    float* BIG  = ws + 18956288;                   // 16,777,216 (X phase / Mbuf)

    // weight hi/lo (bf16 element offsets within wbf)
    bf16* rwb_h = wbf;                  // 524,288
    bf16* kwb_h = wbf + 524288;
    bf16* vwb_h = wbf + 1048576;        // 1,048,576
    bf16* gwb_h = wbf + 2097152;
    bf16* owb_h = wbf + 3145728;
    bf16* rwb_l = wbf + 4194304;
    bf16* kwb_l = wbf + 4718592;
    bf16* vwb_l = wbf + 5242880;
    bf16* gwb_l = wbf + 6291456;
    bf16* owb_l = wbf + 7340032;

    // X phase inside BIG (each bf16 X = 2,097,152 float slots)
    float* Xw = BIG;                           // f32 [0 .. 4,194,304)
    bf16*  Xr = (bf16*)(BIG + 4194304);
    bf16*  Xk = (bf16*)(BIG + 6291456);
    bf16*  Xv = (bf16*)(BIG + 8388608);
    bf16*  Xg = (bf16*)(BIG + 10485760);
    float* x1   = BIG + 12582912;              // 655,360  (dead after mix)
    float* t0bf = BIG + 13238272;              // 131,072  (dead after k_x1b)
    float* w1p  = BIG + 12582912;              // 2,097,152 (after x1/t0 dead; dead before Mbuf)
    float* Mbuf = BIG;                         // full 16,777,216 after X dead
    float* ybuf = vbuf;                        // y f32 in place over v

    // weight conversion (hi/lo pairs), single launch
    k_f2b2_all<<<2048, 256, 0, stream>>>(r_w, k_w, v_w, g_w, o_w,
                                         rwb_h, rwb_l, kwb_h, kwb_l,
                                         vwb_h, vwb_l, gwb_h, gwb_l,
                                         owb_h, owb_l);

    // x1 path: MFMA phase-1 + small phase-2
    k_x1mm<<<NTOK / 64, 256, 0, stream>>>(h, x_mu, xl_w1, t0bf);
    k_x1b<<<NTOK / 64, 256, 0, stream>>>(t0bf, xl_w2, xl_b2, x1);

    // mix: f32 w-slice + MFMA bf16 four-slice
    k_mixw<<<dim3(NTOK / 64, HH / 64), 256, 0, stream>>>(h, x1, x_out_w, x_bias, Xw);
    k_mix4<<<dim3(NTOK / 64, HH / 64), 256, 0, stream>>>(h, x1, x_out_w, x_bias,
                                                         Xr, Xk, Xv, Xg);

    // projections: fused hi/lo MFMA for r/k/v/g; split-K f32 for the w path
    k_gemm_hl<<<dim3(NTOK / 128, KDIM / 128), 256, 0, stream>>>(Xr, rwb_h, rwb_l, rbuf, NTOK, KDIM, HH);
    k_gemm_hl<<<dim3(NTOK / 128, KDIM / 128), 256, 0, stream>>>(Xk, kwb_h, kwb_l, kbuf, NTOK, KDIM, HH);
    k_gemm_hl<<<dim3(NTOK / 128, VDIM / 128), 256, 0, stream>>>(Xv, vwb_h, vwb_l, vbuf, NTOK, VDIM, HH);
    k_gemm_hl<<<dim3(NTOK / 128, VDIM / 128), 256, 0, stream>>>(Xg, gwb_h, gwb_l, gbuf, NTOK, VDIM, HH);
    k_w1<<<dim3(NTOK / 64, WKS), 256, 0, stream>>>(Xw, w_w1, w1p);
    k_we<<<dim3(NTOK / 64, KDIM / 64), 256, 0, stream>>>(w1p, w_w2, w_b, ebuf);

    k_chunkA1<<<dim3(BB * NHD, NCK), 256, 0, stream>>>(ebuf, rbuf, kbuf, vbuf,
                                                       bonus, ubuf, Mbuf, Dbuf);
    k_chunkB<<<dim3(BB * NHD, 32), 256, 0, stream>>>(Mbuf, Dbuf);
    k_chunkCG<<<dim3(BB * NHD, NCK), 512, 0, stream>>>(rbuf, kbuf, vbuf, ubuf, Mbuf,
                                                       gbuf, gn_w, gn_b);

    k_gemm_out<<<dim3(NTOK / 128, HH / 128), 256, 0, stream>>>(ybuf, owb_h, owb_l, out, NTOK, HH, VDIM);
}

// Round 10
// 338.014 us; speedup vs baseline: 6.7411x; 1.1572x over previous
//
#include <hip/hip_runtime.h>
#include <hip/hip_bf16.h>
#include <math.h>

// Problem constants
static constexpr int BB = 4;
static constexpr int TT = 1024;
static constexpr int HH = 1024;
static constexpr int NHD = 4;
static constexpr int KDIM = 512;
static constexpr int VDIM = 1024;
static constexpr int DKH = 128;   // KD / NH
static constexpr int DVH = 256;   // VD / NH
static constexpr int RR = 32;
static constexpr int R5D = 160;
static constexpr int GG = 64;
static constexpr int NTOK = BB * TT;   // 4096
static constexpr int CK = 32;          // chunk length
static constexpr int NCK = TT / CK;    // 32 chunks per sequence
static constexpr int WKS = 8;          // split-K factor for the w1 gemm

typedef __bf16 bf16x8 __attribute__((ext_vector_type(8)));
typedef float f32x4 __attribute__((ext_vector_type(4)));
typedef __hip_bfloat16 bf16;

static __device__ inline unsigned short f2u(float v) {
    __hip_bfloat16 b = __float2bfloat16(v);
    unsigned short u; __builtin_memcpy(&u, &b, 2); return u;
}
static __device__ inline float u2f(unsigned short u) {
    __hip_bfloat16 b; __builtin_memcpy(&b, &u, 2); return __bfloat162float(b);
}

// ---------------------------------------------------------------------------
// Kernel 0: f32 -> bf16 hi/lo pairs, all 5 weights in one launch
// ---------------------------------------------------------------------------
__global__ __launch_bounds__(256) void k_f2b2_all(
    const float* __restrict__ r_w, const float* __restrict__ k_w,
    const float* __restrict__ v_w, const float* __restrict__ g_w,
    const float* __restrict__ o_w,
    bf16* __restrict__ rh, bf16* __restrict__ rl,
    bf16* __restrict__ kh, bf16* __restrict__ kl,
    bf16* __restrict__ vh, bf16* __restrict__ vl,
    bf16* __restrict__ gh, bf16* __restrict__ gl,
    bf16* __restrict__ oh, bf16* __restrict__ ol)
{
    size_t g = ((size_t)blockIdx.x * 256 + threadIdx.x) * 8;
    const float* s; bf16 *hi, *lo; size_t off;
    if (g < 524288)       { s = r_w; hi = rh; lo = rl; off = g; }
    else if (g < 1048576) { s = k_w; hi = kh; lo = kl; off = g - 524288; }
    else if (g < 2097152) { s = v_w; hi = vh; lo = vl; off = g - 1048576; }
    else if (g < 3145728) { s = g_w; hi = gh; lo = gl; off = g - 2097152; }
    else                  { s = o_w; hi = oh; lo = ol; off = g - 3145728; }
    #pragma unroll
    for (int j = 0; j < 8; j++) {
        float v = s[off + j];
        bf16 hb = __float2bfloat16(v);
        hi[off + j] = hb;
        lo[off + j] = __float2bfloat16(v - __bfloat162float(hb));
    }
}

// ---------------------------------------------------------------------------
// Kernel 1a (k_x1mm): t0[4096x32] = tanh( x_lerp @ w1^T ) via bf16 MFMA.
// ---------------------------------------------------------------------------
__global__ __launch_bounds__(256) void k_x1mm(
    const float* __restrict__ h, const float* __restrict__ mu,
    const float* __restrict__ w1, float* __restrict__ t0)
{
    __shared__ unsigned short Al[64][40];
    __shared__ unsigned short Bl[32][40];
    int tid = threadIdx.x;
    int m0 = blockIdx.x * 64;
    int lane = tid & 63, w = tid >> 6;
    f32x4 acc[2];
    acc[0] = (f32x4){0.f, 0.f, 0.f, 0.f};
    acc[1] = (f32x4){0.f, 0.f, 0.f, 0.f};
    int ar = tid >> 2, ac0 = (tid & 3) * 8;        // A stage: 64x32, 8 per thread
    int br = tid >> 3, bc0 = (tid & 7) * 4;        // B stage: 32x32, 4 per thread
    int fr = lane & 15, kb = lane >> 4;
    int mrow = m0 + ar;
    int trow = mrow & (TT - 1);
    const float* hp = h + (size_t)mrow * HH;
    for (int k0 = 0; k0 < HH; k0 += 32) {
        float av[8];
        #pragma unroll
        for (int j = 0; j < 8; j += 4) {
            float4 c4 = *(const float4*)(hp + k0 + ac0 + j);
            float4 p4 = make_float4(0.f, 0.f, 0.f, 0.f);
            if (trow > 0) p4 = *(const float4*)(hp + k0 + ac0 + j - HH);
            float4 m4 = *(const float4*)(mu + k0 + ac0 + j);
            av[j + 0] = c4.x + (p4.x - c4.x) * m4.x;
            av[j + 1] = c4.y + (p4.y - c4.y) * m4.y;
            av[j + 2] = c4.z + (p4.z - c4.z) * m4.z;
            av[j + 3] = c4.w + (p4.w - c4.w) * m4.w;
        }
        float4 b4 = *(const float4*)(w1 + (size_t)br * HH + k0 + bc0);
        __syncthreads();
        #pragma unroll
        for (int j = 0; j < 8; j++) Al[ar][ac0 + j] = f2u(av[j]);
        Bl[br][bc0 + 0] = f2u(b4.x); Bl[br][bc0 + 1] = f2u(b4.y);
        Bl[br][bc0 + 2] = f2u(b4.z); Bl[br][bc0 + 3] = f2u(b4.w);
        __syncthreads();
        bf16x8 af = *(const bf16x8*)(&Al[w * 16 + fr][kb * 8]);
        bf16x8 bf0 = *(const bf16x8*)(&Bl[fr][kb * 8]);
        bf16x8 bf1 = *(const bf16x8*)(&Bl[16 + fr][kb * 8]);
        acc[0] = __builtin_amdgcn_mfma_f32_16x16x32_bf16(af, bf0, acc[0], 0, 0, 0);
        acc[1] = __builtin_amdgcn_mfma_f32_16x16x32_bf16(af, bf1, acc[1], 0, 0, 0);
    }
    int er = (lane >> 4) * 4, ec = lane & 15;
    #pragma unroll
    for (int j = 0; j < 2; j++) {
        #pragma unroll
        for (int q = 0; q < 4; q++) {
            int gr = m0 + w * 16 + er + q;
            t0[(size_t)gr * RR + j * 16 + ec] = tanhf(acc[j][q]);
        }
    }
}

// ---------------------------------------------------------------------------
// Kernel 1b (k_x1b): x1[4096x160] = tanh( t0 @ w2^T + b2 ).  K=32.
// ---------------------------------------------------------------------------
__global__ __launch_bounds__(256) void k_x1b(
    const float* __restrict__ t0, const float* __restrict__ w2,
    const float* __restrict__ b2, float* __restrict__ x1out)
{
    __shared__ float t0s[64][33];
    __shared__ float w2s[R5D * RR];
    __shared__ float b2s[R5D];
    int tid = threadIdx.x;
    int m0 = blockIdx.x * 64;
    {
        int row = tid >> 2, c0 = (tid & 3) * 8;
        float4 a = *(const float4*)(t0 + (size_t)(m0 + row) * RR + c0);
        float4 b = *(const float4*)(t0 + (size_t)(m0 + row) * RR + c0 + 4);
        t0s[row][c0 + 0] = a.x; t0s[row][c0 + 1] = a.y;
        t0s[row][c0 + 2] = a.z; t0s[row][c0 + 3] = a.w;
        t0s[row][c0 + 4] = b.x; t0s[row][c0 + 5] = b.y;
        t0s[row][c0 + 6] = b.z; t0s[row][c0 + 7] = b.w;
    }
    for (int i = tid; i < R5D * RR; i += 256) w2s[i] = w2[i];
    if (tid < R5D) b2s[tid] = b2[tid];
    __syncthreads();
    int tt = tid & 63, cg = tid >> 6;
    float t0r[32];
    #pragma unroll
    for (int q = 0; q < 32; q++) t0r[q] = t0s[tt][q];
    float* xo = x1out + (size_t)(m0 + tt) * R5D + cg * 40;
    for (int c = 0; c < 40; c++) {
        const float* wr = w2s + (cg * 40 + c) * RR;
        float s = b2s[cg * 40 + c];
        #pragma unroll
        for (int q = 0; q < 32; q++) s += t0r[q] * wr[q];
        xo[c] = tanhf(s);
    }
}

// ---------------------------------------------------------------------------
// Kernel 2a (k_mixw): n=1 slice only (w path, f32 exact).
// ---------------------------------------------------------------------------
__global__ __launch_bounds__(256) void k_mixw(
    const float* __restrict__ h, const float* __restrict__ x1,
    const float* __restrict__ xow, const float* __restrict__ xb,
    float* __restrict__ xw)
{
    int m0 = blockIdx.x * 64;
    int h0 = blockIdx.y * 64;
    int tid = threadIdx.x;
    __shared__ float x1sT[32][68];
    __shared__ float xosT[32][68];
    int rr = tid & 63, cg = tid >> 6;    // cg = wave id, 8 cols each
    {
        const float* xp = x1 + (size_t)(m0 + rr) * R5D + 32 + cg * 8;
        const float* wp = xow + (size_t)(h0 + rr) * R5D + 32 + cg * 8;
        float4 a0 = *(const float4*)xp, a1 = *(const float4*)(xp + 4);
        float4 b0 = *(const float4*)wp, b1 = *(const float4*)(wp + 4);
        x1sT[cg * 8 + 0][rr] = a0.x; x1sT[cg * 8 + 1][rr] = a0.y;
        x1sT[cg * 8 + 2][rr] = a0.z; x1sT[cg * 8 + 3][rr] = a0.w;
        x1sT[cg * 8 + 4][rr] = a1.x; x1sT[cg * 8 + 5][rr] = a1.y;
        x1sT[cg * 8 + 6][rr] = a1.z; x1sT[cg * 8 + 7][rr] = a1.w;
        xosT[cg * 8 + 0][rr] = b0.x; xosT[cg * 8 + 1][rr] = b0.y;
        xosT[cg * 8 + 2][rr] = b0.z; xosT[cg * 8 + 3][rr] = b0.w;
        xosT[cg * 8 + 4][rr] = b1.x; xosT[cg * 8 + 5][rr] = b1.y;
        xosT[cg * 8 + 6][rr] = b1.z; xosT[cg * 8 + 7][rr] = b1.w;
    }
    int tx = tid & 15, ty = tid >> 4;
    float creg[4][4], dreg[4][4];
    #pragma unroll
    for (int i = 0; i < 4; i++) {
        int m = m0 + ty * 4 + i;
        int t = m & (TT - 1);
        const float* hp = h + (size_t)m * HH + h0 + tx * 4;
        float4 c4 = *(const float4*)hp;
        float4 p4 = make_float4(0.f, 0.f, 0.f, 0.f);
        if (t > 0) p4 = *(const float4*)(hp - HH);
        creg[i][0] = c4.x; dreg[i][0] = p4.x - c4.x;
        creg[i][1] = c4.y; dreg[i][1] = p4.y - c4.y;
        creg[i][2] = c4.z; dreg[i][2] = p4.z - c4.z;
        creg[i][3] = c4.w; dreg[i][3] = p4.w - c4.w;
    }
    __syncthreads();
    float acc[4][4] = {};
    #pragma unroll
    for (int r2 = 0; r2 < 32; r2++) {
        float4 a4 = *(const float4*)&x1sT[r2][ty * 4];
        float4 b4 = *(const float4*)&xosT[r2][tx * 4];
        float aa[4] = {a4.x, a4.y, a4.z, a4.w};
        float bb[4] = {b4.x, b4.y, b4.z, b4.w};
        #pragma unroll
        for (int i = 0; i < 4; i++)
            #pragma unroll
            for (int j = 0; j < 4; j++)
                acc[i][j] += aa[i] * bb[j];
    }
    float4 xb4 = *(const float4*)(xb + HH + h0 + tx * 4);   // n=1 row of x_bias
    float xbv[4] = {xb4.x, xb4.y, xb4.z, xb4.w};
    #pragma unroll
    for (int i = 0; i < 4; i++) {
        size_t idx = (size_t)(m0 + ty * 4 + i) * HH + h0 + tx * 4;
        float v[4];
        #pragma unroll
        for (int j = 0; j < 4; j++)
            v[j] = creg[i][j] + dreg[i][j] * (acc[i][j] + xbv[j]);
        *(float4*)(xw + idx) = make_float4(v[0], v[1], v[2], v[3]);
    }
}

// ---------------------------------------------------------------------------
// Kernel 2b (k_mix4): n in {0,2,3,4} via direct-from-global MFMA fragments.
// ---------------------------------------------------------------------------
__global__ __launch_bounds__(256) void k_mix4(
    const float* __restrict__ h, const float* __restrict__ x1,
    const float* __restrict__ xow, const float* __restrict__ xb,
    bf16* __restrict__ xr, bf16* __restrict__ xk,
    bf16* __restrict__ xv, bf16* __restrict__ xg)
{
    int m0 = blockIdx.x * 64;
    int h0 = blockIdx.y * 64;
    int tid = threadIdx.x;
    int lane = tid & 63, w = tid >> 6;
    int fr = lane & 15, kb = (lane >> 4) * 8;
    int er = (lane >> 4) * 4, ec = lane & 15;
    float creg[4][4], dreg[4][4];
    #pragma unroll
    for (int q = 0; q < 4; q++) {
        int m = m0 + w * 16 + er + q;
        int t = m & (TT - 1);
        const float* hp = h + (size_t)m * HH;
        #pragma unroll
        for (int j = 0; j < 4; j++) {
            int hh = h0 + j * 16 + ec;
            float c = hp[hh];
            float p = (t > 0) ? hp[hh - HH] : 0.f;
            creg[q][j] = c;
            dreg[q][j] = p - c;
        }
    }
    bf16* outs[4] = {xr, xk, xv, xg};
    const int ns[4] = {0, 2, 3, 4};
    #pragma unroll
    for (int ni = 0; ni < 4; ni++) {
        int n = ns[ni];
        const float* ap = x1 + (size_t)(m0 + w * 16 + fr) * R5D + n * 32 + kb;
        float4 a0 = *(const float4*)ap;
        float4 a1 = *(const float4*)(ap + 4);
        alignas(16) unsigned short ta[8];
        ta[0] = f2u(a0.x); ta[1] = f2u(a0.y); ta[2] = f2u(a0.z); ta[3] = f2u(a0.w);
        ta[4] = f2u(a1.x); ta[5] = f2u(a1.y); ta[6] = f2u(a1.z); ta[7] = f2u(a1.w);
        bf16x8 af = *(const bf16x8*)ta;
        f32x4 accj[4];
        #pragma unroll
        for (int j = 0; j < 4; j++) {
            const float* bp = xow + (size_t)(h0 + j * 16 + fr) * R5D + n * 32 + kb;
            float4 b0 = *(const float4*)bp;
            float4 b1 = *(const float4*)(bp + 4);
            alignas(16) unsigned short tb[8];
            tb[0] = f2u(b0.x); tb[1] = f2u(b0.y); tb[2] = f2u(b0.z); tb[3] = f2u(b0.w);
            tb[4] = f2u(b1.x); tb[5] = f2u(b1.y); tb[6] = f2u(b1.z); tb[7] = f2u(b1.w);
            bf16x8 bf_ = *(const bf16x8*)tb;
            f32x4 z = (f32x4){0.f, 0.f, 0.f, 0.f};
            accj[j] = __builtin_amdgcn_mfma_f32_16x16x32_bf16(af, bf_, z, 0, 0, 0);
        }
        bf16* op = outs[ni];
        #pragma unroll
        for (int j = 0; j < 4; j++) {
            float xbv = xb[n * HH + h0 + j * 16 + ec];
            #pragma unroll
            for (int q = 0; q < 4; q++) {
                float val = creg[q][j] + dreg[q][j] * (accj[j][q] + xbv);
                op[(size_t)(m0 + w * 16 + er + q) * HH + h0 + j * 16 + ec] =
                    __float2bfloat16(val);
            }
        }
    }
}

// ---------------------------------------------------------------------------
// Kernel 3a (k_gemm_hl2): two hi/lo GEMMs in one launch (z selects problem).
// C[M,N] f32 = A[M,K]bf16 @ (Bh+Bl)[N,K]bf16^T
// ---------------------------------------------------------------------------
__global__ __launch_bounds__(256) void k_gemm_hl2(
    const bf16* __restrict__ A0, const bf16* __restrict__ Bh0,
    const bf16* __restrict__ Bl0, float* __restrict__ C0,
    const bf16* __restrict__ A1, const bf16* __restrict__ Bh1,
    const bf16* __restrict__ Bl1, float* __restrict__ C1,
    int M, int N, int K)
{
    const bf16* A  = blockIdx.z ? A1  : A0;
    const bf16* Bh = blockIdx.z ? Bh1 : Bh0;
    const bf16* Bl = blockIdx.z ? Bl1 : Bl0;
    float* C       = blockIdx.z ? C1  : C0;
    __shared__ unsigned short As[128 * 32];
    __shared__ unsigned short Bhs[128 * 32];
    __shared__ unsigned short Bls[128 * 32];
    int tid = threadIdx.x;
    int bm = blockIdx.x * 128, bn = blockIdx.y * 128;
    int lane = tid & 63, w = tid >> 6;
    int wr = w >> 1, wc = w & 1;
    const unsigned short* A16 = (const unsigned short*)A;
    const unsigned short* Bh16 = (const unsigned short*)Bh;
    const unsigned short* Bl16 = (const unsigned short*)Bl;
    f32x4 acc[4][4];
    #pragma unroll
    for (int i = 0; i < 4; i++)
        #pragma unroll
        for (int j = 0; j < 4; j++)
            acc[i][j] = (f32x4){0.f, 0.f, 0.f, 0.f};
    int ch0 = tid, ch1 = tid + 256;
    int r0c = ch0 >> 2, c0c = (ch0 & 3) * 8;
    int r1c = ch1 >> 2, c1c = (ch1 & 3) * 8;
    int fr = lane & 15, kb = (lane >> 4) * 8;
    for (int k0 = 0; k0 < K; k0 += 32) {
        uint4 a0 = *(const uint4*)(A16 + (size_t)(bm + r0c) * K + k0 + c0c);
        uint4 a1 = *(const uint4*)(A16 + (size_t)(bm + r1c) * K + k0 + c1c);
        uint4 bh0 = *(const uint4*)(Bh16 + (size_t)(bn + r0c) * K + k0 + c0c);
        uint4 bh1 = *(const uint4*)(Bh16 + (size_t)(bn + r1c) * K + k0 + c1c);
        uint4 bl0 = *(const uint4*)(Bl16 + (size_t)(bn + r0c) * K + k0 + c0c);
        uint4 bl1 = *(const uint4*)(Bl16 + (size_t)(bn + r1c) * K + k0 + c1c);
        __syncthreads();
        *(uint4*)(As + ch0 * 8) = a0;
        *(uint4*)(As + ch1 * 8) = a1;
        *(uint4*)(Bhs + ch0 * 8) = bh0;
        *(uint4*)(Bhs + ch1 * 8) = bh1;
        *(uint4*)(Bls + ch0 * 8) = bl0;
        *(uint4*)(Bls + ch1 * 8) = bl1;
        __syncthreads();
        bf16x8 af[4], bfh[4], bfl[4];
        #pragma unroll
        for (int i = 0; i < 4; i++) {
            af[i]  = *(const bf16x8*)(As + (wr * 64 + i * 16 + fr) * 32 + kb);
            bfh[i] = *(const bf16x8*)(Bhs + (wc * 64 + i * 16 + fr) * 32 + kb);
            bfl[i] = *(const bf16x8*)(Bls + (wc * 64 + i * 16 + fr) * 32 + kb);
        }
        #pragma unroll
        for (int i = 0; i < 4; i++)
            #pragma unroll
            for (int j = 0; j < 4; j++) {
                acc[i][j] = __builtin_amdgcn_mfma_f32_16x16x32_bf16(af[i], bfh[j], acc[i][j], 0, 0, 0);
                acc[i][j] = __builtin_amdgcn_mfma_f32_16x16x32_bf16(af[i], bfl[j], acc[i][j], 0, 0, 0);
            }
    }
    int er = (lane >> 4) * 4, ec = lane & 15;
    #pragma unroll
    for (int i = 0; i < 4; i++) {
        int gr = bm + wr * 64 + i * 16 + er;
        #pragma unroll
        for (int j = 0; j < 4; j++) {
            int gc = bn + wc * 64 + j * 16 + ec;
            #pragma unroll
            for (int q = 0; q < 4; q++)
                C[(size_t)(gr + q) * N + gc] = acc[i][j][q];
        }
    }
}

// ---------------------------------------------------------------------------
// Kernel 3b (k_w1): split-K partial GEMM for the w path.
// P[ks][4096][64] = Xw[.., ks*128..+128) @ w_w1[.., same)^T.  grid (64, 8).
// ---------------------------------------------------------------------------
__global__ __launch_bounds__(256) void k_w1(
    const float* __restrict__ A, const float* __restrict__ Bm,
    float* __restrict__ P)
{
    __shared__ float As[16][68];
    __shared__ float Bs[16][68];
    int tid = threadIdx.x;
    int bm = blockIdx.x * 64;
    int ks = blockIdx.y;
    int kbase = ks * (HH / WKS);       // 128-wide K slice
    int tx = tid & 15, ty = tid >> 4;
    int lr = tid >> 2;
    int lk = (tid & 3) * 4;
    float acc[4][4] = {};
    for (int k0 = 0; k0 < HH / WKS; k0 += 16) {
        float4 av = *(const float4*)(A + (size_t)(bm + lr) * HH + kbase + k0 + lk);
        float4 bv = *(const float4*)(Bm + (size_t)lr * HH + kbase + k0 + lk);
        As[lk + 0][lr] = av.x; As[lk + 1][lr] = av.y;
        As[lk + 2][lr] = av.z; As[lk + 3][lr] = av.w;
        Bs[lk + 0][lr] = bv.x; Bs[lk + 1][lr] = bv.y;
        Bs[lk + 2][lr] = bv.z; Bs[lk + 3][lr] = bv.w;
        __syncthreads();
        #pragma unroll
        for (int kk = 0; kk < 16; kk++) {
            float4 a4 = *(const float4*)&As[kk][ty * 4];
            float4 b4 = *(const float4*)&Bs[kk][tx * 4];
            float aa[4] = {a4.x, a4.y, a4.z, a4.w};
            float bb[4] = {b4.x, b4.y, b4.z, b4.w};
            #pragma unroll
            for (int i = 0; i < 4; i++)
                #pragma unroll
                for (int j = 0; j < 4; j++)
                    acc[i][j] += aa[i] * bb[j];
        }
        __syncthreads();
    }
    #pragma unroll
    for (int i = 0; i < 4; i++) {
        size_t row = (size_t)ks * NTOK + bm + ty * 4 + i;
        *(float4*)(P + row * GG + tx * 4) =
            make_float4(acc[i][0], acc[i][1], acc[i][2], acc[i][3]);
    }
}

// ---------------------------------------------------------------------------
// Kernel 3c (k_we): e = exp( tanh(sum_ks P) @ w_w2^T + w_b ).
// ---------------------------------------------------------------------------
__global__ __launch_bounds__(256) void k_we(
    const float* __restrict__ P, const float* __restrict__ w_w2,
    const float* __restrict__ w_b, float* __restrict__ eb)
{
    __shared__ float As[64][65];
    __shared__ float Bs[64][65];
    int tid = threadIdx.x;
    int bm = blockIdx.x * 64, bn = blockIdx.y * 64;
    {
        int r = tid >> 2, c0 = (tid & 3) * 16;
        float s[16];
        #pragma unroll
        for (int j = 0; j < 16; j++) s[j] = 0.f;
        for (int ks = 0; ks < WKS; ks++) {
            const float* pp = P + ((size_t)ks * NTOK + bm + r) * GG + c0;
            #pragma unroll
            for (int j = 0; j < 16; j += 4) {
                float4 v = *(const float4*)(pp + j);
                s[j + 0] += v.x; s[j + 1] += v.y; s[j + 2] += v.z; s[j + 3] += v.w;
            }
        }
        #pragma unroll
        for (int j = 0; j < 16; j++) As[r][c0 + j] = tanhf(s[j]);
        const float* bp = w_w2 + (size_t)(bn + r) * GG + c0;
        #pragma unroll
        for (int j = 0; j < 16; j += 4) {
            float4 v = *(const float4*)(bp + j);
            Bs[r][c0 + j + 0] = v.x; Bs[r][c0 + j + 1] = v.y;
            Bs[r][c0 + j + 2] = v.z; Bs[r][c0 + j + 3] = v.w;
        }
    }
    __syncthreads();
    int tx = tid & 15, ty = tid >> 4;
    float acc[4][4] = {};
    #pragma unroll 8
    for (int kk = 0; kk < GG; kk++) {
        float aa[4], bb[4];
        #pragma unroll
        for (int i = 0; i < 4; i++) aa[i] = As[ty * 4 + i][kk];
        #pragma unroll
        for (int j = 0; j < 4; j++) bb[j] = Bs[tx * 4 + j][kk];
        #pragma unroll
        for (int i = 0; i < 4; i++)
            #pragma unroll
            for (int j = 0; j < 4; j++)
                acc[i][j] += aa[i] * bb[j];
    }
    float4 wb4 = *(const float4*)(w_b + bn + tx * 4);
    float wbv[4] = {wb4.x, wb4.y, wb4.z, wb4.w};
    #pragma unroll
    for (int i = 0; i < 4; i++) {
        float v[4];
        #pragma unroll
        for (int j = 0; j < 4; j++) v[j] = __expf(acc[i][j] + wbv[j]);
        *(float4*)(eb + (size_t)(bm + ty * 4 + i) * KDIM + bn + tx * 4) =
            make_float4(v[0], v[1], v[2], v[3]);
    }
}

// ---------------------------------------------------------------------------
// Kernel 5a (chunkA1): LDS-staged r/k/e; 2-way-parallel cumsum; r~,k~ in place;
// M = (k~ * Dtot)^T v; Dtot out; u fused.
// ---------------------------------------------------------------------------
__global__ __launch_bounds__(256) void k_chunkA1(
    const float* __restrict__ eb, float* __restrict__ rb,
    float* __restrict__ kb, const float* __restrict__ vb,
    const float* __restrict__ bonus, float* __restrict__ ub,
    float* __restrict__ Mb, float* __restrict__ Db)
{
    int bh = blockIdx.x;       // b*NH + h (h fast)
    int ck = blockIdx.y;       // 0..31
    int h = bh & 3, b = bh >> 2;
    int tok0 = b * TT + ck * CK;
    int tid = threadIdx.x;
    __shared__ float Ls[CK][128];
    __shared__ float rs[CK][129];
    __shared__ float kt[CK][129];
    __shared__ float vsm[CK][68];
    __shared__ float Dts[128];
    __shared__ float up[CK][8];
    #pragma unroll
    for (int i = 0; i < 16; i++) {
        int idx = i * 256 + tid;
        int t = idx >> 7, c = idx & 127;
        size_t g = (size_t)(tok0 + t) * KDIM + h * DKH + c;
        Ls[t][c] = eb[g];
        rs[t][c] = rb[g];
        kt[t][c] = kb[g];
    }
    __syncthreads();
    {
        int c = tid & 127, hf = tid >> 7;
        float run = 0.f;
        if (hf) {
            #pragma unroll
            for (int t = 0; t < 16; t++) run += Ls[t][c];
        }
        __syncthreads();    // prefix reads of Ls done before overwrites below
        float bc = bonus[h * DKH + c];
        #pragma unroll
        for (int tt2 = 0; tt2 < 16; tt2++) {
            int t = hf * 16 + tt2;
            size_t g = (size_t)(tok0 + t) * KDIM + h * DKH + c;
            float e = Ls[t][c];
            float rv = rs[t][c];
            float kv = kt[t][c];
            rb[g] = rv * __expf(-run);
            Ls[t][c] = rv * kv * bc;          // bonus partial
            run += e;
            float ks = kv * __expf(run);
            kt[t][c] = ks;
            kb[g] = ks;
        }
        if (hf) {
            float dt = __expf(-run);
            Dts[c] = dt;
            Db[(size_t)(bh * NCK + ck) * 128 + c] = dt;
        }
    }
    __syncthreads();
    {
        int t = tid >> 3, seg = tid & 7;
        float s = 0.f;
        #pragma unroll
        for (int q = 0; q < 16; q++) s += Ls[t][seg * 16 + q];
        up[t][seg] = s;
    }
    __syncthreads();
    if (tid < CK) {
        float s = 0.f;
        #pragma unroll
        for (int q = 0; q < 8; q++) s += up[tid][q];
        ub[(size_t)(tok0 + tid) * NHD + h] = s;
    }
    for (int jb = 0; jb < 4; jb++) {
        {
            int j = tid & 63, r0 = tid >> 6;
            #pragma unroll
            for (int i = 0; i < 8; i++) {
                int s = r0 + 4 * i;
                vsm[s][j] = vb[(size_t)(tok0 + s) * VDIM + h * DVH + jb * 64 + j];
            }
        }
        __syncthreads();
        {
            int kk0 = (tid >> 3) * 4;
            int j0 = (tid & 7) * 8;
            float m[4][8] = {};
            for (int s = 0; s < CK; s++) {
                float4 kv = *(const float4*)&kt[s][kk0];
                float4 v0 = *(const float4*)&vsm[s][j0];
                float4 v1 = *(const float4*)&vsm[s][j0 + 4];
                float ka[4] = {kv.x, kv.y, kv.z, kv.w};
                float va[8] = {v0.x, v0.y, v0.z, v0.w, v1.x, v1.y, v1.z, v1.w};
                #pragma unroll
                for (int i = 0; i < 4; i++)
                    #pragma unroll
                    for (int jj = 0; jj < 8; jj++)
                        m[i][jj] += ka[i] * va[jj];
            }
            #pragma unroll
            for (int i = 0; i < 4; i++) {
                float d = Dts[kk0 + i];
                size_t mb = ((size_t)(bh * NCK + ck) * 128 + kk0 + i) * DVH + jb * 64 + j0;
                *(float4*)(Mb + mb)     = make_float4(m[i][0] * d, m[i][1] * d, m[i][2] * d, m[i][3] * d);
                *(float4*)(Mb + mb + 4) = make_float4(m[i][4] * d, m[i][5] * d, m[i][6] * d, m[i][7] * d);
            }
        }
        __syncthreads();
    }
}

// ---------------------------------------------------------------------------
// Kernel 5b (chunkB): sequential over chunks with register prefetch.
// grid (16 bh, 32 j-slices of 8), 4 kk per thread.
// ---------------------------------------------------------------------------
__global__ __launch_bounds__(256) void k_chunkB(
    float* __restrict__ MS, const float* __restrict__ Db)
{
    int bh = blockIdx.x;
    int jsl = blockIdx.y;
    int tid = threadIdx.x;
    int j = jsl * 8 + (tid & 7);
    int kk0 = (tid >> 3) * 4;
    float S[4] = {};
    float m[4], d[4];
    {
        size_t kb0 = (size_t)(bh * NCK) * 128;
        #pragma unroll
        for (int i = 0; i < 4; i++) {
            m[i] = MS[(kb0 + kk0 + i) * DVH + j];
            d[i] = Db[kb0 + kk0 + i];
        }
    }
    for (int c = 0; c < NCK; c++) {
        size_t kbc = (size_t)(bh * NCK + c) * 128;
        float mc[4], dc[4];
        #pragma unroll
        for (int i = 0; i < 4; i++) { mc[i] = m[i]; dc[i] = d[i]; }
        if (c + 1 < NCK) {
            size_t kbn = (size_t)(bh * NCK + c + 1) * 128;
            #pragma unroll
            for (int i = 0; i < 4; i++) {
                m[i] = MS[(kbn + kk0 + i) * DVH + j];
                d[i] = Db[kbn + kk0 + i];
            }
        }
        #pragma unroll
        for (int i = 0; i < 4; i++) {
            MS[(kbc + kk0 + i) * DVH + j] = S[i];
            S[i] = S[i] * dc[i] + mc[i];
        }
    }
}

// ---------------------------------------------------------------------------
// Kernel 5c (chunkCG, fused, 512 threads): P = mask(r~ k~^T, diag=u);
// o = P@v + r~@S (f32 regs); groupnorm; silu(g) gate; y f32 IN PLACE over v.
// Col mapping: thread owns cols c4..c4+3 and c4+128..c4+131 (c4=(tid&31)*4)
// -> lane-consecutive float4 LDS reads (was 8-way bank conflict at stride-8).
// ---------------------------------------------------------------------------
__global__ __launch_bounds__(512) void k_chunkCG(
    const float* __restrict__ rb, const float* __restrict__ kb,
    float* __restrict__ vb, const float* __restrict__ ub,
    const float* __restrict__ Sb, const float* __restrict__ gb_,
    const float* __restrict__ gnw, const float* __restrict__ gnb)
{
    int bh = blockIdx.x, ck = blockIdx.y;
    int h = bh & 3, b = bh >> 2;
    int tok0 = b * TT + ck * CK;
    int tid = threadIdx.x;
    __shared__ float rt[CK][129];
    __shared__ float kt[CK][129];
    __shared__ float Ps[CK][33];
    __shared__ float vsm[CK][256];
    #pragma unroll
    for (int i = 0; i < 8; i++) {
        int idx = i * 512 + tid;
        int t = idx >> 7, c = idx & 127;
        size_t g = (size_t)(tok0 + t) * KDIM + h * DKH + c;
        rt[t][c] = rb[g];
        kt[t][c] = kb[g];
    }
    {
        int r0 = tid >> 4, c0 = (tid & 15) * 16;
        const float* vp = vb + (size_t)(tok0 + r0) * VDIM + h * DVH + c0;
        #pragma unroll
        for (int j = 0; j < 16; j += 4) {
            float4 v4 = *(const float4*)(vp + j);
            vsm[r0][c0 + j + 0] = v4.x; vsm[r0][c0 + j + 1] = v4.y;
            vsm[r0][c0 + j + 2] = v4.z; vsm[r0][c0 + j + 3] = v4.w;
        }
    }
    __syncthreads();
    // P: 2 entries per thread
    {
        int t = tid >> 4;
        int s0 = (tid & 15) * 2;
        float a0 = 0.f, a1 = 0.f;
        for (int k4 = 0; k4 < 128; k4 += 4) {
            float4 a = *(const float4*)&rt[t][k4];
            float4 b0 = *(const float4*)&kt[s0][k4];
            float4 b1 = *(const float4*)&kt[s0 + 1][k4];
            a0 += a.x * b0.x + a.y * b0.y + a.z * b0.z + a.w * b0.w;
            a1 += a.x * b1.x + a.y * b1.y + a.z * b1.z + a.w * b1.w;
        }
        float u0 = ub[(size_t)(tok0 + t) * NHD + h];
        Ps[t][s0]     = (s0 < t)     ? a0 : (s0 == t     ? u0 : 0.f);
        Ps[t][s0 + 1] = (s0 + 1 < t) ? a1 : (s0 + 1 == t ? u0 : 0.f);
    }
    __syncthreads();
    int t0 = (tid >> 5) * 2;
    int c4 = (tid & 31) * 4;            // cols c4..c4+3 and c4+128..c4+131
    float acc[2][2][4] = {};            // [token][colgrp][4]
    // intra-chunk: P @ v
    for (int s = 0; s < CK; s++) {
        float4 v0 = *(const float4*)&vsm[s][c4];
        float4 v1 = *(const float4*)&vsm[s][c4 + 128];
        float va[2][4] = {{v0.x, v0.y, v0.z, v0.w}, {v1.x, v1.y, v1.z, v1.w}};
        float p0 = Ps[t0][s], p1 = Ps[t0 + 1][s];
        #pragma unroll
        for (int g2 = 0; g2 < 2; g2++)
            #pragma unroll
            for (int jj = 0; jj < 4; jj++) {
                acc[0][g2][jj] += p0 * va[g2][jj];
                acc[1][g2][jj] += p1 * va[g2][jj];
            }
    }
    // inter-chunk: r~ @ S
    size_t sbase = (size_t)(bh * NCK + ck) * 128 * DVH;
    for (int kk = 0; kk < 128; kk++) {
        const float* srow = Sb + sbase + (size_t)kk * DVH;
        float4 s0v = *(const float4*)(srow + c4);
        float4 s1v = *(const float4*)(srow + c4 + 128);
        float sv[2][4] = {{s0v.x, s0v.y, s0v.z, s0v.w}, {s1v.x, s1v.y, s1v.z, s1v.w}};
        float a0 = rt[t0][kk], a1 = rt[t0 + 1][kk];
        #pragma unroll
        for (int g2 = 0; g2 < 2; g2++)
            #pragma unroll
            for (int jj = 0; jj < 4; jj++) {
                acc[0][g2][jj] += a0 * sv[g2][jj];
                acc[1][g2][jj] += a1 * sv[g2][jj];
            }
    }
    // groupnorm + affine + silu(g) gate, y f32 in place over v
    int cbase = h * DVH + c4;
    float4 gwA = *(const float4*)(gnw + cbase);
    float4 gwB = *(const float4*)(gnw + cbase + 128);
    float4 gbA = *(const float4*)(gnb + cbase);
    float4 gbB = *(const float4*)(gnb + cbase + 128);
    float gwv[2][4] = {{gwA.x, gwA.y, gwA.z, gwA.w}, {gwB.x, gwB.y, gwB.z, gwB.w}};
    float gbv[2][4] = {{gbA.x, gbA.y, gbA.z, gbA.w}, {gbB.x, gbB.y, gbB.z, gbB.w}};
    #pragma unroll
    for (int i = 0; i < 2; i++) {
        float sum = 0.f, sq = 0.f;
        #pragma unroll
        for (int g2 = 0; g2 < 2; g2++)
            #pragma unroll
            for (int jj = 0; jj < 4; jj++) {
                sum += acc[i][g2][jj];
                sq  += acc[i][g2][jj] * acc[i][g2][jj];
            }
        #pragma unroll
        for (int m = 1; m < 32; m <<= 1) {
            sum += __shfl_xor(sum, m);
            sq  += __shfl_xor(sq, m);
        }
        float mean = sum * (1.f / DVH);
        float var = sq * (1.f / DVH) - mean * mean;
        float inv = rsqrtf(var + 1e-5f);
        size_t mrow = (size_t)(tok0 + t0 + i) * VDIM + cbase;
        float4 gA = *(const float4*)(gb_ + mrow);
        float4 gB = *(const float4*)(gb_ + mrow + 128);
        float gv[2][4] = {{gA.x, gA.y, gA.z, gA.w}, {gB.x, gB.y, gB.z, gB.w}};
        #pragma unroll
        for (int g2 = 0; g2 < 2; g2++) {
            float o4[4];
            #pragma unroll
            for (int jj = 0; jj < 4; jj++) {
                float gg = gv[g2][jj];
                float sig = 1.f / (1.f + __expf(-gg));
                o4[jj] = ((acc[i][g2][jj] - mean) * inv * gwv[g2][jj] + gbv[g2][jj]) * (gg * sig);
            }
            *(float4*)(vb + mrow + g2 * 128) = make_float4(o4[0], o4[1], o4[2], o4[3]);
        }
    }
}

// ---------------------------------------------------------------------------
// Kernel 6: output GEMM, split precision
// ---------------------------------------------------------------------------
__global__ __launch_bounds__(256) void k_gemm_out(
    const float* __restrict__ A, const bf16* __restrict__ Bh,
    const bf16* __restrict__ Bl, float* __restrict__ C, int M, int N, int K)
{
    __shared__ unsigned short Ah[128 * 32];
    __shared__ unsigned short Al[128 * 32];
    __shared__ unsigned short Bhs[128 * 32];
    __shared__ unsigned short Bls[128 * 32];
    int tid = threadIdx.x;
    int bm = blockIdx.x * 128, bn = blockIdx.y * 128;
    int lane = tid & 63, w = tid >> 6;
    int wr = w >> 1, wc = w & 1;
    const unsigned short* Bh16 = (const unsigned short*)Bh;
    const unsigned short* Bl16 = (const unsigned short*)Bl;
    f32x4 acc[4][4];
    #pragma unroll
    for (int i = 0; i < 4; i++)
        #pragma unroll
        for (int j = 0; j < 4; j++)
            acc[i][j] = (f32x4){0.f, 0.f, 0.f, 0.f};
    int arow = tid >> 1, acol = (tid & 1) * 16;
    int ch0 = tid, ch1 = tid + 256;
    int r0c = ch0 >> 2, c0c = (ch0 & 3) * 8;
    int r1c = ch1 >> 2, c1c = (ch1 & 3) * 8;
    int fr = lane & 15, kb = (lane >> 4) * 8;
    for (int k0 = 0; k0 < K; k0 += 32) {
        float av[16];
        #pragma unroll
        for (int q = 0; q < 4; q++) {
            float4 t4 = *(const float4*)(A + (size_t)(bm + arow) * K + k0 + acol + q * 4);
            av[q * 4 + 0] = t4.x; av[q * 4 + 1] = t4.y;
            av[q * 4 + 2] = t4.z; av[q * 4 + 3] = t4.w;
        }
        uint4 bh0 = *(const uint4*)(Bh16 + (size_t)(bn + r0c) * K + k0 + c0c);
        uint4 bh1 = *(const uint4*)(Bh16 + (size_t)(bn + r1c) * K + k0 + c1c);
        uint4 bl0 = *(const uint4*)(Bl16 + (size_t)(bn + r0c) * K + k0 + c0c);
        uint4 bl1 = *(const uint4*)(Bl16 + (size_t)(bn + r1c) * K + k0 + c1c);
        __syncthreads();
        alignas(16) unsigned short th[16], tl[16];
        #pragma unroll
        for (int q = 0; q < 16; q++) {
            unsigned short hu = f2u(av[q]);
            th[q] = hu;
            tl[q] = f2u(av[q] - u2f(hu));
        }
        *(uint4*)(Ah + arow * 32 + acol)     = *(const uint4*)&th[0];
        *(uint4*)(Ah + arow * 32 + acol + 8) = *(const uint4*)&th[8];
        *(uint4*)(Al + arow * 32 + acol)     = *(const uint4*)&tl[0];
        *(uint4*)(Al + arow * 32 + acol + 8) = *(const uint4*)&tl[8];
        *(uint4*)(Bhs + ch0 * 8) = bh0;
        *(uint4*)(Bhs + ch1 * 8) = bh1;
        *(uint4*)(Bls + ch0 * 8) = bl0;
        *(uint4*)(Bls + ch1 * 8) = bl1;
        __syncthreads();
        bf16x8 afh[4], afl[4], bfh[4], bfl[4];
        #pragma unroll
        for (int i = 0; i < 4; i++) {
            afh[i] = *(const bf16x8*)(Ah + (wr * 64 + i * 16 + fr) * 32 + kb);
            afl[i] = *(const bf16x8*)(Al + (wr * 64 + i * 16 + fr) * 32 + kb);
            bfh[i] = *(const bf16x8*)(Bhs + (wc * 64 + i * 16 + fr) * 32 + kb);
            bfl[i] = *(const bf16x8*)(Bls + (wc * 64 + i * 16 + fr) * 32 + kb);
        }
        #pragma unroll
        for (int i = 0; i < 4; i++)
            #pragma unroll
            for (int j = 0; j < 4; j++) {
                acc[i][j] = __builtin_amdgcn_mfma_f32_16x16x32_bf16(afh[i], bfh[j], acc[i][j], 0, 0, 0);
                acc[i][j] = __builtin_amdgcn_mfma_f32_16x16x32_bf16(afl[i], bfh[j], acc[i][j], 0, 0, 0);
                acc[i][j] = __builtin_amdgcn_mfma_f32_16x16x32_bf16(afh[i], bfl[j], acc[i][j], 0, 0, 0);
            }
    }
    int er = (lane >> 4) * 4, ec = lane & 15;
    #pragma unroll
    for (int i = 0; i < 4; i++) {
        int gr = bm + wr * 64 + i * 16 + er;
        #pragma unroll
        for (int j = 0; j < 4; j++) {
            int gc = bn + wc * 64 + j * 16 + ec;
            #pragma unroll
            for (int q = 0; q < 4; q++)
                C[(size_t)(gr + q) * N + gc] = acc[i][j][q];
        }
    }
}

// ---------------------------------------------------------------------------
extern "C" void kernel_launch(void* const* d_in, const int* in_sizes, int n_in,
                              void* d_out, int out_size, void* d_ws, size_t ws_size,
                              hipStream_t stream)
{
    const float* h        = (const float*)d_in[0];
    const float* x_mu     = (const float*)d_in[1];
    const float* xl_w1    = (const float*)d_in[2];
    const float* xl_w2    = (const float*)d_in[3];
    const float* xl_b2    = (const float*)d_in[4];
    const float* x_out_w  = (const float*)d_in[5];
    const float* x_bias   = (const float*)d_in[6];
    const float* r_w      = (const float*)d_in[7];
    const float* w_w1     = (const float*)d_in[8];
    const float* w_w2     = (const float*)d_in[9];
    const float* w_b      = (const float*)d_in[10];
    const float* k_w      = (const float*)d_in[11];
    const float* v_w      = (const float*)d_in[12];
    const float* g_w      = (const float*)d_in[13];
    const float* bonus    = (const float*)d_in[14];
    const float* gn_w     = (const float*)d_in[15];
    const float* gn_b     = (const float*)d_in[16];
    const float* o_w      = (const float*)d_in[17];
    float* out = (float*)d_out;

    // Workspace overlay: total 35,733,504 floats = 142.9 MB (proven size)
    float* ws = (float*)d_ws;
    bf16*  wbf  = (bf16*)ws;                       // 8,388,608 bf16 = 4,194,304 slots
    float* rbuf = ws + 4194304;                    // 2,097,152
    float* vbuf = ws + 6291456;                    // 4,194,304 (y f32 in place later)
    float* gbuf = ws + 10485760;                   // 4,194,304
    float* kbuf = ws + 14680064;                   // 2,097,152
    float* ebuf = ws + 16777216;                   // 2,097,152
    float* ubuf = ws + 18874368;                   // 16,384
    float* Dbuf = ws + 18890752;                   // 65,536
    float* BIG  = ws + 18956288;                   // 16,777,216 (X phase / Mbuf)

    // weight hi/lo (bf16 element offsets within wbf)
    bf16* rwb_h = wbf;                  // 524,288
    bf16* kwb_h = wbf + 524288;
    bf16* vwb_h = wbf + 1048576;        // 1,048,576
    bf16* gwb_h = wbf + 2097152;
    bf16* owb_h = wbf + 3145728;
    bf16* rwb_l = wbf + 4194304;
    bf16* kwb_l = wbf + 4718592;
    bf16* vwb_l = wbf + 5242880;
    bf16* gwb_l = wbf + 6291456;
    bf16* owb_l = wbf + 7340032;

    // X phase inside BIG (each bf16 X = 2,097,152 float slots)
    float* Xw = BIG;                           // f32 [0 .. 4,194,304)
    bf16*  Xr = (bf16*)(BIG + 4194304);
    bf16*  Xk = (bf16*)(BIG + 6291456);
    bf16*  Xv = (bf16*)(BIG + 8388608);
    bf16*  Xg = (bf16*)(BIG + 10485760);
    float* x1   = BIG + 12582912;              // 655,360  (dead after mix)
    float* t0bf = BIG + 13238272;              // 131,072  (dead after k_x1b)
    float* w1p  = BIG + 12582912;              // 2,097,152 (after x1/t0 dead; dead before Mbuf)
    float* Mbuf = BIG;                         // full 16,777,216 after X dead
    float* ybuf = vbuf;                        // y f32 in place over v

    // weight conversion (hi/lo pairs), single launch
    k_f2b2_all<<<2048, 256, 0, stream>>>(r_w, k_w, v_w, g_w, o_w,
                                         rwb_h, rwb_l, kwb_h, kwb_l,
                                         vwb_h, vwb_l, gwb_h, gwb_l,
                                         owb_h, owb_l);

    // x1 path: MFMA phase-1 + small phase-2
    k_x1mm<<<NTOK / 64, 256, 0, stream>>>(h, x_mu, xl_w1, t0bf);
    k_x1b<<<NTOK / 64, 256, 0, stream>>>(t0bf, xl_w2, xl_b2, x1);

    // mix: f32 w-slice + MFMA bf16 four-slice
    k_mixw<<<dim3(NTOK / 64, HH / 64), 256, 0, stream>>>(h, x1, x_out_w, x_bias, Xw);
    k_mix4<<<dim3(NTOK / 64, HH / 64), 256, 0, stream>>>(h, x1, x_out_w, x_bias,
                                                         Xr, Xk, Xv, Xg);

    // projections: fused hi/lo MFMA (r+k merged, v+g merged); split-K f32 w path
    k_gemm_hl2<<<dim3(NTOK / 128, KDIM / 128, 2), 256, 0, stream>>>(
        Xr, rwb_h, rwb_l, rbuf, Xk, kwb_h, kwb_l, kbuf, NTOK, KDIM, HH);
    k_gemm_hl2<<<dim3(NTOK / 128, VDIM / 128, 2), 256, 0, stream>>>(
        Xv, vwb_h, vwb_l, vbuf, Xg, gwb_h, gwb_l, gbuf, NTOK, VDIM, HH);
    k_w1<<<dim3(NTOK / 64, WKS), 256, 0, stream>>>(Xw, w_w1, w1p);
    k_we<<<dim3(NTOK / 64, KDIM / 64), 256, 0, stream>>>(w1p, w_w2, w_b, ebuf);

    k_chunkA1<<<dim3(BB * NHD, NCK), 256, 0, stream>>>(ebuf, rbuf, kbuf, vbuf,
                                                       bonus, ubuf, Mbuf, Dbuf);
    k_chunkB<<<dim3(BB * NHD, 32), 256, 0, stream>>>(Mbuf, Dbuf);
    k_chunkCG<<<dim3(BB * NHD, NCK), 512, 0, stream>>>(rbuf, kbuf, vbuf, ubuf, Mbuf,
                                                       gbuf, gn_w, gn_b);

    k_gemm_out<<<dim3(NTOK / 128, HH / 128), 256, 0, stream>>>(ybuf, owb_h, owb_l, out, NTOK, HH, VDIM);
}

// Round 11
// 335.143 us; speedup vs baseline: 6.7988x; 1.0086x over previous
//
#include <hip/hip_runtime.h>
#include <hip/hip_bf16.h>
#include <math.h>

// Problem constants
static constexpr int BB = 4;
static constexpr int TT = 1024;
static constexpr int HH = 1024;
static constexpr int NHD = 4;
static constexpr int KDIM = 512;
static constexpr int VDIM = 1024;
static constexpr int DKH = 128;   // KD / NH
static constexpr int DVH = 256;   // VD / NH
static constexpr int RR = 32;
static constexpr int R5D = 160;
static constexpr int GG = 64;
static constexpr int NTOK = BB * TT;   // 4096
static constexpr int CK = 32;          // chunk length
static constexpr int NCK = TT / CK;    // 32 chunks per sequence
static constexpr int WKS = 8;          // split-K factor for the w1 gemm

typedef __bf16 bf16x8 __attribute__((ext_vector_type(8)));
typedef float f32x4 __attribute__((ext_vector_type(4)));
typedef __hip_bfloat16 bf16;

static __device__ inline unsigned short f2u(float v) {
    __hip_bfloat16 b = __float2bfloat16(v);
    unsigned short u; __builtin_memcpy(&u, &b, 2); return u;
}
static __device__ inline float u2f(unsigned short u) {
    __hip_bfloat16 b; __builtin_memcpy(&b, &u, 2); return __bfloat162float(b);
}

// ---------------------------------------------------------------------------
// Kernel 0: f32 -> bf16 hi/lo pairs, all 5 weights in one launch
// ---------------------------------------------------------------------------
__global__ __launch_bounds__(256) void k_f2b2_all(
    const float* __restrict__ r_w, const float* __restrict__ k_w,
    const float* __restrict__ v_w, const float* __restrict__ g_w,
    const float* __restrict__ o_w,
    bf16* __restrict__ rh, bf16* __restrict__ rl,
    bf16* __restrict__ kh, bf16* __restrict__ kl,
    bf16* __restrict__ vh, bf16* __restrict__ vl,
    bf16* __restrict__ gh, bf16* __restrict__ gl,
    bf16* __restrict__ oh, bf16* __restrict__ ol)
{
    size_t g = ((size_t)blockIdx.x * 256 + threadIdx.x) * 8;
    const float* s; bf16 *hi, *lo; size_t off;
    if (g < 524288)       { s = r_w; hi = rh; lo = rl; off = g; }
    else if (g < 1048576) { s = k_w; hi = kh; lo = kl; off = g - 524288; }
    else if (g < 2097152) { s = v_w; hi = vh; lo = vl; off = g - 1048576; }
    else if (g < 3145728) { s = g_w; hi = gh; lo = gl; off = g - 2097152; }
    else                  { s = o_w; hi = oh; lo = ol; off = g - 3145728; }
    #pragma unroll
    for (int j = 0; j < 8; j++) {
        float v = s[off + j];
        bf16 hb = __float2bfloat16(v);
        hi[off + j] = hb;
        lo[off + j] = __float2bfloat16(v - __bfloat162float(hb));
    }
}

// ---------------------------------------------------------------------------
// Kernel 1a (k_x1mm): t0[4096x32] = tanh( x_lerp @ w1^T ) via bf16 MFMA.
// ---------------------------------------------------------------------------
__global__ __launch_bounds__(256) void k_x1mm(
    const float* __restrict__ h, const float* __restrict__ mu,
    const float* __restrict__ w1, float* __restrict__ t0)
{
    __shared__ unsigned short Al[64][40];
    __shared__ unsigned short Bl[32][40];
    int tid = threadIdx.x;
    int m0 = blockIdx.x * 64;
    int lane = tid & 63, w = tid >> 6;
    f32x4 acc[2];
    acc[0] = (f32x4){0.f, 0.f, 0.f, 0.f};
    acc[1] = (f32x4){0.f, 0.f, 0.f, 0.f};
    int ar = tid >> 2, ac0 = (tid & 3) * 8;        // A stage: 64x32, 8 per thread
    int br = tid >> 3, bc0 = (tid & 7) * 4;        // B stage: 32x32, 4 per thread
    int fr = lane & 15, kb = lane >> 4;
    int mrow = m0 + ar;
    int trow = mrow & (TT - 1);
    const float* hp = h + (size_t)mrow * HH;
    for (int k0 = 0; k0 < HH; k0 += 32) {
        float av[8];
        #pragma unroll
        for (int j = 0; j < 8; j += 4) {
            float4 c4 = *(const float4*)(hp + k0 + ac0 + j);
            float4 p4 = make_float4(0.f, 0.f, 0.f, 0.f);
            if (trow > 0) p4 = *(const float4*)(hp + k0 + ac0 + j - HH);
            float4 m4 = *(const float4*)(mu + k0 + ac0 + j);
            av[j + 0] = c4.x + (p4.x - c4.x) * m4.x;
            av[j + 1] = c4.y + (p4.y - c4.y) * m4.y;
            av[j + 2] = c4.z + (p4.z - c4.z) * m4.z;
            av[j + 3] = c4.w + (p4.w - c4.w) * m4.w;
        }
        float4 b4 = *(const float4*)(w1 + (size_t)br * HH + k0 + bc0);
        __syncthreads();
        #pragma unroll
        for (int j = 0; j < 8; j++) Al[ar][ac0 + j] = f2u(av[j]);
        Bl[br][bc0 + 0] = f2u(b4.x); Bl[br][bc0 + 1] = f2u(b4.y);
        Bl[br][bc0 + 2] = f2u(b4.z); Bl[br][bc0 + 3] = f2u(b4.w);
        __syncthreads();
        bf16x8 af = *(const bf16x8*)(&Al[w * 16 + fr][kb * 8]);
        bf16x8 bf0 = *(const bf16x8*)(&Bl[fr][kb * 8]);
        bf16x8 bf1 = *(const bf16x8*)(&Bl[16 + fr][kb * 8]);
        acc[0] = __builtin_amdgcn_mfma_f32_16x16x32_bf16(af, bf0, acc[0], 0, 0, 0);
        acc[1] = __builtin_amdgcn_mfma_f32_16x16x32_bf16(af, bf1, acc[1], 0, 0, 0);
    }
    int er = (lane >> 4) * 4, ec = lane & 15;
    #pragma unroll
    for (int j = 0; j < 2; j++) {
        #pragma unroll
        for (int q = 0; q < 4; q++) {
            int gr = m0 + w * 16 + er + q;
            t0[(size_t)gr * RR + j * 16 + ec] = tanhf(acc[j][q]);
        }
    }
}

// ---------------------------------------------------------------------------
// Kernel 1b (k_x1b): x1[4096x160] = tanh( t0 @ w2^T + b2 ).  K=32.
// ---------------------------------------------------------------------------
__global__ __launch_bounds__(256) void k_x1b(
    const float* __restrict__ t0, const float* __restrict__ w2,
    const float* __restrict__ b2, float* __restrict__ x1out)
{
    __shared__ float t0s[64][33];
    __shared__ float w2s[R5D * RR];
    __shared__ float b2s[R5D];
    int tid = threadIdx.x;
    int m0 = blockIdx.x * 64;
    {
        int row = tid >> 2, c0 = (tid & 3) * 8;
        float4 a = *(const float4*)(t0 + (size_t)(m0 + row) * RR + c0);
        float4 b = *(const float4*)(t0 + (size_t)(m0 + row) * RR + c0 + 4);
        t0s[row][c0 + 0] = a.x; t0s[row][c0 + 1] = a.y;
        t0s[row][c0 + 2] = a.z; t0s[row][c0 + 3] = a.w;
        t0s[row][c0 + 4] = b.x; t0s[row][c0 + 5] = b.y;
        t0s[row][c0 + 6] = b.z; t0s[row][c0 + 7] = b.w;
    }
    for (int i = tid; i < R5D * RR; i += 256) w2s[i] = w2[i];
    if (tid < R5D) b2s[tid] = b2[tid];
    __syncthreads();
    int tt = tid & 63, cg = tid >> 6;
    float t0r[32];
    #pragma unroll
    for (int q = 0; q < 32; q++) t0r[q] = t0s[tt][q];
    float* xo = x1out + (size_t)(m0 + tt) * R5D + cg * 40;
    for (int c = 0; c < 40; c++) {
        const float* wr = w2s + (cg * 40 + c) * RR;
        float s = b2s[cg * 40 + c];
        #pragma unroll
        for (int q = 0; q < 32; q++) s += t0r[q] * wr[q];
        xo[c] = tanhf(s);
    }
}

// ---------------------------------------------------------------------------
// Kernel 2a (k_mixw): n=1 slice only (w path, f32 exact).
// ---------------------------------------------------------------------------
__global__ __launch_bounds__(256) void k_mixw(
    const float* __restrict__ h, const float* __restrict__ x1,
    const float* __restrict__ xow, const float* __restrict__ xb,
    float* __restrict__ xw)
{
    int m0 = blockIdx.x * 64;
    int h0 = blockIdx.y * 64;
    int tid = threadIdx.x;
    __shared__ float x1sT[32][68];
    __shared__ float xosT[32][68];
    int rr = tid & 63, cg = tid >> 6;    // cg = wave id, 8 cols each
    {
        const float* xp = x1 + (size_t)(m0 + rr) * R5D + 32 + cg * 8;
        const float* wp = xow + (size_t)(h0 + rr) * R5D + 32 + cg * 8;
        float4 a0 = *(const float4*)xp, a1 = *(const float4*)(xp + 4);
        float4 b0 = *(const float4*)wp, b1 = *(const float4*)(wp + 4);
        x1sT[cg * 8 + 0][rr] = a0.x; x1sT[cg * 8 + 1][rr] = a0.y;
        x1sT[cg * 8 + 2][rr] = a0.z; x1sT[cg * 8 + 3][rr] = a0.w;
        x1sT[cg * 8 + 4][rr] = a1.x; x1sT[cg * 8 + 5][rr] = a1.y;
        x1sT[cg * 8 + 6][rr] = a1.z; x1sT[cg * 8 + 7][rr] = a1.w;
        xosT[cg * 8 + 0][rr] = b0.x; xosT[cg * 8 + 1][rr] = b0.y;
        xosT[cg * 8 + 2][rr] = b0.z; xosT[cg * 8 + 3][rr] = b0.w;
        xosT[cg * 8 + 4][rr] = b1.x; xosT[cg * 8 + 5][rr] = b1.y;
        xosT[cg * 8 + 6][rr] = b1.z; xosT[cg * 8 + 7][rr] = b1.w;
    }
    int tx = tid & 15, ty = tid >> 4;
    float creg[4][4], dreg[4][4];
    #pragma unroll
    for (int i = 0; i < 4; i++) {
        int m = m0 + ty * 4 + i;
        int t = m & (TT - 1);
        const float* hp = h + (size_t)m * HH + h0 + tx * 4;
        float4 c4 = *(const float4*)hp;
        float4 p4 = make_float4(0.f, 0.f, 0.f, 0.f);
        if (t > 0) p4 = *(const float4*)(hp - HH);
        creg[i][0] = c4.x; dreg[i][0] = p4.x - c4.x;
        creg[i][1] = c4.y; dreg[i][1] = p4.y - c4.y;
        creg[i][2] = c4.z; dreg[i][2] = p4.z - c4.z;
        creg[i][3] = c4.w; dreg[i][3] = p4.w - c4.w;
    }
    __syncthreads();
    float acc[4][4] = {};
    #pragma unroll
    for (int r2 = 0; r2 < 32; r2++) {
        float4 a4 = *(const float4*)&x1sT[r2][ty * 4];
        float4 b4 = *(const float4*)&xosT[r2][tx * 4];
        float aa[4] = {a4.x, a4.y, a4.z, a4.w};
        float bb[4] = {b4.x, b4.y, b4.z, b4.w};
        #pragma unroll
        for (int i = 0; i < 4; i++)
            #pragma unroll
            for (int j = 0; j < 4; j++)
                acc[i][j] += aa[i] * bb[j];
    }
    float4 xb4 = *(const float4*)(xb + HH + h0 + tx * 4);   // n=1 row of x_bias
    float xbv[4] = {xb4.x, xb4.y, xb4.z, xb4.w};
    #pragma unroll
    for (int i = 0; i < 4; i++) {
        size_t idx = (size_t)(m0 + ty * 4 + i) * HH + h0 + tx * 4;
        float v[4];
        #pragma unroll
        for (int j = 0; j < 4; j++)
            v[j] = creg[i][j] + dreg[i][j] * (acc[i][j] + xbv[j]);
        *(float4*)(xw + idx) = make_float4(v[0], v[1], v[2], v[3]);
    }
}

// ---------------------------------------------------------------------------
// Kernel 2b (k_mix4): n in {0,2,3,4} via direct-from-global MFMA fragments.
// ---------------------------------------------------------------------------
__global__ __launch_bounds__(256) void k_mix4(
    const float* __restrict__ h, const float* __restrict__ x1,
    const float* __restrict__ xow, const float* __restrict__ xb,
    bf16* __restrict__ xr, bf16* __restrict__ xk,
    bf16* __restrict__ xv, bf16* __restrict__ xg)
{
    int m0 = blockIdx.x * 64;
    int h0 = blockIdx.y * 64;
    int tid = threadIdx.x;
    int lane = tid & 63, w = tid >> 6;
    int fr = lane & 15, kb = (lane >> 4) * 8;
    int er = (lane >> 4) * 4, ec = lane & 15;
    float creg[4][4], dreg[4][4];
    #pragma unroll
    for (int q = 0; q < 4; q++) {
        int m = m0 + w * 16 + er + q;
        int t = m & (TT - 1);
        const float* hp = h + (size_t)m * HH;
        #pragma unroll
        for (int j = 0; j < 4; j++) {
            int hh = h0 + j * 16 + ec;
            float c = hp[hh];
            float p = (t > 0) ? hp[hh - HH] : 0.f;
            creg[q][j] = c;
            dreg[q][j] = p - c;
        }
    }
    bf16* outs[4] = {xr, xk, xv, xg};
    const int ns[4] = {0, 2, 3, 4};
    #pragma unroll
    for (int ni = 0; ni < 4; ni++) {
        int n = ns[ni];
        const float* ap = x1 + (size_t)(m0 + w * 16 + fr) * R5D + n * 32 + kb;
        float4 a0 = *(const float4*)ap;
        float4 a1 = *(const float4*)(ap + 4);
        alignas(16) unsigned short ta[8];
        ta[0] = f2u(a0.x); ta[1] = f2u(a0.y); ta[2] = f2u(a0.z); ta[3] = f2u(a0.w);
        ta[4] = f2u(a1.x); ta[5] = f2u(a1.y); ta[6] = f2u(a1.z); ta[7] = f2u(a1.w);
        bf16x8 af = *(const bf16x8*)ta;
        f32x4 accj[4];
        #pragma unroll
        for (int j = 0; j < 4; j++) {
            const float* bp = xow + (size_t)(h0 + j * 16 + fr) * R5D + n * 32 + kb;
            float4 b0 = *(const float4*)bp;
            float4 b1 = *(const float4*)(bp + 4);
            alignas(16) unsigned short tb[8];
            tb[0] = f2u(b0.x); tb[1] = f2u(b0.y); tb[2] = f2u(b0.z); tb[3] = f2u(b0.w);
            tb[4] = f2u(b1.x); tb[5] = f2u(b1.y); tb[6] = f2u(b1.z); tb[7] = f2u(b1.w);
            bf16x8 bf_ = *(const bf16x8*)tb;
            f32x4 z = (f32x4){0.f, 0.f, 0.f, 0.f};
            accj[j] = __builtin_amdgcn_mfma_f32_16x16x32_bf16(af, bf_, z, 0, 0, 0);
        }
        bf16* op = outs[ni];
        #pragma unroll
        for (int j = 0; j < 4; j++) {
            float xbv = xb[n * HH + h0 + j * 16 + ec];
            #pragma unroll
            for (int q = 0; q < 4; q++) {
                float val = creg[q][j] + dreg[q][j] * (accj[j][q] + xbv);
                op[(size_t)(m0 + w * 16 + er + q) * HH + h0 + j * 16 + ec] =
                    __float2bfloat16(val);
            }
        }
    }
}

// ---------------------------------------------------------------------------
// Kernel 3a (k_gemm_hl2): two hi/lo GEMMs in one launch (z selects problem).
// ---------------------------------------------------------------------------
__global__ __launch_bounds__(256) void k_gemm_hl2(
    const bf16* __restrict__ A0, const bf16* __restrict__ Bh0,
    const bf16* __restrict__ Bl0, float* __restrict__ C0,
    const bf16* __restrict__ A1, const bf16* __restrict__ Bh1,
    const bf16* __restrict__ Bl1, float* __restrict__ C1,
    int M, int N, int K)
{
    const bf16* A  = blockIdx.z ? A1  : A0;
    const bf16* Bh = blockIdx.z ? Bh1 : Bh0;
    const bf16* Bl = blockIdx.z ? Bl1 : Bl0;
    float* C       = blockIdx.z ? C1  : C0;
    __shared__ unsigned short As[128 * 32];
    __shared__ unsigned short Bhs[128 * 32];
    __shared__ unsigned short Bls[128 * 32];
    int tid = threadIdx.x;
    int bm = blockIdx.x * 128, bn = blockIdx.y * 128;
    int lane = tid & 63, w = tid >> 6;
    int wr = w >> 1, wc = w & 1;
    const unsigned short* A16 = (const unsigned short*)A;
    const unsigned short* Bh16 = (const unsigned short*)Bh;
    const unsigned short* Bl16 = (const unsigned short*)Bl;
    f32x4 acc[4][4];
    #pragma unroll
    for (int i = 0; i < 4; i++)
        #pragma unroll
        for (int j = 0; j < 4; j++)
            acc[i][j] = (f32x4){0.f, 0.f, 0.f, 0.f};
    int ch0 = tid, ch1 = tid + 256;
    int r0c = ch0 >> 2, c0c = (ch0 & 3) * 8;
    int r1c = ch1 >> 2, c1c = (ch1 & 3) * 8;
    int fr = lane & 15, kb = (lane >> 4) * 8;
    for (int k0 = 0; k0 < K; k0 += 32) {
        uint4 a0 = *(const uint4*)(A16 + (size_t)(bm + r0c) * K + k0 + c0c);
        uint4 a1 = *(const uint4*)(A16 + (size_t)(bm + r1c) * K + k0 + c1c);
        uint4 bh0 = *(const uint4*)(Bh16 + (size_t)(bn + r0c) * K + k0 + c0c);
        uint4 bh1 = *(const uint4*)(Bh16 + (size_t)(bn + r1c) * K + k0 + c1c);
        uint4 bl0 = *(const uint4*)(Bl16 + (size_t)(bn + r0c) * K + k0 + c0c);
        uint4 bl1 = *(const uint4*)(Bl16 + (size_t)(bn + r1c) * K + k0 + c1c);
        __syncthreads();
        *(uint4*)(As + ch0 * 8) = a0;
        *(uint4*)(As + ch1 * 8) = a1;
        *(uint4*)(Bhs + ch0 * 8) = bh0;
        *(uint4*)(Bhs + ch1 * 8) = bh1;
        *(uint4*)(Bls + ch0 * 8) = bl0;
        *(uint4*)(Bls + ch1 * 8) = bl1;
        __syncthreads();
        bf16x8 af[4], bfh[4], bfl[4];
        #pragma unroll
        for (int i = 0; i < 4; i++) {
            af[i]  = *(const bf16x8*)(As + (wr * 64 + i * 16 + fr) * 32 + kb);
            bfh[i] = *(const bf16x8*)(Bhs + (wc * 64 + i * 16 + fr) * 32 + kb);
            bfl[i] = *(const bf16x8*)(Bls + (wc * 64 + i * 16 + fr) * 32 + kb);
        }
        #pragma unroll
        for (int i = 0; i < 4; i++)
            #pragma unroll
            for (int j = 0; j < 4; j++) {
                acc[i][j] = __builtin_amdgcn_mfma_f32_16x16x32_bf16(af[i], bfh[j], acc[i][j], 0, 0, 0);
                acc[i][j] = __builtin_amdgcn_mfma_f32_16x16x32_bf16(af[i], bfl[j], acc[i][j], 0, 0, 0);
            }
    }
    int er = (lane >> 4) * 4, ec = lane & 15;
    #pragma unroll
    for (int i = 0; i < 4; i++) {
        int gr = bm + wr * 64 + i * 16 + er;
        #pragma unroll
        for (int j = 0; j < 4; j++) {
            int gc = bn + wc * 64 + j * 16 + ec;
            #pragma unroll
            for (int q = 0; q < 4; q++)
                C[(size_t)(gr + q) * N + gc] = acc[i][j][q];
        }
    }
}

// ---------------------------------------------------------------------------
// Kernel 3b (k_w1): split-K partial GEMM for the w path.
// ---------------------------------------------------------------------------
__global__ __launch_bounds__(256) void k_w1(
    const float* __restrict__ A, const float* __restrict__ Bm,
    float* __restrict__ P)
{
    __shared__ float As[16][68];
    __shared__ float Bs[16][68];
    int tid = threadIdx.x;
    int bm = blockIdx.x * 64;
    int ks = blockIdx.y;
    int kbase = ks * (HH / WKS);       // 128-wide K slice
    int tx = tid & 15, ty = tid >> 4;
    int lr = tid >> 2;
    int lk = (tid & 3) * 4;
    float acc[4][4] = {};
    for (int k0 = 0; k0 < HH / WKS; k0 += 16) {
        float4 av = *(const float4*)(A + (size_t)(bm + lr) * HH + kbase + k0 + lk);
        float4 bv = *(const float4*)(Bm + (size_t)lr * HH + kbase + k0 + lk);
        As[lk + 0][lr] = av.x; As[lk + 1][lr] = av.y;
        As[lk + 2][lr] = av.z; As[lk + 3][lr] = av.w;
        Bs[lk + 0][lr] = bv.x; Bs[lk + 1][lr] = bv.y;
        Bs[lk + 2][lr] = bv.z; Bs[lk + 3][lr] = bv.w;
        __syncthreads();
        #pragma unroll
        for (int kk = 0; kk < 16; kk++) {
            float4 a4 = *(const float4*)&As[kk][ty * 4];
            float4 b4 = *(const float4*)&Bs[kk][tx * 4];
            float aa[4] = {a4.x, a4.y, a4.z, a4.w};
            float bb[4] = {b4.x, b4.y, b4.z, b4.w};
            #pragma unroll
            for (int i = 0; i < 4; i++)
                #pragma unroll
                for (int j = 0; j < 4; j++)
                    acc[i][j] += aa[i] * bb[j];
        }
        __syncthreads();
    }
    #pragma unroll
    for (int i = 0; i < 4; i++) {
        size_t row = (size_t)ks * NTOK + bm + ty * 4 + i;
        *(float4*)(P + row * GG + tx * 4) =
            make_float4(acc[i][0], acc[i][1], acc[i][2], acc[i][3]);
    }
}

// ---------------------------------------------------------------------------
// Kernel 3c (k_we): e = exp( tanh(sum_ks P) @ w_w2^T + w_b ).
// ---------------------------------------------------------------------------
__global__ __launch_bounds__(256) void k_we(
    const float* __restrict__ P, const float* __restrict__ w_w2,
    const float* __restrict__ w_b, float* __restrict__ eb)
{
    __shared__ float As[64][65];
    __shared__ float Bs[64][65];
    int tid = threadIdx.x;
    int bm = blockIdx.x * 64, bn = blockIdx.y * 64;
    {
        int r = tid >> 2, c0 = (tid & 3) * 16;
        float s[16];
        #pragma unroll
        for (int j = 0; j < 16; j++) s[j] = 0.f;
        for (int ks = 0; ks < WKS; ks++) {
            const float* pp = P + ((size_t)ks * NTOK + bm + r) * GG + c0;
            #pragma unroll
            for (int j = 0; j < 16; j += 4) {
                float4 v = *(const float4*)(pp + j);
                s[j + 0] += v.x; s[j + 1] += v.y; s[j + 2] += v.z; s[j + 3] += v.w;
            }
        }
        #pragma unroll
        for (int j = 0; j < 16; j++) As[r][c0 + j] = tanhf(s[j]);
        const float* bp = w_w2 + (size_t)(bn + r) * GG + c0;
        #pragma unroll
        for (int j = 0; j < 16; j += 4) {
            float4 v = *(const float4*)(bp + j);
            Bs[r][c0 + j + 0] = v.x; Bs[r][c0 + j + 1] = v.y;
            Bs[r][c0 + j + 2] = v.z; Bs[r][c0 + j + 3] = v.w;
        }
    }
    __syncthreads();
    int tx = tid & 15, ty = tid >> 4;
    float acc[4][4] = {};
    #pragma unroll 8
    for (int kk = 0; kk < GG; kk++) {
        float aa[4], bb[4];
        #pragma unroll
        for (int i = 0; i < 4; i++) aa[i] = As[ty * 4 + i][kk];
        #pragma unroll
        for (int j = 0; j < 4; j++) bb[j] = Bs[tx * 4 + j][kk];
        #pragma unroll
        for (int i = 0; i < 4; i++)
            #pragma unroll
            for (int j = 0; j < 4; j++)
                acc[i][j] += aa[i] * bb[j];
    }
    float4 wb4 = *(const float4*)(w_b + bn + tx * 4);
    float wbv[4] = {wb4.x, wb4.y, wb4.z, wb4.w};
    #pragma unroll
    for (int i = 0; i < 4; i++) {
        float v[4];
        #pragma unroll
        for (int j = 0; j < 4; j++) v[j] = __expf(acc[i][j] + wbv[j]);
        *(float4*)(eb + (size_t)(bm + ty * 4 + i) * KDIM + bn + tx * 4) =
            make_float4(v[0], v[1], v[2], v[3]);
    }
}

// ---------------------------------------------------------------------------
// Kernel 5a (chunkA1): LDS-staged r/k/e; 2-way-parallel cumsum; r~,k~ in place;
// M = (k~ * Dtot)^T v; Dtot out; u fused.
// ---------------------------------------------------------------------------
__global__ __launch_bounds__(256) void k_chunkA1(
    const float* __restrict__ eb, float* __restrict__ rb,
    float* __restrict__ kb, const float* __restrict__ vb,
    const float* __restrict__ bonus, float* __restrict__ ub,
    float* __restrict__ Mb, float* __restrict__ Db)
{
    int bh = blockIdx.x;       // b*NH + h (h fast)
    int ck = blockIdx.y;       // 0..31
    int h = bh & 3, b = bh >> 2;
    int tok0 = b * TT + ck * CK;
    int tid = threadIdx.x;
    __shared__ float Ls[CK][128];
    __shared__ float rs[CK][129];
    __shared__ float kt[CK][129];
    __shared__ float vsm[CK][68];
    __shared__ float Dts[128];
    __shared__ float up[CK][8];
    #pragma unroll
    for (int i = 0; i < 16; i++) {
        int idx = i * 256 + tid;
        int t = idx >> 7, c = idx & 127;
        size_t g = (size_t)(tok0 + t) * KDIM + h * DKH + c;
        Ls[t][c] = eb[g];
        rs[t][c] = rb[g];
        kt[t][c] = kb[g];
    }
    __syncthreads();
    {
        int c = tid & 127, hf = tid >> 7;
        float run = 0.f;
        if (hf) {
            #pragma unroll
            for (int t = 0; t < 16; t++) run += Ls[t][c];
        }
        __syncthreads();    // prefix reads of Ls done before overwrites below
        float bc = bonus[h * DKH + c];
        #pragma unroll
        for (int tt2 = 0; tt2 < 16; tt2++) {
            int t = hf * 16 + tt2;
            size_t g = (size_t)(tok0 + t) * KDIM + h * DKH + c;
            float e = Ls[t][c];
            float rv = rs[t][c];
            float kv = kt[t][c];
            rb[g] = rv * __expf(-run);
            Ls[t][c] = rv * kv * bc;          // bonus partial
            run += e;
            float ks = kv * __expf(run);
            kt[t][c] = ks;
            kb[g] = ks;
        }
        if (hf) {
            float dt = __expf(-run);
            Dts[c] = dt;
            Db[(size_t)(bh * NCK + ck) * 128 + c] = dt;
        }
    }
    __syncthreads();
    {
        int t = tid >> 3, seg = tid & 7;
        float s = 0.f;
        #pragma unroll
        for (int q = 0; q < 16; q++) s += Ls[t][seg * 16 + q];
        up[t][seg] = s;
    }
    __syncthreads();
    if (tid < CK) {
        float s = 0.f;
        #pragma unroll
        for (int q = 0; q < 8; q++) s += up[tid][q];
        ub[(size_t)(tok0 + tid) * NHD + h] = s;
    }
    for (int jb = 0; jb < 4; jb++) {
        {
            int j = tid & 63, r0 = tid >> 6;
            #pragma unroll
            for (int i = 0; i < 8; i++) {
                int s = r0 + 4 * i;
                vsm[s][j] = vb[(size_t)(tok0 + s) * VDIM + h * DVH + jb * 64 + j];
            }
        }
        __syncthreads();
        {
            int kk0 = (tid >> 3) * 4;
            int j0 = (tid & 7) * 8;
            float m[4][8] = {};
            for (int s = 0; s < CK; s++) {
                float4 kv = *(const float4*)&kt[s][kk0];
                float4 v0 = *(const float4*)&vsm[s][j0];
                float4 v1 = *(const float4*)&vsm[s][j0 + 4];
                float ka[4] = {kv.x, kv.y, kv.z, kv.w};
                float va[8] = {v0.x, v0.y, v0.z, v0.w, v1.x, v1.y, v1.z, v1.w};
                #pragma unroll
                for (int i = 0; i < 4; i++)
                    #pragma unroll
                    for (int jj = 0; jj < 8; jj++)
                        m[i][jj] += ka[i] * va[jj];
            }
            #pragma unroll
            for (int i = 0; i < 4; i++) {
                float d = Dts[kk0 + i];
                size_t mb = ((size_t)(bh * NCK + ck) * 128 + kk0 + i) * DVH + jb * 64 + j0;
                *(float4*)(Mb + mb)     = make_float4(m[i][0] * d, m[i][1] * d, m[i][2] * d, m[i][3] * d);
                *(float4*)(Mb + mb + 4) = make_float4(m[i][4] * d, m[i][5] * d, m[i][6] * d, m[i][7] * d);
            }
        }
        __syncthreads();
    }
}

// ---------------------------------------------------------------------------
// Kernel 5b (chunkB): sequential over chunks with register prefetch.
// ---------------------------------------------------------------------------
__global__ __launch_bounds__(256) void k_chunkB(
    float* __restrict__ MS, const float* __restrict__ Db)
{
    int bh = blockIdx.x;
    int jsl = blockIdx.y;
    int tid = threadIdx.x;
    int j = jsl * 8 + (tid & 7);
    int kk0 = (tid >> 3) * 4;
    float S[4] = {};
    float m[4], d[4];
    {
        size_t kb0 = (size_t)(bh * NCK) * 128;
        #pragma unroll
        for (int i = 0; i < 4; i++) {
            m[i] = MS[(kb0 + kk0 + i) * DVH + j];
            d[i] = Db[kb0 + kk0 + i];
        }
    }
    for (int c = 0; c < NCK; c++) {
        size_t kbc = (size_t)(bh * NCK + c) * 128;
        float mc[4], dc[4];
        #pragma unroll
        for (int i = 0; i < 4; i++) { mc[i] = m[i]; dc[i] = d[i]; }
        if (c + 1 < NCK) {
            size_t kbn = (size_t)(bh * NCK + c + 1) * 128;
            #pragma unroll
            for (int i = 0; i < 4; i++) {
                m[i] = MS[(kbn + kk0 + i) * DVH + j];
                d[i] = Db[kbn + kk0 + i];
            }
        }
        #pragma unroll
        for (int i = 0; i < 4; i++) {
            MS[(kbc + kk0 + i) * DVH + j] = S[i];
            S[i] = S[i] * dc[i] + mc[i];
        }
    }
}

// ---------------------------------------------------------------------------
// Kernel 5c (chunkCG, fused, 512 threads): P = mask(r~ k~^T, diag=u);
// o = P@v + r~@S (f32 regs); groupnorm; silu(g) gate; y f32 IN PLACE over v.
// LDS-slim variant: only rt (unpadded), kt (padded), Ps staged (36.7 KB).
// v and S read from global (v: 16x L1 reuse; S: streamed once).
// Barrier between P@v global v-reads and in-place y writes keeps it race-free.
// ---------------------------------------------------------------------------
__global__ __launch_bounds__(512) void k_chunkCG(
    const float* __restrict__ rb, const float* __restrict__ kb,
    float* __restrict__ vb, const float* __restrict__ ub,
    const float* __restrict__ Sb, const float* __restrict__ gb_,
    const float* __restrict__ gnw, const float* __restrict__ gnb)
{
    int bh = blockIdx.x, ck = blockIdx.y;
    int h = bh & 3, b = bh >> 2;
    int tok0 = b * TT + ck * CK;
    int tid = threadIdx.x;
    __shared__ float rt[CK][128];
    __shared__ float kt[CK][129];
    __shared__ float Ps[CK][33];
    #pragma unroll
    for (int i = 0; i < 8; i++) {
        int idx = i * 512 + tid;
        int t = idx >> 7, c = idx & 127;
        size_t g = (size_t)(tok0 + t) * KDIM + h * DKH + c;
        rt[t][c] = rb[g];
        kt[t][c] = kb[g];
    }
    __syncthreads();
    // P: 2 entries per thread
    {
        int t = tid >> 4;
        int s0 = (tid & 15) * 2;
        float a0 = 0.f, a1 = 0.f;
        for (int k4 = 0; k4 < 128; k4 += 4) {
            float4 a = *(const float4*)&rt[t][k4];
            float4 b0 = *(const float4*)&kt[s0][k4];
            float4 b1 = *(const float4*)&kt[s0 + 1][k4];
            a0 += a.x * b0.x + a.y * b0.y + a.z * b0.z + a.w * b0.w;
            a1 += a.x * b1.x + a.y * b1.y + a.z * b1.z + a.w * b1.w;
        }
        float u0 = ub[(size_t)(tok0 + t) * NHD + h];
        Ps[t][s0]     = (s0 < t)     ? a0 : (s0 == t     ? u0 : 0.f);
        Ps[t][s0 + 1] = (s0 + 1 < t) ? a1 : (s0 + 1 == t ? u0 : 0.f);
    }
    __syncthreads();
    int t0 = (tid >> 5) * 2;
    int c4 = (tid & 31) * 4;            // cols c4..c4+3 and c4+128..c4+131
    float acc[2][2][4] = {};            // [token][colgrp][4]
    // intra-chunk: P @ v  (v from global, 16x reuse via L1)
    for (int s = 0; s < CK; s++) {
        const float* vp = vb + (size_t)(tok0 + s) * VDIM + h * DVH;
        float4 v0 = *(const float4*)(vp + c4);
        float4 v1 = *(const float4*)(vp + c4 + 128);
        float va[2][4] = {{v0.x, v0.y, v0.z, v0.w}, {v1.x, v1.y, v1.z, v1.w}};
        float p0 = Ps[t0][s], p1 = Ps[t0 + 1][s];
        #pragma unroll
        for (int g2 = 0; g2 < 2; g2++)
            #pragma unroll
            for (int jj = 0; jj < 4; jj++) {
                acc[0][g2][jj] += p0 * va[g2][jj];
                acc[1][g2][jj] += p1 * va[g2][jj];
            }
    }
    __syncthreads();   // all global v reads done before in-place y writes below
    // inter-chunk: r~ @ S (streamed from global)
    size_t sbase = (size_t)(bh * NCK + ck) * 128 * DVH;
    for (int kk = 0; kk < 128; kk++) {
        const float* srow = Sb + sbase + (size_t)kk * DVH;
        float4 s0v = *(const float4*)(srow + c4);
        float4 s1v = *(const float4*)(srow + c4 + 128);
        float sv[2][4] = {{s0v.x, s0v.y, s0v.z, s0v.w}, {s1v.x, s1v.y, s1v.z, s1v.w}};
        float a0 = rt[t0][kk], a1 = rt[t0 + 1][kk];
        #pragma unroll
        for (int g2 = 0; g2 < 2; g2++)
            #pragma unroll
            for (int jj = 0; jj < 4; jj++) {
                acc[0][g2][jj] += a0 * sv[g2][jj];
                acc[1][g2][jj] += a1 * sv[g2][jj];
            }
    }
    // groupnorm + affine + silu(g) gate, y f32 in place over v
    int cbase = h * DVH + c4;
    float4 gwA = *(const float4*)(gnw + cbase);
    float4 gwB = *(const float4*)(gnw + cbase + 128);
    float4 gbA = *(const float4*)(gnb + cbase);
    float4 gbB = *(const float4*)(gnb + cbase + 128);
    float gwv[2][4] = {{gwA.x, gwA.y, gwA.z, gwA.w}, {gwB.x, gwB.y, gwB.z, gwB.w}};
    float gbv[2][4] = {{gbA.x, gbA.y, gbA.z, gbA.w}, {gbB.x, gbB.y, gbB.z, gbB.w}};
    #pragma unroll
    for (int i = 0; i < 2; i++) {
        float sum = 0.f, sq = 0.f;
        #pragma unroll
        for (int g2 = 0; g2 < 2; g2++)
            #pragma unroll
            for (int jj = 0; jj < 4; jj++) {
                sum += acc[i][g2][jj];
                sq  += acc[i][g2][jj] * acc[i][g2][jj];
            }
        #pragma unroll
        for (int m = 1; m < 32; m <<= 1) {
            sum += __shfl_xor(sum, m);
            sq  += __shfl_xor(sq, m);
        }
        float mean = sum * (1.f / DVH);
        float var = sq * (1.f / DVH) - mean * mean;
        float inv = rsqrtf(var + 1e-5f);
        size_t mrow = (size_t)(tok0 + t0 + i) * VDIM + cbase;
        float4 gA = *(const float4*)(gb_ + mrow);
        float4 gB = *(const float4*)(gb_ + mrow + 128);
        float gv[2][4] = {{gA.x, gA.y, gA.z, gA.w}, {gB.x, gB.y, gB.z, gB.w}};
        #pragma unroll
        for (int g2 = 0; g2 < 2; g2++) {
            float o4[4];
            #pragma unroll
            for (int jj = 0; jj < 4; jj++) {
                float gg = gv[g2][jj];
                float sig = 1.f / (1.f + __expf(-gg));
                o4[jj] = ((acc[i][g2][jj] - mean) * inv * gwv[g2][jj] + gbv[g2][jj]) * (gg * sig);
            }
            *(float4*)(vb + mrow + g2 * 128) = make_float4(o4[0], o4[1], o4[2], o4[3]);
        }
    }
}

// ---------------------------------------------------------------------------
// Kernel 6: output GEMM, split precision
// ---------------------------------------------------------------------------
__global__ __launch_bounds__(256) void k_gemm_out(
    const float* __restrict__ A, const bf16* __restrict__ Bh,
    const bf16* __restrict__ Bl, float* __restrict__ C, int M, int N, int K)
{
    __shared__ unsigned short Ah[128 * 32];
    __shared__ unsigned short Al[128 * 32];
    __shared__ unsigned short Bhs[128 * 32];
    __shared__ unsigned short Bls[128 * 32];
    int tid = threadIdx.x;
    int bm = blockIdx.x * 128, bn = blockIdx.y * 128;
    int lane = tid & 63, w = tid >> 6;
    int wr = w >> 1, wc = w & 1;
    const unsigned short* Bh16 = (const unsigned short*)Bh;
    const unsigned short* Bl16 = (const unsigned short*)Bl;
    f32x4 acc[4][4];
    #pragma unroll
    for (int i = 0; i < 4; i++)
        #pragma unroll
        for (int j = 0; j < 4; j++)
            acc[i][j] = (f32x4){0.f, 0.f, 0.f, 0.f};
    int arow = tid >> 1, acol = (tid & 1) * 16;
    int ch0 = tid, ch1 = tid + 256;
    int r0c = ch0 >> 2, c0c = (ch0 & 3) * 8;
    int r1c = ch1 >> 2, c1c = (ch1 & 3) * 8;
    int fr = lane & 15, kb = (lane >> 4) * 8;
    for (int k0 = 0; k0 < K; k0 += 32) {
        float av[16];
        #pragma unroll
        for (int q = 0; q < 4; q++) {
            float4 t4 = *(const float4*)(A + (size_t)(bm + arow) * K + k0 + acol + q * 4);
            av[q * 4 + 0] = t4.x; av[q * 4 + 1] = t4.y;
            av[q * 4 + 2] = t4.z; av[q * 4 + 3] = t4.w;
        }
        uint4 bh0 = *(const uint4*)(Bh16 + (size_t)(bn + r0c) * K + k0 + c0c);
        uint4 bh1 = *(const uint4*)(Bh16 + (size_t)(bn + r1c) * K + k0 + c1c);
        uint4 bl0 = *(const uint4*)(Bl16 + (size_t)(bn + r0c) * K + k0 + c0c);
        uint4 bl1 = *(const uint4*)(Bl16 + (size_t)(bn + r1c) * K + k0 + c1c);
        __syncthreads();
        alignas(16) unsigned short th[16], tl[16];
        #pragma unroll
        for (int q = 0; q < 16; q++) {
            unsigned short hu = f2u(av[q]);
            th[q] = hu;
            tl[q] = f2u(av[q] - u2f(hu));
        }
        *(uint4*)(Ah + arow * 32 + acol)     = *(const uint4*)&th[0];
        *(uint4*)(Ah + arow * 32 + acol + 8) = *(const uint4*)&th[8];
        *(uint4*)(Al + arow * 32 + acol)     = *(const uint4*)&tl[0];
        *(uint4*)(Al + arow * 32 + acol + 8) = *(const uint4*)&tl[8];
        *(uint4*)(Bhs + ch0 * 8) = bh0;
        *(uint4*)(Bhs + ch1 * 8) = bh1;
        *(uint4*)(Bls + ch0 * 8) = bl0;
        *(uint4*)(Bls + ch1 * 8) = bl1;
        __syncthreads();
        bf16x8 afh[4], afl[4], bfh[4], bfl[4];
        #pragma unroll
        for (int i = 0; i < 4; i++) {
            afh[i] = *(const bf16x8*)(Ah + (wr * 64 + i * 16 + fr) * 32 + kb);
            afl[i] = *(const bf16x8*)(Al + (wr * 64 + i * 16 + fr) * 32 + kb);
            bfh[i] = *(const bf16x8*)(Bhs + (wc * 64 + i * 16 + fr) * 32 + kb);
            bfl[i] = *(const bf16x8*)(Bls + (wc * 64 + i * 16 + fr) * 32 + kb);
        }
        #pragma unroll
        for (int i = 0; i < 4; i++)
            #pragma unroll
            for (int j = 0; j < 4; j++) {
                acc[i][j] = __builtin_amdgcn_mfma_f32_16x16x32_bf16(afh[i], bfh[j], acc[i][j], 0, 0, 0);
                acc[i][j] = __builtin_amdgcn_mfma_f32_16x16x32_bf16(afl[i], bfh[j], acc[i][j], 0, 0, 0);
                acc[i][j] = __builtin_amdgcn_mfma_f32_16x16x32_bf16(afh[i], bfl[j], acc[i][j], 0, 0, 0);
            }
    }
    int er = (lane >> 4) * 4, ec = lane & 15;
    #pragma unroll
    for (int i = 0; i < 4; i++) {
        int gr = bm + wr * 64 + i * 16 + er;
        #pragma unroll
        for (int j = 0; j < 4; j++) {
            int gc = bn + wc * 64 + j * 16 + ec;
            #pragma unroll
            for (int q = 0; q < 4; q++)
                C[(size_t)(gr + q) * N + gc] = acc[i][j][q];
        }
    }
}

// ---------------------------------------------------------------------------
extern "C" void kernel_launch(void* const* d_in, const int* in_sizes, int n_in,
                              void* d_out, int out_size, void* d_ws, size_t ws_size,
                              hipStream_t stream)
{
    const float* h        = (const float*)d_in[0];
    const float* x_mu     = (const float*)d_in[1];
    const float* xl_w1    = (const float*)d_in[2];
    const float* xl_w2    = (const float*)d_in[3];
    const float* xl_b2    = (const float*)d_in[4];
    const float* x_out_w  = (const float*)d_in[5];
    const float* x_bias   = (const float*)d_in[6];
    const float* r_w      = (const float*)d_in[7];
    const float* w_w1     = (const float*)d_in[8];
    const float* w_w2     = (const float*)d_in[9];
    const float* w_b      = (const float*)d_in[10];
    const float* k_w      = (const float*)d_in[11];
    const float* v_w      = (const float*)d_in[12];
    const float* g_w      = (const float*)d_in[13];
    const float* bonus    = (const float*)d_in[14];
    const float* gn_w     = (const float*)d_in[15];
    const float* gn_b     = (const float*)d_in[16];
    const float* o_w      = (const float*)d_in[17];
    float* out = (float*)d_out;

    // Workspace overlay: total 35,733,504 floats = 142.9 MB (proven size)
    float* ws = (float*)d_ws;
    bf16*  wbf  = (bf16*)ws;                       // 8,388,608 bf16 = 4,194,304 slots
    float* rbuf = ws + 4194304;                    // 2,097,152
    float* vbuf = ws + 6291456;                    // 4,194,304 (y f32 in place later)
    float* gbuf = ws + 10485760;                   // 4,194,304
    float* kbuf = ws + 14680064;                   // 2,097,152
    float* ebuf = ws + 16777216;                   // 2,097,152
    float* ubuf = ws + 18874368;                   // 16,384
    float* Dbuf = ws + 18890752;                   // 65,536
    float* BIG  = ws + 18956288;                   // 16,777,216 (X phase / Mbuf)

    // weight hi/lo (bf16 element offsets within wbf)
    bf16* rwb_h = wbf;                  // 524,288
    bf16* kwb_h = wbf + 524288;
    bf16* vwb_h = wbf + 1048576;        // 1,048,576
    bf16* gwb_h = wbf + 2097152;
    bf16* owb_h = wbf + 3145728;
    bf16* rwb_l = wbf + 4194304;
    bf16* kwb_l = wbf + 4718592;
    bf16* vwb_l = wbf + 5242880;
    bf16* gwb_l = wbf + 6291456;
    bf16* owb_l = wbf + 7340032;

    // X phase inside BIG (each bf16 X = 2,097,152 float slots)
    float* Xw = BIG;                           // f32 [0 .. 4,194,304)
    bf16*  Xr = (bf16*)(BIG + 4194304);
    bf16*  Xk = (bf16*)(BIG + 6291456);
    bf16*  Xv = (bf16*)(BIG + 8388608);
    bf16*  Xg = (bf16*)(BIG + 10485760);
    float* x1   = BIG + 12582912;              // 655,360  (dead after mix)
    float* t0bf = BIG + 13238272;              // 131,072  (dead after k_x1b)
    float* w1p  = BIG + 12582912;              // 2,097,152 (after x1/t0 dead; dead before Mbuf)
    float* Mbuf = BIG;                         // full 16,777,216 after X dead
    float* ybuf = vbuf;                        // y f32 in place over v

    // weight conversion (hi/lo pairs), single launch
    k_f2b2_all<<<2048, 256, 0, stream>>>(r_w, k_w, v_w, g_w, o_w,
                                         rwb_h, rwb_l, kwb_h, kwb_l,
                                         vwb_h, vwb_l, gwb_h, gwb_l,
                                         owb_h, owb_l);

    // x1 path: MFMA phase-1 + small phase-2
    k_x1mm<<<NTOK / 64, 256, 0, stream>>>(h, x_mu, xl_w1, t0bf);
    k_x1b<<<NTOK / 64, 256, 0, stream>>>(t0bf, xl_w2, xl_b2, x1);

    // mix: f32 w-slice + MFMA bf16 four-slice
    k_mixw<<<dim3(NTOK / 64, HH / 64), 256, 0, stream>>>(h, x1, x_out_w, x_bias, Xw);
    k_mix4<<<dim3(NTOK / 64, HH / 64), 256, 0, stream>>>(h, x1, x_out_w, x_bias,
                                                         Xr, Xk, Xv, Xg);

    // projections: fused hi/lo MFMA (r+k merged, v+g merged); split-K f32 w path
    k_gemm_hl2<<<dim3(NTOK / 128, KDIM / 128, 2), 256, 0, stream>>>(
        Xr, rwb_h, rwb_l, rbuf, Xk, kwb_h, kwb_l, kbuf, NTOK, KDIM, HH);
    k_gemm_hl2<<<dim3(NTOK / 128, VDIM / 128, 2), 256, 0, stream>>>(
        Xv, vwb_h, vwb_l, vbuf, Xg, gwb_h, gwb_l, gbuf, NTOK, VDIM, HH);
    k_w1<<<dim3(NTOK / 64, WKS), 256, 0, stream>>>(Xw, w_w1, w1p);
    k_we<<<dim3(NTOK / 64, KDIM / 64), 256, 0, stream>>>(w1p, w_w2, w_b, ebuf);

    k_chunkA1<<<dim3(BB * NHD, NCK), 256, 0, stream>>>(ebuf, rbuf, kbuf, vbuf,
                                                       bonus, ubuf, Mbuf, Dbuf);
    k_chunkB<<<dim3(BB * NHD, 32), 256, 0, stream>>>(Mbuf, Dbuf);
    k_chunkCG<<<dim3(BB * NHD, NCK), 512, 0, stream>>>(rbuf, kbuf, vbuf, ubuf, Mbuf,
                                                       gbuf, gn_w, gn_b);

    k_gemm_out<<<dim3(NTOK / 128, HH / 128), 256, 0, stream>>>(ybuf, owb_h, owb_l, out, NTOK, HH, VDIM);
}